// Round 1
// baseline (666.879 us; speedup 1.0000x reference)
//
#include <hip/hip_runtime.h>
#include <cmath>

#define NN 50000
#define NE 800000
#define FIN 256
#define HD 64
#define CD 40
#define NEG_SLOPE 0.2f

// ---------------- wave-level reductions (64 lanes) ----------------
__device__ __forceinline__ float wave_sum(float v) {
#pragma unroll
  for (int m = 32; m >= 1; m >>= 1) v += __shfl_xor(v, m, 64);
  return v;
}
__device__ __forceinline__ float wave_max(float v) {
#pragma unroll
  for (int m = 32; m >= 1; m >>= 1) v = fmaxf(v, __shfl_xor(v, m, 64));
  return v;
}

// ---------------- CSR build ----------------
__global__ __launch_bounds__(256) void init_counts(int* __restrict__ counts) {
  int i = blockIdx.x * 256 + threadIdx.x;
  if (i < NN) counts[i] = 1;  // self-loop pre-count
}

__global__ __launch_bounds__(256) void count_edges(const int* __restrict__ ei,
                                                   int* __restrict__ counts) {
  int i = blockIdx.x * 256 + threadIdx.x;
  if (i < NE) atomicAdd(&counts[ei[NE + i]], 1);
}

__global__ __launch_bounds__(256) void scan_block(const int* __restrict__ in,
                                                  int* __restrict__ partial,
                                                  int* __restrict__ bsums) {
  __shared__ int s[256];
  int i = blockIdx.x * 256 + threadIdx.x;
  int v = (i < NN) ? in[i] : 0;
  s[threadIdx.x] = v;
  __syncthreads();
#pragma unroll
  for (int off = 1; off < 256; off <<= 1) {
    int t = (threadIdx.x >= off) ? s[threadIdx.x - off] : 0;
    __syncthreads();
    s[threadIdx.x] += t;
    __syncthreads();
  }
  if (i < NN) partial[i] = s[threadIdx.x];  // inclusive within block
  if (threadIdx.x == 255) bsums[blockIdx.x] = s[255];
}

__global__ __launch_bounds__(256) void scan_top(int* __restrict__ bsums, int nb) {
  __shared__ int s[256];
  int v = (threadIdx.x < nb) ? bsums[threadIdx.x] : 0;
  s[threadIdx.x] = v;
  __syncthreads();
#pragma unroll
  for (int off = 1; off < 256; off <<= 1) {
    int t = (threadIdx.x >= off) ? s[threadIdx.x - off] : 0;
    __syncthreads();
    s[threadIdx.x] += t;
    __syncthreads();
  }
  int excl = (threadIdx.x == 0) ? 0 : s[threadIdx.x - 1];
  if (threadIdx.x < nb) bsums[threadIdx.x] = excl;
}

__global__ __launch_bounds__(256) void scan_final(const int* __restrict__ partial,
                                                  const int* __restrict__ bsums,
                                                  int* __restrict__ offsets) {
  int i = blockIdx.x * 256 + threadIdx.x;
  if (i < NN) {
    offsets[i + 1] = partial[i] + bsums[blockIdx.x];
    if (i == 0) offsets[0] = 0;
  }
}

__global__ __launch_bounds__(256) void copy_cursor(const int* __restrict__ offsets,
                                                   int* __restrict__ cursor) {
  int i = blockIdx.x * 256 + threadIdx.x;
  if (i < NN) cursor[i] = offsets[i];
}

__global__ __launch_bounds__(256) void fill_csr(const int* __restrict__ ei,
                                                int* __restrict__ cursor,
                                                int* __restrict__ csr_src) {
  int i = blockIdx.x * 256 + threadIdx.x;
  if (i < NE + NN) {
    int s, d;
    if (i < NE) { s = ei[i]; d = ei[NE + i]; }
    else        { s = i - NE; d = s; }
    int p = atomicAdd(&cursor[d], 1);
    csr_src[p] = s;
  }
}

// ---------------- fp32 GEMM: Y[N,64pad] = X[N,K] @ W[K,OC] + b ----------------
// 32-row LDS tile (+4 pad: 2-way bank aliasing, free), thread = 2 rows x 4 cols.
template <int K>
__global__ __launch_bounds__(256) void gemm_bias(const float* __restrict__ X,
                                                 const float* __restrict__ W,
                                                 const float* __restrict__ bias,
                                                 float* __restrict__ Y, int OC) {
  constexpr int KP = K + 4;
  __shared__ float xs[32 * KP];
  const int tid = threadIdx.x;
  const int row0 = blockIdx.x * 32;
  const int nvalid = min(32, NN - row0);
  const float4* Xv = reinterpret_cast<const float4*>(X + (size_t)row0 * K);
  const int totv = 32 * K / 4;
  const int valv = nvalid * K / 4;
  for (int i = tid; i < totv; i += 256) {
    float4 v = make_float4(0.f, 0.f, 0.f, 0.f);
    if (i < valv) v = Xv[i];
    const int r = i / (K / 4);
    const int c4 = i % (K / 4);
    *reinterpret_cast<float4*>(&xs[r * KP + c4 * 4]) = v;
  }
  __syncthreads();
  const int c0 = (tid & 15) * 4;
  const int r0 = (tid >> 4) * 2;
  float acc[2][4] = {};
  if (c0 < OC) {  // idle col-groups (OC=40) keep acc=0 -> zero pad columns
#pragma unroll 4
    for (int k = 0; k < K; k += 4) {
      const float4 w0 = *reinterpret_cast<const float4*>(&W[(k + 0) * OC + c0]);
      const float4 w1 = *reinterpret_cast<const float4*>(&W[(k + 1) * OC + c0]);
      const float4 w2 = *reinterpret_cast<const float4*>(&W[(k + 2) * OC + c0]);
      const float4 w3 = *reinterpret_cast<const float4*>(&W[(k + 3) * OC + c0]);
#pragma unroll
      for (int j = 0; j < 2; ++j) {
        const float4 xv = *reinterpret_cast<const float4*>(&xs[(r0 + j) * KP + k]);
        acc[j][0] = fmaf(xv.w, w3.x, fmaf(xv.z, w2.x, fmaf(xv.y, w1.x, fmaf(xv.x, w0.x, acc[j][0]))));
        acc[j][1] = fmaf(xv.w, w3.y, fmaf(xv.z, w2.y, fmaf(xv.y, w1.y, fmaf(xv.x, w0.y, acc[j][1]))));
        acc[j][2] = fmaf(xv.w, w3.z, fmaf(xv.z, w2.z, fmaf(xv.y, w1.z, fmaf(xv.x, w0.z, acc[j][2]))));
        acc[j][3] = fmaf(xv.w, w3.w, fmaf(xv.z, w2.w, fmaf(xv.y, w1.w, fmaf(xv.x, w0.w, acc[j][3]))));
      }
    }
  }
  const float b0 = (c0 + 0 < OC) ? bias[c0 + 0] : 0.f;
  const float b1 = (c0 + 1 < OC) ? bias[c0 + 1] : 0.f;
  const float b2 = (c0 + 2 < OC) ? bias[c0 + 2] : 0.f;
  const float b3 = (c0 + 3 < OC) ? bias[c0 + 3] : 0.f;
#pragma unroll
  for (int j = 0; j < 2; ++j) {
    const int row = row0 + r0 + j;
    if (row < NN) {
      float4 o;
      o.x = (c0 + 0 < OC) ? acc[j][0] + b0 : 0.f;
      o.y = (c0 + 1 < OC) ? acc[j][1] + b1 : 0.f;
      o.z = (c0 + 2 < OC) ? acc[j][2] + b2 : 0.f;
      o.w = (c0 + 3 < OC) ? acc[j][3] + b3 : 0.f;
      *reinterpret_cast<float4*>(&Y[(size_t)row * 64 + c0]) = o;
    }
  }
}

// ---------------- node-centric GATv2 aggregation, online softmax ----------------
// One wave per dst node; lane = feature dim (stride-64 padded arrays).
template <int OC, bool FINAL>
__global__ __launch_bounds__(256) void gat_agg(const float* __restrict__ XL,
                                               const float* __restrict__ XR,
                                               const float* __restrict__ XLIN,
                                               const float* __restrict__ att,
                                               const float* __restrict__ bias,
                                               const int* __restrict__ offsets,
                                               const int* __restrict__ csr_src,
                                               float* __restrict__ out) {
  const int lane = threadIdx.x & 63;
  const int d = blockIdx.x * 4 + (threadIdx.x >> 6);
  if (d >= NN) return;
  const float a = (lane < OC) ? att[lane] : 0.f;
  const float xr = XR[(size_t)d * 64 + lane];
  const int beg = offsets[d];
  const int end = offsets[d + 1];
  float m = -INFINITY, denom = 0.f, acc = 0.f;
  for (int i = beg; i < end; ++i) {
    const int s = csr_src[i];
    const float xl = XL[(size_t)s * 64 + lane];
    const float t = xl + xr;
    const float lr = (t > 0.f) ? t : NEG_SLOPE * t;
    const float e = wave_sum(lr * a);  // wave-uniform logit
    if (e > m) {                       // uniform branch, no divergence
      const float sc = __expf(m - e);  // m=-inf on first edge -> 0
      denom = denom * sc + 1.f;
      acc = acc * sc + xl;
      m = e;
    } else {
      const float w = __expf(e - m);
      denom += w;
      acc += w * xl;
    }
  }
  const float val = acc / denom + ((lane < OC) ? bias[lane] : 0.f) +
                    XLIN[(size_t)d * 64 + lane];
  if (!FINAL) {
    out[(size_t)d * 64 + lane] = fmaxf(val, 0.f);  // relu -> h
  } else {
    const float v = (lane < OC) ? val : -INFINITY;
    const float mx = wave_max(v);
    const float ex = (lane < OC) ? __expf(val - mx) : 0.f;
    const float sm = wave_sum(ex);
    if (lane < OC) out[(size_t)d * OC + lane] = val - mx - __logf(sm);
  }
}

// ---------------- pass-through edge_index as float (output 1) ----------------
__global__ __launch_bounds__(256) void copy_edges(const int* __restrict__ ei,
                                                  float* __restrict__ out) {
  int i = blockIdx.x * 256 + threadIdx.x;
  if (i < 2 * NE) out[i] = (float)ei[i];
}

// ---------------- launch ----------------
extern "C" void kernel_launch(void* const* d_in, const int* in_sizes, int n_in,
                              void* d_out, int out_size, void* d_ws, size_t ws_size,
                              hipStream_t stream) {
  const float* x     = (const float*)d_in[0];
  const int*   ei    = (const int*)d_in[1];
  const float* W1l   = (const float*)d_in[2];
  const float* b1l   = (const float*)d_in[3];
  const float* W1r   = (const float*)d_in[4];
  const float* b1r   = (const float*)d_in[5];
  const float* att1  = (const float*)d_in[6];
  const float* bias1 = (const float*)d_in[7];
  const float* lin1W = (const float*)d_in[8];
  const float* lin1b = (const float*)d_in[9];
  const float* W2l   = (const float*)d_in[10];
  const float* b2l   = (const float*)d_in[11];
  const float* W2r   = (const float*)d_in[12];
  const float* b2r   = (const float*)d_in[13];
  const float* att2  = (const float*)d_in[14];
  const float* bias2 = (const float*)d_in[15];
  const float* lin2W = (const float*)d_in[16];
  const float* lin2b = (const float*)d_in[17];
  float* out = (float*)d_out;

  char* ws = (char*)d_ws;
  size_t off = 0;
  auto alloc = [&](size_t bytes) -> void* {
    void* p = ws + off;
    off += (bytes + 255) & ~(size_t)255;
    return p;
  };
  float* XL1   = (float*)alloc((size_t)NN * 64 * 4);
  float* XR1   = (float*)alloc((size_t)NN * 64 * 4);
  float* XLIN1 = (float*)alloc((size_t)NN * 64 * 4);
  float* Hb    = (float*)alloc((size_t)NN * 64 * 4);
  float* XL2   = (float*)alloc((size_t)NN * 64 * 4);
  float* XR2   = (float*)alloc((size_t)NN * 64 * 4);
  float* XLIN2 = (float*)alloc((size_t)NN * 64 * 4);
  int* counts  = (int*)alloc((size_t)NN * 4);
  int* partial = (int*)alloc((size_t)NN * 4);
  int* bsums   = (int*)alloc(1024);
  int* offsets = (int*)alloc((size_t)(NN + 1) * 4);
  int* cursor  = (int*)alloc((size_t)NN * 4);
  int* csr     = (int*)alloc((size_t)(NE + NN) * 4);

  const int SB = (NN + 255) / 256;  // 196 scan blocks (<=256 for scan_top)

  // CSR build (independent of GEMMs, all stream-ordered)
  init_counts<<<SB, 256, 0, stream>>>(counts);
  count_edges<<<(NE + 255) / 256, 256, 0, stream>>>(ei, counts);
  scan_block<<<SB, 256, 0, stream>>>(counts, partial, bsums);
  scan_top<<<1, 256, 0, stream>>>(bsums, SB);
  scan_final<<<SB, 256, 0, stream>>>(partial, bsums, offsets);
  copy_cursor<<<SB, 256, 0, stream>>>(offsets, cursor);
  fill_csr<<<(NE + NN + 255) / 256, 256, 0, stream>>>(ei, cursor, csr);

  const int GB = (NN + 31) / 32;
  // layer 1
  gemm_bias<256><<<GB, 256, 0, stream>>>(x, W1l, b1l, XL1, 64);
  gemm_bias<256><<<GB, 256, 0, stream>>>(x, W1r, b1r, XR1, 64);
  gemm_bias<256><<<GB, 256, 0, stream>>>(x, lin1W, lin1b, XLIN1, 64);
  gat_agg<64, false><<<(NN + 3) / 4, 256, 0, stream>>>(XL1, XR1, XLIN1, att1,
                                                       bias1, offsets, csr, Hb);
  // layer 2 (padded to stride 64, zero cols 40..63)
  gemm_bias<64><<<GB, 256, 0, stream>>>(Hb, W2l, b2l, XL2, 40);
  gemm_bias<64><<<GB, 256, 0, stream>>>(Hb, W2r, b2r, XR2, 40);
  gemm_bias<64><<<GB, 256, 0, stream>>>(Hb, lin2W, lin2b, XLIN2, 40);
  gat_agg<40, true><<<(NN + 3) / 4, 256, 0, stream>>>(XL2, XR2, XLIN2, att2,
                                                      bias2, offsets, csr, out);
  // output 1: edge_index cast to float
  copy_edges<<<(2 * NE + 255) / 256, 256, 0, stream>>>(ei, out + (size_t)NN * CD);
}

// Round 2
// 509.851 us; speedup vs baseline: 1.3080x; 1.3080x over previous
//
#include <hip/hip_runtime.h>
#include <cmath>

#define NN 50000
#define NE 800000
#define CD 40
#define NEG_SLOPE 0.2f

// ---------------- CSR build ----------------
__global__ __launch_bounds__(256) void init_counts(int* __restrict__ counts) {
  int i = blockIdx.x * 256 + threadIdx.x;
  if (i < NN) counts[i] = 1;  // self-loop pre-count
}

__global__ __launch_bounds__(256) void count_edges(const int* __restrict__ ei,
                                                   int* __restrict__ counts) {
  int i = blockIdx.x * 256 + threadIdx.x;
  if (i < NE) atomicAdd(&counts[ei[NE + i]], 1);
}

__global__ __launch_bounds__(256) void scan_block(const int* __restrict__ in,
                                                  int* __restrict__ partial,
                                                  int* __restrict__ bsums) {
  __shared__ int s[256];
  int i = blockIdx.x * 256 + threadIdx.x;
  int v = (i < NN) ? in[i] : 0;
  s[threadIdx.x] = v;
  __syncthreads();
#pragma unroll
  for (int off = 1; off < 256; off <<= 1) {
    int t = (threadIdx.x >= off) ? s[threadIdx.x - off] : 0;
    __syncthreads();
    s[threadIdx.x] += t;
    __syncthreads();
  }
  if (i < NN) partial[i] = s[threadIdx.x];  // inclusive within block
  if (threadIdx.x == 255) bsums[blockIdx.x] = s[255];
}

__global__ __launch_bounds__(256) void scan_top(int* __restrict__ bsums, int nb) {
  __shared__ int s[256];
  int v = (threadIdx.x < nb) ? bsums[threadIdx.x] : 0;
  s[threadIdx.x] = v;
  __syncthreads();
#pragma unroll
  for (int off = 1; off < 256; off <<= 1) {
    int t = (threadIdx.x >= off) ? s[threadIdx.x - off] : 0;
    __syncthreads();
    s[threadIdx.x] += t;
    __syncthreads();
  }
  int excl = (threadIdx.x == 0) ? 0 : s[threadIdx.x - 1];
  if (threadIdx.x < nb) bsums[threadIdx.x] = excl;
}

// offsets[i+1] = inclusive(i); cursor[i] = inclusive(i) - counts[i] = offsets[i]
__global__ __launch_bounds__(256) void scan_final(const int* __restrict__ partial,
                                                  const int* __restrict__ bsums,
                                                  const int* __restrict__ counts,
                                                  int* __restrict__ offsets,
                                                  int* __restrict__ cursor) {
  int i = blockIdx.x * 256 + threadIdx.x;
  if (i < NN) {
    int incl = partial[i] + bsums[blockIdx.x];
    offsets[i + 1] = incl;
    cursor[i] = incl - counts[i];
    if (i == 0) offsets[0] = 0;
  }
}

__global__ __launch_bounds__(256) void fill_csr(const int* __restrict__ ei,
                                                int* __restrict__ cursor,
                                                int* __restrict__ csr_src) {
  int i = blockIdx.x * 256 + threadIdx.x;
  if (i < NE + NN) {
    int s, d;
    if (i < NE) { s = ei[i]; d = ei[NE + i]; }
    else        { s = i - NE; d = s; }
    int p = atomicAdd(&cursor[d], 1);
    csr_src[p] = s;
  }
}

// ---------------- fused triple fp32 GEMM: Yk[N,64pad] = X[N,K] @ Wk + bk ----------------
template <int K>
__global__ __launch_bounds__(256) void gemm3(const float* __restrict__ X,
                                             const float* __restrict__ W0,
                                             const float* __restrict__ B0,
                                             float* __restrict__ Y0,
                                             const float* __restrict__ W1,
                                             const float* __restrict__ B1,
                                             float* __restrict__ Y1,
                                             const float* __restrict__ W2,
                                             const float* __restrict__ B2,
                                             float* __restrict__ Y2, int OC) {
  constexpr int KP = K + 4;
  __shared__ float xs[32 * KP];
  const int tid = threadIdx.x;
  const int row0 = blockIdx.x * 32;
  const int nvalid = min(32, NN - row0);
  const float4* Xv = reinterpret_cast<const float4*>(X + (size_t)row0 * K);
  const int totv = 32 * K / 4;
  const int valv = nvalid * K / 4;
  for (int i = tid; i < totv; i += 256) {
    float4 v = make_float4(0.f, 0.f, 0.f, 0.f);
    if (i < valv) v = Xv[i];
    const int r = i / (K / 4);
    const int c4 = i % (K / 4);
    *reinterpret_cast<float4*>(&xs[r * KP + c4 * 4]) = v;
  }
  __syncthreads();
  const int c0 = (tid & 15) * 4;
  const int r0 = (tid >> 4) * 2;
#pragma unroll
  for (int wsel = 0; wsel < 3; ++wsel) {
    const float* W = (wsel == 0) ? W0 : (wsel == 1) ? W1 : W2;
    const float* B = (wsel == 0) ? B0 : (wsel == 1) ? B1 : B2;
    float* Y = (wsel == 0) ? Y0 : (wsel == 1) ? Y1 : Y2;
    float acc[2][4] = {};
    if (c0 < OC) {
#pragma unroll 4
      for (int k = 0; k < K; k += 4) {
        const float4 w0 = *reinterpret_cast<const float4*>(&W[(k + 0) * OC + c0]);
        const float4 w1 = *reinterpret_cast<const float4*>(&W[(k + 1) * OC + c0]);
        const float4 w2 = *reinterpret_cast<const float4*>(&W[(k + 2) * OC + c0]);
        const float4 w3 = *reinterpret_cast<const float4*>(&W[(k + 3) * OC + c0]);
#pragma unroll
        for (int j = 0; j < 2; ++j) {
          const float4 xv = *reinterpret_cast<const float4*>(&xs[(r0 + j) * KP + k]);
          acc[j][0] = fmaf(xv.w, w3.x, fmaf(xv.z, w2.x, fmaf(xv.y, w1.x, fmaf(xv.x, w0.x, acc[j][0]))));
          acc[j][1] = fmaf(xv.w, w3.y, fmaf(xv.z, w2.y, fmaf(xv.y, w1.y, fmaf(xv.x, w0.y, acc[j][1]))));
          acc[j][2] = fmaf(xv.w, w3.z, fmaf(xv.z, w2.z, fmaf(xv.y, w1.z, fmaf(xv.x, w0.z, acc[j][2]))));
          acc[j][3] = fmaf(xv.w, w3.w, fmaf(xv.z, w2.w, fmaf(xv.y, w1.w, fmaf(xv.x, w0.w, acc[j][3]))));
        }
      }
    }
    const float b0 = (c0 + 0 < OC) ? B[c0 + 0] : 0.f;
    const float b1 = (c0 + 1 < OC) ? B[c0 + 1] : 0.f;
    const float b2 = (c0 + 2 < OC) ? B[c0 + 2] : 0.f;
    const float b3 = (c0 + 3 < OC) ? B[c0 + 3] : 0.f;
#pragma unroll
    for (int j = 0; j < 2; ++j) {
      const int row = row0 + r0 + j;
      if (row < NN) {
        float4 o;
        o.x = (c0 + 0 < OC) ? acc[j][0] + b0 : 0.f;
        o.y = (c0 + 1 < OC) ? acc[j][1] + b1 : 0.f;
        o.z = (c0 + 2 < OC) ? acc[j][2] + b2 : 0.f;
        o.w = (c0 + 3 < OC) ? acc[j][3] + b3 : 0.f;
        *reinterpret_cast<float4*>(&Y[(size_t)row * 64 + c0]) = o;
      }
    }
  }
}

// ---------------- GATv2 aggregation: 16 lanes/edge, 4 edges in flight ----------------
// Wave = 4 groups of 16 lanes; group g handles edges beg+4*it+g of dst d.
// Lane l holds feature dims 4l..4l+3 (float4). Each group keeps a private
// online-softmax state (m, D, A[4]); states merged across groups at the end.
template <int OC, bool FINAL>
__global__ __launch_bounds__(256) void gat_agg(const float* __restrict__ XL,
                                               const float* __restrict__ XR,
                                               const float* __restrict__ XLIN,
                                               const float* __restrict__ att,
                                               const float* __restrict__ bias,
                                               const int* __restrict__ offsets,
                                               const int* __restrict__ csr,
                                               float* __restrict__ out) {
  const int lane = threadIdx.x & 63;
  const int g = lane >> 4;
  const int l = lane & 15;
  const int d = blockIdx.x * 4 + (threadIdx.x >> 6);
  if (d >= NN) return;
  const bool dimok = (4 * l < OC);
  float4 a4 = make_float4(0.f, 0.f, 0.f, 0.f);
  if (dimok) a4 = *reinterpret_cast<const float4*>(&att[4 * l]);
  const float4 xr4 = *reinterpret_cast<const float4*>(&XR[(size_t)d * 64 + 4 * l]);
  const int beg = offsets[d];
  const int end = offsets[d + 1];
  float m = -1e30f, D = 0.f;
  float4 A = make_float4(0.f, 0.f, 0.f, 0.f);
  const int nit = (end - beg + 3) >> 2;
  for (int it = 0; it < nit; ++it) {
    const int i = beg + it * 4 + g;
    const bool act = (i < end);
    const int s = csr[act ? i : beg];
    const float4 xl = *reinterpret_cast<const float4*>(&XL[(size_t)s * 64 + 4 * l]);
    float4 t;
    t.x = xl.x + xr4.x; t.y = xl.y + xr4.y; t.z = xl.z + xr4.z; t.w = xl.w + xr4.w;
    float4 lr;  // leaky_relu(t) = max(t, 0.2*t)
    lr.x = fmaxf(t.x, NEG_SLOPE * t.x);
    lr.y = fmaxf(t.y, NEG_SLOPE * t.y);
    lr.z = fmaxf(t.z, NEG_SLOPE * t.z);
    lr.w = fmaxf(t.w, NEG_SLOPE * t.w);
    float p = lr.x * a4.x;
    p = fmaf(lr.y, a4.y, p);
    p = fmaf(lr.z, a4.z, p);
    p = fmaf(lr.w, a4.w, p);
    p += __shfl_xor(p, 1, 64);
    p += __shfl_xor(p, 2, 64);
    p += __shfl_xor(p, 4, 64);
    p += __shfl_xor(p, 8, 64);  // e, uniform within the 16-lane group
    const float e = act ? p : -3e38f;
    const float mn = fmaxf(m, e);
    const float c = __expf(m - mn);   // 1 if m unchanged; 0 on first real edge
    const float w = __expf(e - mn);   // 0 for inactive slots
    D = fmaf(D, c, w);
    A.x = fmaf(A.x, c, w * xl.x);
    A.y = fmaf(A.y, c, w * xl.y);
    A.z = fmaf(A.z, c, w * xl.z);
    A.w = fmaf(A.w, c, w * xl.w);
    m = mn;
  }
  // merge the 4 group states
  float mw = fmaxf(m, __shfl_xor(m, 16, 64));
  mw = fmaxf(mw, __shfl_xor(mw, 32, 64));
  const float sc = __expf(m - mw);  // 0 for groups that saw no edge
  float Dw = D * sc;
  Dw += __shfl_xor(Dw, 16, 64);
  Dw += __shfl_xor(Dw, 32, 64);
  float4 Aw;
  Aw.x = A.x * sc; Aw.y = A.y * sc; Aw.z = A.z * sc; Aw.w = A.w * sc;
  Aw.x += __shfl_xor(Aw.x, 16, 64); Aw.x += __shfl_xor(Aw.x, 32, 64);
  Aw.y += __shfl_xor(Aw.y, 16, 64); Aw.y += __shfl_xor(Aw.y, 32, 64);
  Aw.z += __shfl_xor(Aw.z, 16, 64); Aw.z += __shfl_xor(Aw.z, 32, 64);
  Aw.w += __shfl_xor(Aw.w, 16, 64); Aw.w += __shfl_xor(Aw.w, 32, 64);
  const float4 xlin = *reinterpret_cast<const float4*>(&XLIN[(size_t)d * 64 + 4 * l]);
  float4 b4 = make_float4(0.f, 0.f, 0.f, 0.f);
  if (dimok) b4 = *reinterpret_cast<const float4*>(&bias[4 * l]);
  const float inv = 1.0f / Dw;  // Dw > 0 guaranteed (self-loop)
  float4 val;
  val.x = fmaf(Aw.x, inv, b4.x) + xlin.x;
  val.y = fmaf(Aw.y, inv, b4.y) + xlin.y;
  val.z = fmaf(Aw.z, inv, b4.z) + xlin.z;
  val.w = fmaf(Aw.w, inv, b4.w) + xlin.w;
  if (!FINAL) {
    if (g == 0) {
      float4 o;
      o.x = fmaxf(val.x, 0.f); o.y = fmaxf(val.y, 0.f);
      o.z = fmaxf(val.z, 0.f); o.w = fmaxf(val.w, 0.f);
      *reinterpret_cast<float4*>(&out[(size_t)d * 64 + 4 * l]) = o;
    }
  } else {
    // log-softmax over dims 0..OC-1 (OC=40 = 10 float4 lanes)
    float mx = dimok ? fmaxf(fmaxf(val.x, val.y), fmaxf(val.z, val.w)) : -3e38f;
    mx = fmaxf(mx, __shfl_xor(mx, 1, 64));
    mx = fmaxf(mx, __shfl_xor(mx, 2, 64));
    mx = fmaxf(mx, __shfl_xor(mx, 4, 64));
    mx = fmaxf(mx, __shfl_xor(mx, 8, 64));
    float es = 0.f;
    if (dimok)
      es = __expf(val.x - mx) + __expf(val.y - mx) + __expf(val.z - mx) + __expf(val.w - mx);
    es += __shfl_xor(es, 1, 64);
    es += __shfl_xor(es, 2, 64);
    es += __shfl_xor(es, 4, 64);
    es += __shfl_xor(es, 8, 64);
    const float lse = mx + __logf(es);
    if (g == 0 && dimok) {
      float4 o;
      o.x = val.x - lse; o.y = val.y - lse; o.z = val.z - lse; o.w = val.w - lse;
      *reinterpret_cast<float4*>(&out[(size_t)d * OC + 4 * l]) = o;
    }
  }
}

// ---------------- pass-through edge_index as float (output 1) ----------------
__global__ __launch_bounds__(256) void copy_edges(const int* __restrict__ ei,
                                                  float* __restrict__ out) {
  int i = blockIdx.x * 256 + threadIdx.x;
  if (i < 2 * NE) out[i] = (float)ei[i];
}

// ---------------- launch ----------------
extern "C" void kernel_launch(void* const* d_in, const int* in_sizes, int n_in,
                              void* d_out, int out_size, void* d_ws, size_t ws_size,
                              hipStream_t stream) {
  const float* x     = (const float*)d_in[0];
  const int*   ei    = (const int*)d_in[1];
  const float* W1l   = (const float*)d_in[2];
  const float* b1l   = (const float*)d_in[3];
  const float* W1r   = (const float*)d_in[4];
  const float* b1r   = (const float*)d_in[5];
  const float* att1  = (const float*)d_in[6];
  const float* bias1 = (const float*)d_in[7];
  const float* lin1W = (const float*)d_in[8];
  const float* lin1b = (const float*)d_in[9];
  const float* W2l   = (const float*)d_in[10];
  const float* b2l   = (const float*)d_in[11];
  const float* W2r   = (const float*)d_in[12];
  const float* b2r   = (const float*)d_in[13];
  const float* att2  = (const float*)d_in[14];
  const float* bias2 = (const float*)d_in[15];
  const float* lin2W = (const float*)d_in[16];
  const float* lin2b = (const float*)d_in[17];
  float* out = (float*)d_out;

  char* ws = (char*)d_ws;
  size_t off = 0;
  auto alloc = [&](size_t bytes) -> void* {
    void* p = ws + off;
    off += (bytes + 255) & ~(size_t)255;
    return p;
  };
  float* XL1   = (float*)alloc((size_t)NN * 64 * 4);
  float* XR1   = (float*)alloc((size_t)NN * 64 * 4);
  float* XLIN1 = (float*)alloc((size_t)NN * 64 * 4);
  float* Hb    = (float*)alloc((size_t)NN * 64 * 4);
  float* XL2   = (float*)alloc((size_t)NN * 64 * 4);
  float* XR2   = (float*)alloc((size_t)NN * 64 * 4);
  float* XLIN2 = (float*)alloc((size_t)NN * 64 * 4);
  int* counts  = (int*)alloc((size_t)NN * 4);
  int* partial = (int*)alloc((size_t)NN * 4);
  int* bsums   = (int*)alloc(1024);
  int* offsets = (int*)alloc((size_t)(NN + 1) * 4);
  int* cursor  = (int*)alloc((size_t)NN * 4);
  int* csr     = (int*)alloc((size_t)(NE + NN) * 4);

  const int SB = (NN + 255) / 256;  // 196 blocks (<=256 so scan_top fits)

  init_counts<<<SB, 256, 0, stream>>>(counts);
  count_edges<<<(NE + 255) / 256, 256, 0, stream>>>(ei, counts);
  scan_block<<<SB, 256, 0, stream>>>(counts, partial, bsums);
  scan_top<<<1, 256, 0, stream>>>(bsums, SB);
  scan_final<<<SB, 256, 0, stream>>>(partial, bsums, counts, offsets, cursor);
  fill_csr<<<(NE + NN + 255) / 256, 256, 0, stream>>>(ei, cursor, csr);

  const int GB = (NN + 31) / 32;
  gemm3<256><<<GB, 256, 0, stream>>>(x, W1l, b1l, XL1, W1r, b1r, XR1,
                                     lin1W, lin1b, XLIN1, 64);
  gat_agg<64, false><<<(NN + 3) / 4, 256, 0, stream>>>(XL1, XR1, XLIN1, att1,
                                                       bias1, offsets, csr, Hb);
  gemm3<64><<<GB, 256, 0, stream>>>(Hb, W2l, b2l, XL2, W2r, b2r, XR2,
                                    lin2W, lin2b, XLIN2, 40);
  gat_agg<40, true><<<(NN + 3) / 4, 256, 0, stream>>>(XL2, XR2, XLIN2, att2,
                                                      bias2, offsets, csr, out);
  copy_edges<<<(2 * NE + 255) / 256, 256, 0, stream>>>(ei, out + (size_t)NN * CD);
}

// Round 3
// 393.685 us; speedup vs baseline: 1.6939x; 1.2951x over previous
//
#include <hip/hip_runtime.h>
#include <cmath>

#define NN 50000
#define NP 50048   // NN padded to 64-row multiple (782 * 64)
#define NE 800000
#define CD 40
#define NEG_SLOPE 0.2f

typedef __attribute__((ext_vector_type(8))) short s16x8;   // 8 bf16 (4 VGPRs)
typedef __attribute__((ext_vector_type(4))) float f32x4;   // 4 fp32 acc

// float -> bf16 (RNE), finite inputs
__device__ __forceinline__ short f2bf(float x) {
  unsigned u = __builtin_bit_cast(unsigned, x);
  u += 0x7fffu + ((u >> 16) & 1u);
  return (short)(u >> 16);
}

// ---------------- CSR build ----------------
__global__ __launch_bounds__(256) void init_counts(int* __restrict__ counts) {
  int i = blockIdx.x * 256 + threadIdx.x;
  if (i < NN) counts[i] = 1;  // self-loop pre-count
}

__global__ __launch_bounds__(256) void count_edges(const int* __restrict__ ei,
                                                   int* __restrict__ counts) {
  int i = blockIdx.x * 256 + threadIdx.x;
  if (i < NE) atomicAdd(&counts[ei[NE + i]], 1);
}

__global__ __launch_bounds__(256) void scan_block(const int* __restrict__ in,
                                                  int* __restrict__ partial,
                                                  int* __restrict__ bsums) {
  __shared__ int s[256];
  int i = blockIdx.x * 256 + threadIdx.x;
  int v = (i < NN) ? in[i] : 0;
  s[threadIdx.x] = v;
  __syncthreads();
#pragma unroll
  for (int off = 1; off < 256; off <<= 1) {
    int t = (threadIdx.x >= off) ? s[threadIdx.x - off] : 0;
    __syncthreads();
    s[threadIdx.x] += t;
    __syncthreads();
  }
  if (i < NN) partial[i] = s[threadIdx.x];
  if (threadIdx.x == 255) bsums[blockIdx.x] = s[255];
}

__global__ __launch_bounds__(256) void scan_top(int* __restrict__ bsums, int nb) {
  __shared__ int s[256];
  int v = (threadIdx.x < nb) ? bsums[threadIdx.x] : 0;
  s[threadIdx.x] = v;
  __syncthreads();
#pragma unroll
  for (int off = 1; off < 256; off <<= 1) {
    int t = (threadIdx.x >= off) ? s[threadIdx.x - off] : 0;
    __syncthreads();
    s[threadIdx.x] += t;
    __syncthreads();
  }
  int excl = (threadIdx.x == 0) ? 0 : s[threadIdx.x - 1];
  if (threadIdx.x < nb) bsums[threadIdx.x] = excl;
}

__global__ __launch_bounds__(256) void scan_final(const int* __restrict__ partial,
                                                  const int* __restrict__ bsums,
                                                  const int* __restrict__ counts,
                                                  int* __restrict__ offsets,
                                                  int* __restrict__ cursor) {
  int i = blockIdx.x * 256 + threadIdx.x;
  if (i < NN) {
    int incl = partial[i] + bsums[blockIdx.x];
    offsets[i + 1] = incl;
    cursor[i] = incl - counts[i];
    if (i == 0) offsets[0] = 0;
  }
}

__global__ __launch_bounds__(256) void fill_csr(const int* __restrict__ ei,
                                                int* __restrict__ cursor,
                                                int* __restrict__ csr_src) {
  int i = blockIdx.x * 256 + threadIdx.x;
  if (i < NE + NN) {
    int s, d;
    if (i < NE) { s = ei[i]; d = ei[NE + i]; }
    else        { s = i - NE; d = s; }
    int p = atomicAdd(&cursor[d], 1);
    csr_src[p] = s;
  }
}

// ---------------- X fp32 -> bf16 row-major [NP][256] ----------------
__global__ __launch_bounds__(256) void convert_x(const float* __restrict__ X,
                                                 short* __restrict__ Xb) {
  int i = blockIdx.x * 256 + threadIdx.x;  // octet index
  const int tot = NN * 256 / 8;
  if (i >= tot) return;
  const float4* src = reinterpret_cast<const float4*>(X) + (size_t)i * 2;
  const float4 a = src[0], b = src[1];
  s16x8 o;
  o[0] = f2bf(a.x); o[1] = f2bf(a.y); o[2] = f2bf(a.z); o[3] = f2bf(a.w);
  o[4] = f2bf(b.x); o[5] = f2bf(b.y); o[6] = f2bf(b.z); o[7] = f2bf(b.w);
  *(reinterpret_cast<s16x8*>(Xb) + i) = o;
}

// ---------------- W prep: transpose+convert(+pad) to Wt[wsel][n][K] bf16 ----------------
__global__ __launch_bounds__(256) void prep_w(const float* __restrict__ W1l,
                                              const float* __restrict__ W1r,
                                              const float* __restrict__ L1,
                                              const float* __restrict__ W2l,
                                              const float* __restrict__ W2r,
                                              const float* __restrict__ L2,
                                              short* __restrict__ Wt1,
                                              short* __restrict__ Wt2) {
  int i = blockIdx.x * 256 + threadIdx.x;
  if (i < 3 * 64 * 256) {           // layer 1: K=256, OC=64, src [256][64]
    int w = i / (64 * 256), r = i % (64 * 256), n = r / 256, k = r % 256;
    const float* W = (w == 0) ? W1l : (w == 1) ? W1r : L1;
    Wt1[i] = f2bf(W[k * 64 + n]);
  } else if (i < 3 * 64 * 256 + 3 * 64 * 64) {  // layer 2: K=64, OC=40 pad 64
    int j = i - 3 * 64 * 256;
    int w = j / (64 * 64), r = j % (64 * 64), n = r / 64, k = r % 64;
    const float* W = (w == 0) ? W2l : (w == 1) ? W2r : L2;
    Wt2[j] = (n < 40) ? f2bf(W[k * 40 + n]) : (short)0;
  }
}

// ---------------- bf16 MFMA triple GEMM ----------------
// Block = 4 waves; wave computes rows r0..r0+15 x 192 cols (3 wsel x 64).
// A-frag: lane m=l&15 row, k=q*8+j; B-frag: n=l&15 col, same k; C/D: col=l&15,
// row=q*4+reg (verified layouts, learn_hip m89/m91/m120).
template <int K>
__global__ __launch_bounds__(256) void gemm3_mfma(const short* __restrict__ Xb,
                                                  const short* __restrict__ Wt,
                                                  const float* __restrict__ B0,
                                                  const float* __restrict__ B1,
                                                  const float* __restrict__ B2,
                                                  float* __restrict__ Y0,
                                                  float* __restrict__ Y1,
                                                  float* __restrict__ Y2, int OC) {
  const int lane = threadIdx.x & 63;
  const int wave = threadIdx.x >> 6;
  const int r0 = blockIdx.x * 64 + wave * 16;
  const int m = lane & 15;
  const int q = lane >> 4;
  f32x4 acc[3][4] = {};
  const short* arow = Xb + (size_t)(r0 + m) * K + q * 8;
#pragma unroll
  for (int kb = 0; kb < K; kb += 32) {
    const s16x8 af = *reinterpret_cast<const s16x8*>(arow + kb);
#pragma unroll
    for (int w = 0; w < 3; ++w) {
#pragma unroll
      for (int t = 0; t < 4; ++t) {
        const s16x8 bf = *reinterpret_cast<const s16x8*>(
            Wt + (size_t)(w * 64 + t * 16 + m) * K + kb + q * 8);
        acc[w][t] = __builtin_amdgcn_mfma_f32_16x16x32_bf16(af, bf, acc[w][t], 0, 0, 0);
      }
    }
  }
#pragma unroll
  for (int w = 0; w < 3; ++w) {
    const float* B = (w == 0) ? B0 : (w == 1) ? B1 : B2;
    float* Y = (w == 0) ? Y0 : (w == 1) ? Y1 : Y2;
#pragma unroll
    for (int t = 0; t < 4; ++t) {
      const int c = t * 16 + m;
      const float bv = (c < OC) ? B[c] : 0.f;
#pragma unroll
      for (int rg = 0; rg < 4; ++rg) {
        const int row = r0 + q * 4 + rg;
        if (row < NN) Y[(size_t)row * 64 + c] = acc[w][t][rg] + bv;
      }
    }
  }
}

// ---------------- GATv2 aggregation (16 lanes/edge, 4 edges in flight) ----------------
template <int OC, bool FINAL>
__global__ __launch_bounds__(256) void gat_agg(const float* __restrict__ XL,
                                               const float* __restrict__ XR,
                                               const float* __restrict__ XLIN,
                                               const float* __restrict__ att,
                                               const float* __restrict__ bias,
                                               const int* __restrict__ offsets,
                                               const int* __restrict__ csr,
                                               float* __restrict__ out,
                                               short* __restrict__ outb) {
  const int lane = threadIdx.x & 63;
  const int g = lane >> 4;
  const int l = lane & 15;
  const int d = blockIdx.x * 4 + (threadIdx.x >> 6);
  if (d >= NN) return;
  const bool dimok = (4 * l < OC);
  float4 a4 = make_float4(0.f, 0.f, 0.f, 0.f);
  if (dimok) a4 = *reinterpret_cast<const float4*>(&att[4 * l]);
  const float4 xr4 = *reinterpret_cast<const float4*>(&XR[(size_t)d * 64 + 4 * l]);
  const int beg = offsets[d];
  const int end = offsets[d + 1];
  float m = -1e30f, D = 0.f;
  float4 A = make_float4(0.f, 0.f, 0.f, 0.f);
  const int nit = (end - beg + 3) >> 2;
  for (int it = 0; it < nit; ++it) {
    const int i = beg + it * 4 + g;
    const bool act = (i < end);
    const int s = csr[act ? i : beg];
    const float4 xl = *reinterpret_cast<const float4*>(&XL[(size_t)s * 64 + 4 * l]);
    float4 t;
    t.x = xl.x + xr4.x; t.y = xl.y + xr4.y; t.z = xl.z + xr4.z; t.w = xl.w + xr4.w;
    float4 lr;
    lr.x = fmaxf(t.x, NEG_SLOPE * t.x);
    lr.y = fmaxf(t.y, NEG_SLOPE * t.y);
    lr.z = fmaxf(t.z, NEG_SLOPE * t.z);
    lr.w = fmaxf(t.w, NEG_SLOPE * t.w);
    float p = lr.x * a4.x;
    p = fmaf(lr.y, a4.y, p);
    p = fmaf(lr.z, a4.z, p);
    p = fmaf(lr.w, a4.w, p);
    p += __shfl_xor(p, 1, 64);
    p += __shfl_xor(p, 2, 64);
    p += __shfl_xor(p, 4, 64);
    p += __shfl_xor(p, 8, 64);
    const float e = act ? p : -3e38f;
    const float mn = fmaxf(m, e);
    const float c = __expf(m - mn);
    const float w = __expf(e - mn);
    D = fmaf(D, c, w);
    A.x = fmaf(A.x, c, w * xl.x);
    A.y = fmaf(A.y, c, w * xl.y);
    A.z = fmaf(A.z, c, w * xl.z);
    A.w = fmaf(A.w, c, w * xl.w);
    m = mn;
  }
  float mw = fmaxf(m, __shfl_xor(m, 16, 64));
  mw = fmaxf(mw, __shfl_xor(mw, 32, 64));
  const float sc = __expf(m - mw);
  float Dw = D * sc;
  Dw += __shfl_xor(Dw, 16, 64);
  Dw += __shfl_xor(Dw, 32, 64);
  float4 Aw;
  Aw.x = A.x * sc; Aw.y = A.y * sc; Aw.z = A.z * sc; Aw.w = A.w * sc;
  Aw.x += __shfl_xor(Aw.x, 16, 64); Aw.x += __shfl_xor(Aw.x, 32, 64);
  Aw.y += __shfl_xor(Aw.y, 16, 64); Aw.y += __shfl_xor(Aw.y, 32, 64);
  Aw.z += __shfl_xor(Aw.z, 16, 64); Aw.z += __shfl_xor(Aw.z, 32, 64);
  Aw.w += __shfl_xor(Aw.w, 16, 64); Aw.w += __shfl_xor(Aw.w, 32, 64);
  const float4 xlin = *reinterpret_cast<const float4*>(&XLIN[(size_t)d * 64 + 4 * l]);
  float4 b4 = make_float4(0.f, 0.f, 0.f, 0.f);
  if (dimok) b4 = *reinterpret_cast<const float4*>(&bias[4 * l]);
  const float inv = 1.0f / Dw;
  float4 val;
  val.x = fmaf(Aw.x, inv, b4.x) + xlin.x;
  val.y = fmaf(Aw.y, inv, b4.y) + xlin.y;
  val.z = fmaf(Aw.z, inv, b4.z) + xlin.z;
  val.w = fmaf(Aw.w, inv, b4.w) + xlin.w;
  if (!FINAL) {
    if (g == 0) {  // relu -> bf16 H (consumed only by layer-2 MFMA GEMM)
      const float vx = fmaxf(val.x, 0.f), vy = fmaxf(val.y, 0.f);
      const float vz = fmaxf(val.z, 0.f), vw = fmaxf(val.w, 0.f);
      uint2 o;
      o.x = (unsigned short)f2bf(vx) | ((unsigned)(unsigned short)f2bf(vy) << 16);
      o.y = (unsigned short)f2bf(vz) | ((unsigned)(unsigned short)f2bf(vw) << 16);
      *reinterpret_cast<uint2*>(&outb[(size_t)d * 64 + 4 * l]) = o;
    }
  } else {
    float mx = dimok ? fmaxf(fmaxf(val.x, val.y), fmaxf(val.z, val.w)) : -3e38f;
    mx = fmaxf(mx, __shfl_xor(mx, 1, 64));
    mx = fmaxf(mx, __shfl_xor(mx, 2, 64));
    mx = fmaxf(mx, __shfl_xor(mx, 4, 64));
    mx = fmaxf(mx, __shfl_xor(mx, 8, 64));
    float es = 0.f;
    if (dimok)
      es = __expf(val.x - mx) + __expf(val.y - mx) + __expf(val.z - mx) + __expf(val.w - mx);
    es += __shfl_xor(es, 1, 64);
    es += __shfl_xor(es, 2, 64);
    es += __shfl_xor(es, 4, 64);
    es += __shfl_xor(es, 8, 64);
    const float lse = mx + __logf(es);
    if (g == 0 && dimok) {
      float4 o;
      o.x = val.x - lse; o.y = val.y - lse; o.z = val.z - lse; o.w = val.w - lse;
      *reinterpret_cast<float4*>(&out[(size_t)d * OC + 4 * l]) = o;
    }
  }
}

// ---------------- pass-through edge_index as float (output 1) ----------------
__global__ __launch_bounds__(256) void copy_edges(const int* __restrict__ ei,
                                                  float* __restrict__ out) {
  int i = blockIdx.x * 256 + threadIdx.x;
  if (i < 2 * NE) out[i] = (float)ei[i];
}

// ---------------- launch ----------------
extern "C" void kernel_launch(void* const* d_in, const int* in_sizes, int n_in,
                              void* d_out, int out_size, void* d_ws, size_t ws_size,
                              hipStream_t stream) {
  const float* x     = (const float*)d_in[0];
  const int*   ei    = (const int*)d_in[1];
  const float* W1l   = (const float*)d_in[2];
  const float* b1l   = (const float*)d_in[3];
  const float* W1r   = (const float*)d_in[4];
  const float* b1r   = (const float*)d_in[5];
  const float* att1  = (const float*)d_in[6];
  const float* bias1 = (const float*)d_in[7];
  const float* lin1W = (const float*)d_in[8];
  const float* lin1b = (const float*)d_in[9];
  const float* W2l   = (const float*)d_in[10];
  const float* b2l   = (const float*)d_in[11];
  const float* W2r   = (const float*)d_in[12];
  const float* b2r   = (const float*)d_in[13];
  const float* att2  = (const float*)d_in[14];
  const float* bias2 = (const float*)d_in[15];
  const float* lin2W = (const float*)d_in[16];
  const float* lin2b = (const float*)d_in[17];
  float* out = (float*)d_out;

  char* ws = (char*)d_ws;
  size_t off = 0;
  auto alloc = [&](size_t bytes) -> void* {
    void* p = ws + off;
    off += (bytes + 255) & ~(size_t)255;
    return p;
  };
  short* Xb    = (short*)alloc((size_t)NP * 256 * 2);
  short* Wt1   = (short*)alloc((size_t)3 * 64 * 256 * 2);
  short* Wt2   = (short*)alloc((size_t)3 * 64 * 64 * 2);
  float* XL1   = (float*)alloc((size_t)NN * 64 * 4);
  float* XR1   = (float*)alloc((size_t)NN * 64 * 4);
  float* XLIN1 = (float*)alloc((size_t)NN * 64 * 4);
  short* Hb    = (short*)alloc((size_t)NP * 64 * 2);
  float* XL2   = (float*)alloc((size_t)NN * 64 * 4);
  float* XR2   = (float*)alloc((size_t)NN * 64 * 4);
  float* XLIN2 = (float*)alloc((size_t)NN * 64 * 4);
  int* counts  = (int*)alloc((size_t)NN * 4);
  int* partial = (int*)alloc((size_t)NN * 4);
  int* bsums   = (int*)alloc(1024);
  int* offsets = (int*)alloc((size_t)(NN + 1) * 4);
  int* cursor  = (int*)alloc((size_t)NN * 4);
  int* csr     = (int*)alloc((size_t)(NE + NN) * 4);

  const int SB = (NN + 255) / 256;

  // prep (independent of CSR)
  convert_x<<<(NN * 256 / 8 + 255) / 256, 256, 0, stream>>>(x, Xb);
  prep_w<<<(3 * 64 * 256 + 3 * 64 * 64 + 255) / 256, 256, 0, stream>>>(
      W1l, W1r, lin1W, W2l, W2r, lin2W, Wt1, Wt2);

  // CSR build
  init_counts<<<SB, 256, 0, stream>>>(counts);
  count_edges<<<(NE + 255) / 256, 256, 0, stream>>>(ei, counts);
  scan_block<<<SB, 256, 0, stream>>>(counts, partial, bsums);
  scan_top<<<1, 256, 0, stream>>>(bsums, SB);
  scan_final<<<SB, 256, 0, stream>>>(partial, bsums, counts, offsets, cursor);
  fill_csr<<<(NE + NN + 255) / 256, 256, 0, stream>>>(ei, cursor, csr);

  const int GB = NP / 64;  // 782
  gemm3_mfma<256><<<GB, 256, 0, stream>>>(Xb, Wt1, b1l, b1r, lin1b,
                                          XL1, XR1, XLIN1, 64);
  gat_agg<64, false><<<(NN + 3) / 4, 256, 0, stream>>>(XL1, XR1, XLIN1, att1,
                                                       bias1, offsets, csr,
                                                       nullptr, Hb);
  gemm3_mfma<64><<<GB, 256, 0, stream>>>(Hb, Wt2, b2l, b2r, lin2b,
                                         XL2, XR2, XLIN2, 40);
  gat_agg<40, true><<<(NN + 3) / 4, 256, 0, stream>>>(XL2, XR2, XLIN2, att2,
                                                      bias2, offsets, csr,
                                                      out, nullptr);
  copy_edges<<<(2 * NE + 255) / 256, 256, 0, stream>>>(ei, out + (size_t)NN * CD);
}

// Round 4
// 369.580 us; speedup vs baseline: 1.8044x; 1.0652x over previous
//
#include <hip/hip_runtime.h>
#include <cmath>

#define NN 50000
#define NP 50048   // 391 * 128
#define NE 800000
#define CD 40
#define NEG_SLOPE 0.2f

typedef __attribute__((ext_vector_type(8))) short s16x8;   // 8 bf16
typedef __attribute__((ext_vector_type(4))) float f32x4;   // 4 fp32 acc

__device__ __forceinline__ short f2bf(float x) {  // RNE, finite
  unsigned u = __builtin_bit_cast(unsigned, x);
  u += 0x7fffu + ((u >> 16) & 1u);
  return (short)(u >> 16);
}
__device__ __forceinline__ float bf2f_lo(unsigned v) {
  return __builtin_bit_cast(float, v << 16);
}
__device__ __forceinline__ float bf2f_hi(unsigned v) {
  return __builtin_bit_cast(float, v & 0xffff0000u);
}
// load 4 bf16 (8B) -> float4
__device__ __forceinline__ float4 ldbf4(const unsigned short* p) {
  const uint2 v = *reinterpret_cast<const uint2*>(p);
  return make_float4(bf2f_lo(v.x), bf2f_hi(v.x), bf2f_lo(v.y), bf2f_hi(v.y));
}

// ================= prep: X->bf16, W->packed-frag bf16, counts=1 =================
// Wp layout: [kb][w][t][lane][j]  (frag-contiguous 1KB per (kb,w,t))
#define TA (NN * 256 / 8)
#define TB1 (3 * 64 * 256)
#define TB2 (3 * 64 * 64)
#define TC NN
__global__ __launch_bounds__(256) void prep(const float* __restrict__ X,
                                            short* __restrict__ Xb,
                                            const float* __restrict__ W1l,
                                            const float* __restrict__ W1r,
                                            const float* __restrict__ L1,
                                            const float* __restrict__ W2l,
                                            const float* __restrict__ W2r,
                                            const float* __restrict__ L2,
                                            short* __restrict__ Wp1,
                                            short* __restrict__ Wp2,
                                            int* __restrict__ counts) {
  int i = blockIdx.x * 256 + threadIdx.x;
  if (i < TA) {  // X convert, octet per thread
    const float4* src = reinterpret_cast<const float4*>(X) + (size_t)i * 2;
    const float4 a = src[0], b = src[1];
    s16x8 o;
    o[0] = f2bf(a.x); o[1] = f2bf(a.y); o[2] = f2bf(a.z); o[3] = f2bf(a.w);
    o[4] = f2bf(b.x); o[5] = f2bf(b.y); o[6] = f2bf(b.z); o[7] = f2bf(b.w);
    *(reinterpret_cast<s16x8*>(Xb) + i) = o;
  } else if (i < TA + TB1) {  // layer-1 W pack: K=256, OC=64, src [256][64]
    int e = i - TA;
    int kb = e >> 11; int r = e & 2047;       // e / 6144 wrong -- recompute below
    kb = e / 6144; r = e % 6144;
    int w = r / 2048; int r2 = r % 2048;
    int t = r2 / 512; int r3 = r2 % 512;
    int lane = r3 / 8, j = r3 % 8;
    int n = t * 16 + (lane & 15);
    int k = kb * 32 + (lane >> 4) * 8 + j;
    const float* W = (w == 0) ? W1l : (w == 1) ? W1r : L1;
    Wp1[e] = f2bf(W[k * 64 + n]);
  } else if (i < TA + TB1 + TB2) {  // layer-2 W pack: K=64, OC=40 pad 64
    int e = i - TA - TB1;
    int kb = e / 6144, r = e % 6144;
    int w = r / 2048, r2 = r % 2048;
    int t = r2 / 512, r3 = r2 % 512;
    int lane = r3 / 8, j = r3 % 8;
    int n = t * 16 + (lane & 15);
    int k = kb * 32 + (lane >> 4) * 8 + j;
    const float* W = (w == 0) ? W2l : (w == 1) ? W2r : L2;
    Wp2[e] = (n < 40) ? f2bf(W[k * 40 + n]) : (short)0;
  } else if (i < TA + TB1 + TB2 + TC) {
    counts[i - TA - TB1 - TB2] = 1;  // self-loop pre-count
  }
}

// ============ count dst degrees + pass-through edge_index (output 1) ============
__global__ __launch_bounds__(256) void count_copy(const int* __restrict__ ei,
                                                  int* __restrict__ counts,
                                                  float* __restrict__ outE) {
  int i = blockIdx.x * 256 + threadIdx.x;
  if (i < 2 * NE) {
    const int v = ei[i];
    outE[i] = (float)v;
    if (i >= NE) atomicAdd(&counts[v], 1);
  }
}

// ================= hierarchical exclusive scan (3 dispatches) =================
__global__ __launch_bounds__(256) void scan_block(const int* __restrict__ in,
                                                  int* __restrict__ partial,
                                                  int* __restrict__ bsums) {
  __shared__ int s[256];
  int i = blockIdx.x * 256 + threadIdx.x;
  int v = (i < NN) ? in[i] : 0;
  s[threadIdx.x] = v;
  __syncthreads();
#pragma unroll
  for (int off = 1; off < 256; off <<= 1) {
    int t = (threadIdx.x >= off) ? s[threadIdx.x - off] : 0;
    __syncthreads();
    s[threadIdx.x] += t;
    __syncthreads();
  }
  if (i < NN) partial[i] = s[threadIdx.x];
  if (threadIdx.x == 255) bsums[blockIdx.x] = s[255];
}

__global__ __launch_bounds__(256) void scan_top(int* __restrict__ bsums, int nb) {
  __shared__ int s[256];
  int v = (threadIdx.x < nb) ? bsums[threadIdx.x] : 0;
  s[threadIdx.x] = v;
  __syncthreads();
#pragma unroll
  for (int off = 1; off < 256; off <<= 1) {
    int t = (threadIdx.x >= off) ? s[threadIdx.x - off] : 0;
    __syncthreads();
    s[threadIdx.x] += t;
    __syncthreads();
  }
  int excl = (threadIdx.x == 0) ? 0 : s[threadIdx.x - 1];
  if (threadIdx.x < nb) bsums[threadIdx.x] = excl;
}

__global__ __launch_bounds__(256) void scan_final(const int* __restrict__ partial,
                                                  const int* __restrict__ bsums,
                                                  const int* __restrict__ counts,
                                                  int* __restrict__ offsets,
                                                  int* __restrict__ cursor) {
  int i = blockIdx.x * 256 + threadIdx.x;
  if (i < NN) {
    int incl = partial[i] + bsums[blockIdx.x];
    offsets[i + 1] = incl;
    cursor[i] = incl - counts[i];
    if (i == 0) offsets[0] = 0;
  }
}

__global__ __launch_bounds__(256) void fill_csr(const int* __restrict__ ei,
                                                int* __restrict__ cursor,
                                                int* __restrict__ csr_src) {
  int i = blockIdx.x * 256 + threadIdx.x;
  if (i < NE + NN) {
    int s, d;
    if (i < NE) { s = ei[i]; d = ei[NE + i]; }
    else        { s = i - NE; d = s; }
    int p = atomicAdd(&cursor[d], 1);
    csr_src[p] = s;
  }
}

// ================= bf16 MFMA triple GEMM, fragment-packed B =================
// Block = 4 waves; wave: 32 rows (2 row-tiles) x 192 cols (3 wsel x 64).
// B-frag load = wave-contiguous 1KB. C/D: col=lane&15, row=(lane>>4)*4+reg.
template <int K>
__global__ __launch_bounds__(256, 2) void gemm3_mfma(
    const short* __restrict__ Xb, const short* __restrict__ Wp,
    const float* __restrict__ B0, const float* __restrict__ B1,
    const float* __restrict__ B2, unsigned short* __restrict__ Y0,
    unsigned short* __restrict__ Y1, unsigned short* __restrict__ Y2, int OC) {
  const int lane = threadIdx.x & 63;
  const int wave = threadIdx.x >> 6;
  const int r0 = blockIdx.x * 128 + wave * 32;
  const int m = lane & 15;
  const int q = lane >> 4;
  f32x4 acc[3][4][2] = {};
  const short* a0 = Xb + (size_t)(r0 + m) * K + q * 8;
  const short* a1 = a0 + 16 * K;
  const short* bp = Wp + lane * 8;
#pragma unroll
  for (int kb = 0; kb < K / 32; ++kb) {
    const s16x8 af0 = *reinterpret_cast<const s16x8*>(a0 + kb * 32);
    const s16x8 af1 = *reinterpret_cast<const s16x8*>(a1 + kb * 32);
#pragma unroll
    for (int w = 0; w < 3; ++w) {
#pragma unroll
      for (int t = 0; t < 4; ++t) {
        const s16x8 bf = *reinterpret_cast<const s16x8*>(
            bp + (size_t)((kb * 3 + w) * 4 + t) * 512);
        acc[w][t][0] = __builtin_amdgcn_mfma_f32_16x16x32_bf16(af0, bf, acc[w][t][0], 0, 0, 0);
        acc[w][t][1] = __builtin_amdgcn_mfma_f32_16x16x32_bf16(af1, bf, acc[w][t][1], 0, 0, 0);
      }
    }
  }
#pragma unroll
  for (int w = 0; w < 3; ++w) {
    const float* B = (w == 0) ? B0 : (w == 1) ? B1 : B2;
    unsigned short* Y = (w == 0) ? Y0 : (w == 1) ? Y1 : Y2;
#pragma unroll
    for (int t = 0; t < 4; ++t) {
      const int c = t * 16 + m;
      const float bv = (c < OC) ? B[c] : 0.f;
#pragma unroll
      for (int rt = 0; rt < 2; ++rt) {
#pragma unroll
        for (int rg = 0; rg < 4; ++rg) {
          const int row = r0 + rt * 16 + q * 4 + rg;
          if (row < NN)
            Y[(size_t)row * 64 + c] = (unsigned short)f2bf(acc[w][t][rt][rg] + bv);
        }
      }
    }
  }
}

// ====== GATv2 aggregation: 16 lanes/edge, 4 edges in flight, bf16 inputs ======
template <int OC, bool FINAL>
__global__ __launch_bounds__(256) void gat_agg(const unsigned short* __restrict__ XL,
                                               const unsigned short* __restrict__ XR,
                                               const unsigned short* __restrict__ XLIN,
                                               const float* __restrict__ att,
                                               const float* __restrict__ bias,
                                               const int* __restrict__ offsets,
                                               const int* __restrict__ csr,
                                               float* __restrict__ out,
                                               unsigned short* __restrict__ outb) {
  const int lane = threadIdx.x & 63;
  const int g = lane >> 4;
  const int l = lane & 15;
  const int d = blockIdx.x * 4 + (threadIdx.x >> 6);
  if (d >= NN) return;
  const bool dimok = (4 * l < OC);
  float4 a4 = make_float4(0.f, 0.f, 0.f, 0.f);
  if (dimok) a4 = *reinterpret_cast<const float4*>(&att[4 * l]);
  const float4 xr4 = ldbf4(XR + (size_t)d * 64 + 4 * l);
  const int beg = offsets[d];
  const int end = offsets[d + 1];
  float m = -1e30f, D = 0.f;
  float4 A = make_float4(0.f, 0.f, 0.f, 0.f);
  const int nit = (end - beg + 3) >> 2;
  for (int it = 0; it < nit; ++it) {
    const int i = beg + it * 4 + g;
    const bool act = (i < end);
    const int s = csr[act ? i : beg];
    const float4 xl = ldbf4(XL + (size_t)s * 64 + 4 * l);
    float4 t;
    t.x = xl.x + xr4.x; t.y = xl.y + xr4.y; t.z = xl.z + xr4.z; t.w = xl.w + xr4.w;
    float4 lr;
    lr.x = fmaxf(t.x, NEG_SLOPE * t.x);
    lr.y = fmaxf(t.y, NEG_SLOPE * t.y);
    lr.z = fmaxf(t.z, NEG_SLOPE * t.z);
    lr.w = fmaxf(t.w, NEG_SLOPE * t.w);
    float p = lr.x * a4.x;
    p = fmaf(lr.y, a4.y, p);
    p = fmaf(lr.z, a4.z, p);
    p = fmaf(lr.w, a4.w, p);
    p += __shfl_xor(p, 1, 64);
    p += __shfl_xor(p, 2, 64);
    p += __shfl_xor(p, 4, 64);
    p += __shfl_xor(p, 8, 64);
    const float e = act ? p : -3e38f;
    const float mn = fmaxf(m, e);
    const float c = __expf(m - mn);
    const float w = __expf(e - mn);
    D = fmaf(D, c, w);
    A.x = fmaf(A.x, c, w * xl.x);
    A.y = fmaf(A.y, c, w * xl.y);
    A.z = fmaf(A.z, c, w * xl.z);
    A.w = fmaf(A.w, c, w * xl.w);
    m = mn;
  }
  float mw = fmaxf(m, __shfl_xor(m, 16, 64));
  mw = fmaxf(mw, __shfl_xor(mw, 32, 64));
  const float sc = __expf(m - mw);
  float Dw = D * sc;
  Dw += __shfl_xor(Dw, 16, 64);
  Dw += __shfl_xor(Dw, 32, 64);
  float4 Aw;
  Aw.x = A.x * sc; Aw.y = A.y * sc; Aw.z = A.z * sc; Aw.w = A.w * sc;
  Aw.x += __shfl_xor(Aw.x, 16, 64); Aw.x += __shfl_xor(Aw.x, 32, 64);
  Aw.y += __shfl_xor(Aw.y, 16, 64); Aw.y += __shfl_xor(Aw.y, 32, 64);
  Aw.z += __shfl_xor(Aw.z, 16, 64); Aw.z += __shfl_xor(Aw.z, 32, 64);
  Aw.w += __shfl_xor(Aw.w, 16, 64); Aw.w += __shfl_xor(Aw.w, 32, 64);
  const float4 xlin = ldbf4(XLIN + (size_t)d * 64 + 4 * l);
  float4 b4 = make_float4(0.f, 0.f, 0.f, 0.f);
  if (dimok) b4 = *reinterpret_cast<const float4*>(&bias[4 * l]);
  const float inv = 1.0f / Dw;
  float4 val;
  val.x = fmaf(Aw.x, inv, b4.x) + xlin.x;
  val.y = fmaf(Aw.y, inv, b4.y) + xlin.y;
  val.z = fmaf(Aw.z, inv, b4.z) + xlin.z;
  val.w = fmaf(Aw.w, inv, b4.w) + xlin.w;
  if (!FINAL) {
    if (g == 0) {  // relu -> bf16 H
      uint2 o;
      o.x = (unsigned short)f2bf(fmaxf(val.x, 0.f)) |
            ((unsigned)(unsigned short)f2bf(fmaxf(val.y, 0.f)) << 16);
      o.y = (unsigned short)f2bf(fmaxf(val.z, 0.f)) |
            ((unsigned)(unsigned short)f2bf(fmaxf(val.w, 0.f)) << 16);
      *reinterpret_cast<uint2*>(&outb[(size_t)d * 64 + 4 * l]) = o;
    }
  } else {
    float mx = dimok ? fmaxf(fmaxf(val.x, val.y), fmaxf(val.z, val.w)) : -3e38f;
    mx = fmaxf(mx, __shfl_xor(mx, 1, 64));
    mx = fmaxf(mx, __shfl_xor(mx, 2, 64));
    mx = fmaxf(mx, __shfl_xor(mx, 4, 64));
    mx = fmaxf(mx, __shfl_xor(mx, 8, 64));
    float es = 0.f;
    if (dimok)
      es = __expf(val.x - mx) + __expf(val.y - mx) + __expf(val.z - mx) + __expf(val.w - mx);
    es += __shfl_xor(es, 1, 64);
    es += __shfl_xor(es, 2, 64);
    es += __shfl_xor(es, 4, 64);
    es += __shfl_xor(es, 8, 64);
    const float lse = mx + __logf(es);
    if (g == 0 && dimok) {
      float4 o;
      o.x = val.x - lse; o.y = val.y - lse; o.z = val.z - lse; o.w = val.w - lse;
      *reinterpret_cast<float4*>(&out[(size_t)d * OC + 4 * l]) = o;
    }
  }
}

// ---------------- launch ----------------
extern "C" void kernel_launch(void* const* d_in, const int* in_sizes, int n_in,
                              void* d_out, int out_size, void* d_ws, size_t ws_size,
                              hipStream_t stream) {
  const float* x     = (const float*)d_in[0];
  const int*   ei    = (const int*)d_in[1];
  const float* W1l   = (const float*)d_in[2];
  const float* b1l   = (const float*)d_in[3];
  const float* W1r   = (const float*)d_in[4];
  const float* b1r   = (const float*)d_in[5];
  const float* att1  = (const float*)d_in[6];
  const float* bias1 = (const float*)d_in[7];
  const float* lin1W = (const float*)d_in[8];
  const float* lin1b = (const float*)d_in[9];
  const float* W2l   = (const float*)d_in[10];
  const float* b2l   = (const float*)d_in[11];
  const float* W2r   = (const float*)d_in[12];
  const float* b2r   = (const float*)d_in[13];
  const float* att2  = (const float*)d_in[14];
  const float* bias2 = (const float*)d_in[15];
  const float* lin2W = (const float*)d_in[16];
  const float* lin2b = (const float*)d_in[17];
  float* out = (float*)d_out;

  char* ws = (char*)d_ws;
  size_t off = 0;
  auto alloc = [&](size_t bytes) -> void* {
    void* p = ws + off;
    off += (bytes + 255) & ~(size_t)255;
    return p;
  };
  short* Xb  = (short*)alloc((size_t)NP * 256 * 2);
  short* Wp1 = (short*)alloc((size_t)TB1 * 2);
  short* Wp2 = (short*)alloc((size_t)TB2 * 2);
  unsigned short* XL1   = (unsigned short*)alloc((size_t)NN * 64 * 2);
  unsigned short* XR1   = (unsigned short*)alloc((size_t)NN * 64 * 2);
  unsigned short* XLIN1 = (unsigned short*)alloc((size_t)NN * 64 * 2);
  unsigned short* Hb    = (unsigned short*)alloc((size_t)NP * 64 * 2);
  unsigned short* XL2   = (unsigned short*)alloc((size_t)NN * 64 * 2);
  unsigned short* XR2   = (unsigned short*)alloc((size_t)NN * 64 * 2);
  unsigned short* XLIN2 = (unsigned short*)alloc((size_t)NN * 64 * 2);
  int* counts  = (int*)alloc((size_t)NN * 4);
  int* partial = (int*)alloc((size_t)NN * 4);
  int* bsums   = (int*)alloc(1024);
  int* offsets = (int*)alloc((size_t)(NN + 1) * 4);
  int* cursor  = (int*)alloc((size_t)NN * 4);
  int* csr     = (int*)alloc((size_t)(NE + NN) * 4);

  const int SB = (NN + 255) / 256;
  const int PT = TA + TB1 + TB2 + TC;

  prep<<<(PT + 255) / 256, 256, 0, stream>>>(x, Xb, W1l, W1r, lin1W, W2l, W2r,
                                             lin2W, Wp1, Wp2, counts);
  count_copy<<<(2 * NE + 255) / 256, 256, 0, stream>>>(ei, counts,
                                                       out + (size_t)NN * CD);
  scan_block<<<SB, 256, 0, stream>>>(counts, partial, bsums);
  scan_top<<<1, 256, 0, stream>>>(bsums, SB);
  scan_final<<<SB, 256, 0, stream>>>(partial, bsums, counts, offsets, cursor);
  fill_csr<<<(NE + NN + 255) / 256, 256, 0, stream>>>(ei, cursor, csr);

  const int GB = NP / 128;  // 391
  gemm3_mfma<256><<<GB, 256, 0, stream>>>(Xb, Wp1, b1l, b1r, lin1b,
                                          XL1, XR1, XLIN1, 64);
  gat_agg<64, false><<<(NN + 3) / 4, 256, 0, stream>>>(XL1, XR1, XLIN1, att1,
                                                       bias1, offsets, csr,
                                                       nullptr, Hb);
  gemm3_mfma<64><<<GB, 256, 0, stream>>>((const short*)Hb, Wp2, b2l, b2r, lin2b,
                                         XL2, XR2, XLIN2, 40);
  gat_agg<40, true><<<(NN + 3) / 4, 256, 0, stream>>>(XL2, XR2, XLIN2, att2,
                                                      bias2, offsets, csr,
                                                      out, nullptr);
}

// Round 5
// 343.351 us; speedup vs baseline: 1.9423x; 1.0764x over previous
//
#include <hip/hip_runtime.h>
#include <cmath>

#define NN 50000
#define NP 50048   // 391 * 128
#define NE 800000
#define CD 40
#define NEG_SLOPE 0.2f
#define NITEMS (NE + NN)   // edges + self-loops
#define CHUNK 2048
#define NBKT 391           // dst >> 7 buckets (50000/128)

typedef __attribute__((ext_vector_type(8))) short s16x8;   // 8 bf16
typedef __attribute__((ext_vector_type(4))) float f32x4;   // 4 fp32 acc

__device__ __forceinline__ short f2bf(float x) {  // RNE, finite
  unsigned u = __builtin_bit_cast(unsigned, x);
  u += 0x7fffu + ((u >> 16) & 1u);
  return (short)(u >> 16);
}
__device__ __forceinline__ float bf2f_lo(unsigned v) {
  return __builtin_bit_cast(float, v << 16);
}
__device__ __forceinline__ float bf2f_hi(unsigned v) {
  return __builtin_bit_cast(float, v & 0xffff0000u);
}
__device__ __forceinline__ float4 ldbf4(const unsigned short* p) {
  const uint2 v = *reinterpret_cast<const uint2*>(p);
  return make_float4(bf2f_lo(v.x), bf2f_hi(v.x), bf2f_lo(v.y), bf2f_hi(v.y));
}

// ================= prep: X->bf16, W->packed-frag bf16, counts=1 =================
#define TA (NN * 256 / 8)
#define TB1 (3 * 64 * 256)
#define TB2 (3 * 64 * 64)
#define TC NN
__global__ __launch_bounds__(256) void prep(const float* __restrict__ X,
                                            short* __restrict__ Xb,
                                            const float* __restrict__ W1l,
                                            const float* __restrict__ W1r,
                                            const float* __restrict__ L1,
                                            const float* __restrict__ W2l,
                                            const float* __restrict__ W2r,
                                            const float* __restrict__ L2,
                                            short* __restrict__ Wp1,
                                            short* __restrict__ Wp2,
                                            int* __restrict__ counts) {
  int i = blockIdx.x * 256 + threadIdx.x;
  if (i < TA) {  // X convert, octet per thread
    const float4* src = reinterpret_cast<const float4*>(X) + (size_t)i * 2;
    const float4 a = src[0], b = src[1];
    s16x8 o;
    o[0] = f2bf(a.x); o[1] = f2bf(a.y); o[2] = f2bf(a.z); o[3] = f2bf(a.w);
    o[4] = f2bf(b.x); o[5] = f2bf(b.y); o[6] = f2bf(b.z); o[7] = f2bf(b.w);
    *(reinterpret_cast<s16x8*>(Xb) + i) = o;
  } else if (i < TA + TB1) {  // layer-1 W pack: [kb][w][t][lane][j], src [256][64]
    int e = i - TA;
    int kb = e / 6144, r = e % 6144;
    int w = r / 2048, r2 = r % 2048;
    int t = r2 / 512, r3 = r2 % 512;
    int lane = r3 / 8, j = r3 % 8;
    int n = t * 16 + (lane & 15);
    int k = kb * 32 + (lane >> 4) * 8 + j;
    const float* W = (w == 0) ? W1l : (w == 1) ? W1r : L1;
    Wp1[e] = f2bf(W[k * 64 + n]);
  } else if (i < TA + TB1 + TB2) {  // layer-2 W pack: K=64, OC=40 pad 64
    int e = i - TA - TB1;
    int kb = e / 6144, r = e % 6144;
    int w = r / 2048, r2 = r % 2048;
    int t = r2 / 512, r3 = r2 % 512;
    int lane = r3 / 8, j = r3 % 8;
    int n = t * 16 + (lane & 15);
    int k = kb * 32 + (lane >> 4) * 8 + j;
    const float* W = (w == 0) ? W2l : (w == 1) ? W2r : L2;
    Wp2[e] = (n < 40) ? f2bf(W[k * 40 + n]) : (short)0;
  } else if (i < TA + TB1 + TB2 + TC) {
    counts[i - TA - TB1 - TB2] = 1;  // self-loop pre-count
  }
}

// ================= count dst degrees (dst half only) =================
__global__ __launch_bounds__(256) void count_dst(const int* __restrict__ ei,
                                                 int* __restrict__ counts) {
  int i = blockIdx.x * 256 + threadIdx.x;
  if (i < NE) atomicAdd(&counts[ei[NE + i]], 1);
}

// ================= scan =================
__global__ __launch_bounds__(256) void scan_block(const int* __restrict__ in,
                                                  int* __restrict__ partial,
                                                  int* __restrict__ bsums) {
  __shared__ int s[256];
  int i = blockIdx.x * 256 + threadIdx.x;
  int v = (i < NN) ? in[i] : 0;
  s[threadIdx.x] = v;
  __syncthreads();
#pragma unroll
  for (int off = 1; off < 256; off <<= 1) {
    int t = (threadIdx.x >= off) ? s[threadIdx.x - off] : 0;
    __syncthreads();
    s[threadIdx.x] += t;
    __syncthreads();
  }
  if (i < NN) partial[i] = s[threadIdx.x];
  if (threadIdx.x == 255) bsums[blockIdx.x] = s[255];
}

// per-block base = sum of bsums below this block (196 values, LDS reduce)
__global__ __launch_bounds__(256) void scan_final(const int* __restrict__ partial,
                                                  const int* __restrict__ bsums,
                                                  const int* __restrict__ counts,
                                                  int* __restrict__ offsets,
                                                  int* __restrict__ cursor, int nb) {
  __shared__ int red[256];
  const int t = threadIdx.x;
  red[t] = (t < nb && t < (int)blockIdx.x) ? bsums[t] : 0;
  __syncthreads();
#pragma unroll
  for (int off = 128; off >= 1; off >>= 1) {
    if (t < off) red[t] += red[t + off];
    __syncthreads();
  }
  const int base = red[0];
  int i = blockIdx.x * 256 + t;
  if (i < NN) {
    int incl = partial[i] + base;
    offsets[i + 1] = incl;
    cursor[i] = incl - counts[i];
    if (i == 0) offsets[0] = 0;
  }
}

// ====== LDS-binned CSR fill (+ fused edge_index pass-through, output 1) ======
// Block sorts a 2048-item chunk by dst>>7 in LDS, then scatters bucket-by-
// bucket so consecutive lanes write within a ~4KB csr region (L2-coalesced).
__global__ __launch_bounds__(256) void fill_binned(const int* __restrict__ ei,
                                                   int* __restrict__ cursor,
                                                   unsigned short* __restrict__ csr16,
                                                   float* __restrict__ outE) {
  __shared__ unsigned sorted[CHUNK];
  __shared__ int hist[512];
  __shared__ int bcur[512];
  const int tid = threadIdx.x;
  const int base = blockIdx.x * CHUNK;
  for (int t = tid; t < 512; t += 256) { hist[t] = 0; bcur[t] = 0; }
  __syncthreads();
  unsigned key[CHUNK / 256];
#pragma unroll
  for (int u = 0; u < CHUNK / 256; ++u) {
    const int j = base + u * 256 + tid;  // coalesced
    unsigned k = 0xFFFFFFFFu;
    if (j < NITEMS) {
      int s, d;
      if (j < NE) {
        s = ei[j]; d = ei[NE + j];
        outE[j] = (float)s; outE[NE + j] = (float)d;
      } else {
        s = j - NE; d = s;
      }
      k = ((unsigned)d << 16) | (unsigned)s;
      atomicAdd(&hist[k >> 23], 1);  // bucket = d >> 7
    }
    key[u] = k;
  }
  __syncthreads();
  // exclusive scan of hist[0..511] by one wave (8 x 64 shfl scan)
  if (tid < 64) {
    int carry = 0;
#pragma unroll
    for (int c = 0; c < 8; ++c) {
      int v = hist[c * 64 + tid];
      int inc = v;
#pragma unroll
      for (int off = 1; off < 64; off <<= 1) {
        int tt = __shfl_up(inc, off, 64);
        if (tid >= off) inc += tt;
      }
      hist[c * 64 + tid] = carry + inc - v;  // exclusive
      carry += __shfl(inc, 63, 64);
    }
  }
  __syncthreads();
  // place keys into LDS sorted by bucket
#pragma unroll
  for (int u = 0; u < CHUNK / 256; ++u) {
    const unsigned k = key[u];
    if (k != 0xFFFFFFFFu) {
      const int b = k >> 23;
      const int pos = hist[b] + atomicAdd(&bcur[b], 1);
      sorted[pos] = k;
    }
  }
  __syncthreads();
  // scatter: consecutive lanes -> same bucket -> localized csr writes
  const int cnt = min(CHUNK, NITEMS - base);
  for (int t = tid; t < cnt; t += 256) {
    const unsigned k = sorted[t];
    const int d = k >> 16;
    const int p = atomicAdd(&cursor[d], 1);
    csr16[p] = (unsigned short)(k & 0xFFFFu);
  }
}

// ================= bf16 MFMA triple GEMM, fragment-packed B =================
template <int K>
__global__ __launch_bounds__(256, 2) void gemm3_mfma(
    const short* __restrict__ Xb, const short* __restrict__ Wp,
    const float* __restrict__ B0, const float* __restrict__ B1,
    const float* __restrict__ B2, unsigned short* __restrict__ Y0,
    unsigned short* __restrict__ Y1, unsigned short* __restrict__ Y2, int OC) {
  const int lane = threadIdx.x & 63;
  const int wave = threadIdx.x >> 6;
  const int r0 = blockIdx.x * 128 + wave * 32;
  const int m = lane & 15;
  const int q = lane >> 4;
  f32x4 acc[3][4][2] = {};
  const short* a0 = Xb + (size_t)(r0 + m) * K + q * 8;
  const short* a1 = a0 + 16 * K;
  const short* bp = Wp + lane * 8;
#pragma unroll
  for (int kb = 0; kb < K / 32; ++kb) {
    const s16x8 af0 = *reinterpret_cast<const s16x8*>(a0 + kb * 32);
    const s16x8 af1 = *reinterpret_cast<const s16x8*>(a1 + kb * 32);
#pragma unroll
    for (int w = 0; w < 3; ++w) {
#pragma unroll
      for (int t = 0; t < 4; ++t) {
        const s16x8 bf = *reinterpret_cast<const s16x8*>(
            bp + (size_t)((kb * 3 + w) * 4 + t) * 512);
        acc[w][t][0] = __builtin_amdgcn_mfma_f32_16x16x32_bf16(af0, bf, acc[w][t][0], 0, 0, 0);
        acc[w][t][1] = __builtin_amdgcn_mfma_f32_16x16x32_bf16(af1, bf, acc[w][t][1], 0, 0, 0);
      }
    }
  }
#pragma unroll
  for (int w = 0; w < 3; ++w) {
    const float* B = (w == 0) ? B0 : (w == 1) ? B1 : B2;
    unsigned short* Y = (w == 0) ? Y0 : (w == 1) ? Y1 : Y2;
#pragma unroll
    for (int t = 0; t < 4; ++t) {
      const int c = t * 16 + m;
      const float bv = (c < OC) ? B[c] : 0.f;
#pragma unroll
      for (int rt = 0; rt < 2; ++rt) {
#pragma unroll
        for (int rg = 0; rg < 4; ++rg) {
          const int row = r0 + rt * 16 + q * 4 + rg;
          if (row < NN)
            Y[(size_t)row * 64 + c] = (unsigned short)f2bf(acc[w][t][rt][rg] + bv);
        }
      }
    }
  }
}

// ====== GATv2 aggregation: 16 lanes/edge, 4 edges in flight, csr prefetch ======
template <int OC, bool FINAL>
__global__ __launch_bounds__(256) void gat_agg(const unsigned short* __restrict__ XL,
                                               const unsigned short* __restrict__ XR,
                                               const unsigned short* __restrict__ XLIN,
                                               const float* __restrict__ att,
                                               const float* __restrict__ bias,
                                               const int* __restrict__ offsets,
                                               const unsigned short* __restrict__ csr,
                                               float* __restrict__ out,
                                               unsigned short* __restrict__ outb) {
  const int lane = threadIdx.x & 63;
  const int g = lane >> 4;
  const int l = lane & 15;
  const int d = blockIdx.x * 4 + (threadIdx.x >> 6);
  if (d >= NN) return;
  const bool dimok = (4 * l < OC);
  float4 a4 = make_float4(0.f, 0.f, 0.f, 0.f);
  if (dimok) a4 = *reinterpret_cast<const float4*>(&att[4 * l]);
  const float4 xr4 = ldbf4(XR + (size_t)d * 64 + 4 * l);
  const int beg = offsets[d];
  const int end = offsets[d + 1];
  float m = -1e30f, D = 0.f;
  float4 A = make_float4(0.f, 0.f, 0.f, 0.f);
  const int nit = (end - beg + 3) >> 2;
  const int i0 = beg + g;
  int sa = (int)csr[(i0 < end) ? i0 : beg];  // stage-0 src index
  for (int it = 0; it < nit; ++it) {
    const int icur = beg + it * 4 + g;
    const bool act = (icur < end);
    const float4 xl = ldbf4(XL + (size_t)sa * 64 + 4 * l);  // uses prefetched sa
    const int inext = icur + 4;
    sa = (int)csr[(inext < end) ? inext : beg];  // prefetch next iteration
    float4 t;
    t.x = xl.x + xr4.x; t.y = xl.y + xr4.y; t.z = xl.z + xr4.z; t.w = xl.w + xr4.w;
    float4 lr;
    lr.x = fmaxf(t.x, NEG_SLOPE * t.x);
    lr.y = fmaxf(t.y, NEG_SLOPE * t.y);
    lr.z = fmaxf(t.z, NEG_SLOPE * t.z);
    lr.w = fmaxf(t.w, NEG_SLOPE * t.w);
    float p = lr.x * a4.x;
    p = fmaf(lr.y, a4.y, p);
    p = fmaf(lr.z, a4.z, p);
    p = fmaf(lr.w, a4.w, p);
    p += __shfl_xor(p, 1, 64);
    p += __shfl_xor(p, 2, 64);
    p += __shfl_xor(p, 4, 64);
    p += __shfl_xor(p, 8, 64);
    const float e = act ? p : -3e38f;
    const float mn = fmaxf(m, e);
    const float c = __expf(m - mn);
    const float w = __expf(e - mn);
    D = fmaf(D, c, w);
    A.x = fmaf(A.x, c, w * xl.x);
    A.y = fmaf(A.y, c, w * xl.y);
    A.z = fmaf(A.z, c, w * xl.z);
    A.w = fmaf(A.w, c, w * xl.w);
    m = mn;
  }
  float mw = fmaxf(m, __shfl_xor(m, 16, 64));
  mw = fmaxf(mw, __shfl_xor(mw, 32, 64));
  const float sc = __expf(m - mw);
  float Dw = D * sc;
  Dw += __shfl_xor(Dw, 16, 64);
  Dw += __shfl_xor(Dw, 32, 64);
  float4 Aw;
  Aw.x = A.x * sc; Aw.y = A.y * sc; Aw.z = A.z * sc; Aw.w = A.w * sc;
  Aw.x += __shfl_xor(Aw.x, 16, 64); Aw.x += __shfl_xor(Aw.x, 32, 64);
  Aw.y += __shfl_xor(Aw.y, 16, 64); Aw.y += __shfl_xor(Aw.y, 32, 64);
  Aw.z += __shfl_xor(Aw.z, 16, 64); Aw.z += __shfl_xor(Aw.z, 32, 64);
  Aw.w += __shfl_xor(Aw.w, 16, 64); Aw.w += __shfl_xor(Aw.w, 32, 64);
  const float4 xlin = ldbf4(XLIN + (size_t)d * 64 + 4 * l);
  float4 b4 = make_float4(0.f, 0.f, 0.f, 0.f);
  if (dimok) b4 = *reinterpret_cast<const float4*>(&bias[4 * l]);
  const float inv = 1.0f / Dw;
  float4 val;
  val.x = fmaf(Aw.x, inv, b4.x) + xlin.x;
  val.y = fmaf(Aw.y, inv, b4.y) + xlin.y;
  val.z = fmaf(Aw.z, inv, b4.z) + xlin.z;
  val.w = fmaf(Aw.w, inv, b4.w) + xlin.w;
  if (!FINAL) {
    if (g == 0) {  // relu -> bf16 H
      uint2 o;
      o.x = (unsigned short)f2bf(fmaxf(val.x, 0.f)) |
            ((unsigned)(unsigned short)f2bf(fmaxf(val.y, 0.f)) << 16);
      o.y = (unsigned short)f2bf(fmaxf(val.z, 0.f)) |
            ((unsigned)(unsigned short)f2bf(fmaxf(val.w, 0.f)) << 16);
      *reinterpret_cast<uint2*>(&outb[(size_t)d * 64 + 4 * l]) = o;
    }
  } else {
    float mx = dimok ? fmaxf(fmaxf(val.x, val.y), fmaxf(val.z, val.w)) : -3e38f;
    mx = fmaxf(mx, __shfl_xor(mx, 1, 64));
    mx = fmaxf(mx, __shfl_xor(mx, 2, 64));
    mx = fmaxf(mx, __shfl_xor(mx, 4, 64));
    mx = fmaxf(mx, __shfl_xor(mx, 8, 64));
    float es = 0.f;
    if (dimok)
      es = __expf(val.x - mx) + __expf(val.y - mx) + __expf(val.z - mx) + __expf(val.w - mx);
    es += __shfl_xor(es, 1, 64);
    es += __shfl_xor(es, 2, 64);
    es += __shfl_xor(es, 4, 64);
    es += __shfl_xor(es, 8, 64);
    const float lse = mx + __logf(es);
    if (g == 0 && dimok) {
      float4 o;
      o.x = val.x - lse; o.y = val.y - lse; o.z = val.z - lse; o.w = val.w - lse;
      *reinterpret_cast<float4*>(&out[(size_t)d * OC + 4 * l]) = o;
    }
  }
}

// ---------------- launch ----------------
extern "C" void kernel_launch(void* const* d_in, const int* in_sizes, int n_in,
                              void* d_out, int out_size, void* d_ws, size_t ws_size,
                              hipStream_t stream) {
  const float* x     = (const float*)d_in[0];
  const int*   ei    = (const int*)d_in[1];
  const float* W1l   = (const float*)d_in[2];
  const float* b1l   = (const float*)d_in[3];
  const float* W1r   = (const float*)d_in[4];
  const float* b1r   = (const float*)d_in[5];
  const float* att1  = (const float*)d_in[6];
  const float* bias1 = (const float*)d_in[7];
  const float* lin1W = (const float*)d_in[8];
  const float* lin1b = (const float*)d_in[9];
  const float* W2l   = (const float*)d_in[10];
  const float* b2l   = (const float*)d_in[11];
  const float* W2r   = (const float*)d_in[12];
  const float* b2r   = (const float*)d_in[13];
  const float* att2  = (const float*)d_in[14];
  const float* bias2 = (const float*)d_in[15];
  const float* lin2W = (const float*)d_in[16];
  const float* lin2b = (const float*)d_in[17];
  float* out = (float*)d_out;

  char* ws = (char*)d_ws;
  size_t off = 0;
  auto alloc = [&](size_t bytes) -> void* {
    void* p = ws + off;
    off += (bytes + 255) & ~(size_t)255;
    return p;
  };
  short* Xb  = (short*)alloc((size_t)NP * 256 * 2);
  short* Wp1 = (short*)alloc((size_t)TB1 * 2);
  short* Wp2 = (short*)alloc((size_t)TB2 * 2);
  unsigned short* XL1   = (unsigned short*)alloc((size_t)NN * 64 * 2);
  unsigned short* XR1   = (unsigned short*)alloc((size_t)NN * 64 * 2);
  unsigned short* XLIN1 = (unsigned short*)alloc((size_t)NN * 64 * 2);
  unsigned short* Hb    = (unsigned short*)alloc((size_t)NP * 64 * 2);
  unsigned short* XL2   = (unsigned short*)alloc((size_t)NN * 64 * 2);
  unsigned short* XR2   = (unsigned short*)alloc((size_t)NN * 64 * 2);
  unsigned short* XLIN2 = (unsigned short*)alloc((size_t)NN * 64 * 2);
  int* counts  = (int*)alloc((size_t)NN * 4);
  int* partial = (int*)alloc((size_t)NN * 4);
  int* bsums   = (int*)alloc(1024);
  int* offsets = (int*)alloc((size_t)(NN + 1) * 4);
  int* cursor  = (int*)alloc((size_t)NN * 4);
  unsigned short* csr = (unsigned short*)alloc((size_t)NITEMS * 2);

  const int SB = (NN + 255) / 256;  // 196
  const int PT = TA + TB1 + TB2 + TC;

  prep<<<(PT + 255) / 256, 256, 0, stream>>>(x, Xb, W1l, W1r, lin1W, W2l, W2r,
                                             lin2W, Wp1, Wp2, counts);
  count_dst<<<(NE + 255) / 256, 256, 0, stream>>>(ei, counts);
  scan_block<<<SB, 256, 0, stream>>>(counts, partial, bsums);
  scan_final<<<SB, 256, 0, stream>>>(partial, bsums, counts, offsets, cursor, SB);
  fill_binned<<<(NITEMS + CHUNK - 1) / CHUNK, 256, 0, stream>>>(
      ei, cursor, csr, out + (size_t)NN * CD);

  const int GB = NP / 128;  // 391
  gemm3_mfma<256><<<GB, 256, 0, stream>>>(Xb, Wp1, b1l, b1r, lin1b,
                                          XL1, XR1, XLIN1, 64);
  gat_agg<64, false><<<(NN + 3) / 4, 256, 0, stream>>>(XL1, XR1, XLIN1, att1,
                                                       bias1, offsets, csr,
                                                       nullptr, Hb);
  gemm3_mfma<64><<<GB, 256, 0, stream>>>((const short*)Hb, Wp2, b2l, b2r, lin2b,
                                         XL2, XR2, XLIN2, 40);
  gat_agg<40, true><<<(NN + 3) / 4, 256, 0, stream>>>(XL2, XR2, XLIN2, att2,
                                                      bias2, offsets, csr,
                                                      out, nullptr);
}

// Round 6
// 325.348 us; speedup vs baseline: 2.0497x; 1.0553x over previous
//
#include <hip/hip_runtime.h>
#include <cmath>

#define NN 50000
#define NP 50048   // 391 * 128
#define NE 800000
#define CD 40
#define NEG_SLOPE 0.2f
#define NITEMS (NE + NN)   // edges + self-loops
#define CHUNK 2048
#define SB 196             // scan blocks (ceil(NN/256))
#define GB 391             // gemm blocks (NP/128)

typedef __attribute__((ext_vector_type(8))) short s16x8;   // 8 bf16
typedef __attribute__((ext_vector_type(4))) float f32x4;   // 4 fp32 acc

__device__ __forceinline__ short f2bf(float x) {  // RNE, finite
  unsigned u = __builtin_bit_cast(unsigned, x);
  u += 0x7fffu + ((u >> 16) & 1u);
  return (short)(u >> 16);
}
__device__ __forceinline__ unsigned pack2(float lo, float hi) {
  return (unsigned)(unsigned short)f2bf(lo) | ((unsigned)(unsigned short)f2bf(hi) << 16);
}
__device__ __forceinline__ float bf2f_lo(unsigned v) {
  return __builtin_bit_cast(float, v << 16);
}
__device__ __forceinline__ float bf2f_hi(unsigned v) {
  return __builtin_bit_cast(float, v & 0xffff0000u);
}
// load 8 bf16 (16B) -> 8 floats
__device__ __forceinline__ void ldbf8(const unsigned short* p, float* f) {
  const uint4 v = *reinterpret_cast<const uint4*>(p);
  f[0] = bf2f_lo(v.x); f[1] = bf2f_hi(v.x);
  f[2] = bf2f_lo(v.y); f[3] = bf2f_hi(v.y);
  f[4] = bf2f_lo(v.z); f[5] = bf2f_hi(v.z);
  f[6] = bf2f_lo(v.w); f[7] = bf2f_hi(v.w);
}

// ========== mega_prep: X->bf16 | W->frag-pack | dst-degree count ==========
#define TA (NN * 256 / 8)
#define TB1 (3 * 64 * 256)
#define TB2 (3 * 64 * 64)
#define TCNT NE
__global__ __launch_bounds__(256) void mega_prep(const float* __restrict__ X,
                                                 short* __restrict__ Xb,
                                                 const float* __restrict__ W1l,
                                                 const float* __restrict__ W1r,
                                                 const float* __restrict__ L1,
                                                 const float* __restrict__ W2l,
                                                 const float* __restrict__ W2r,
                                                 const float* __restrict__ L2,
                                                 short* __restrict__ Wp1,
                                                 short* __restrict__ Wp2,
                                                 const int* __restrict__ ei,
                                                 int* __restrict__ counts) {
  int i = blockIdx.x * 256 + threadIdx.x;
  if (i < TA) {  // X convert, octet per thread
    const float4* src = reinterpret_cast<const float4*>(X) + (size_t)i * 2;
    const float4 a = src[0], b = src[1];
    s16x8 o;
    o[0] = f2bf(a.x); o[1] = f2bf(a.y); o[2] = f2bf(a.z); o[3] = f2bf(a.w);
    o[4] = f2bf(b.x); o[5] = f2bf(b.y); o[6] = f2bf(b.z); o[7] = f2bf(b.w);
    *(reinterpret_cast<s16x8*>(Xb) + i) = o;
  } else if (i < TA + TB1) {  // layer-1 W pack: [kb][w][t][lane][j], src [256][64]
    int e = i - TA;
    int kb = e / 6144, r = e % 6144;
    int w = r / 2048, r2 = r % 2048;
    int t = r2 / 512, r3 = r2 % 512;
    int lane = r3 / 8, j = r3 % 8;
    int n = t * 16 + (lane & 15);
    int k = kb * 32 + (lane >> 4) * 8 + j;
    const float* W = (w == 0) ? W1l : (w == 1) ? W1r : L1;
    Wp1[e] = f2bf(W[k * 64 + n]);
  } else if (i < TA + TB1 + TB2) {  // layer-2 W pack: K=64, OC=40 pad 64
    int e = i - TA - TB1;
    int kb = e / 6144, r = e % 6144;
    int w = r / 2048, r2 = r % 2048;
    int t = r2 / 512, r3 = r2 % 512;
    int lane = r3 / 8, j = r3 % 8;
    int n = t * 16 + (lane & 15);
    int k = kb * 32 + (lane >> 4) * 8 + j;
    const float* W = (w == 0) ? W2l : (w == 1) ? W2r : L2;
    Wp2[e] = (n < 40) ? f2bf(W[k * 40 + n]) : (short)0;
  } else if (i < TA + TB1 + TB2 + TCNT) {  // dst-degree histogram
    atomicAdd(&counts[ei[NE + (i - TA - TB1 - TB2)]], 1);
  }
}

// ================= shared gemm body (frag-packed B) =================
template <int K>
__device__ __forceinline__ void gemm3_body(int bid, const short* __restrict__ Xb,
                                           const short* __restrict__ Wp,
                                           const float* __restrict__ B0,
                                           const float* __restrict__ B1,
                                           const float* __restrict__ B2,
                                           unsigned short* __restrict__ Y0,
                                           unsigned short* __restrict__ Y1,
                                           unsigned short* __restrict__ Y2, int OC) {
  const int lane = threadIdx.x & 63;
  const int wave = threadIdx.x >> 6;
  const int r0 = bid * 128 + wave * 32;
  const int m = lane & 15;
  const int q = lane >> 4;
  f32x4 acc[3][4][2] = {};
  const short* a0 = Xb + (size_t)(r0 + m) * K + q * 8;
  const short* a1 = a0 + 16 * K;
  const short* bp = Wp + lane * 8;
#pragma unroll
  for (int kb = 0; kb < K / 32; ++kb) {
    const s16x8 af0 = *reinterpret_cast<const s16x8*>(a0 + kb * 32);
    const s16x8 af1 = *reinterpret_cast<const s16x8*>(a1 + kb * 32);
#pragma unroll
    for (int w = 0; w < 3; ++w) {
#pragma unroll
      for (int t = 0; t < 4; ++t) {
        const s16x8 bf = *reinterpret_cast<const s16x8*>(
            bp + (size_t)((kb * 3 + w) * 4 + t) * 512);
        acc[w][t][0] = __builtin_amdgcn_mfma_f32_16x16x32_bf16(af0, bf, acc[w][t][0], 0, 0, 0);
        acc[w][t][1] = __builtin_amdgcn_mfma_f32_16x16x32_bf16(af1, bf, acc[w][t][1], 0, 0, 0);
      }
    }
  }
#pragma unroll
  for (int w = 0; w < 3; ++w) {
    const float* B = (w == 0) ? B0 : (w == 1) ? B1 : B2;
    unsigned short* Y = (w == 0) ? Y0 : (w == 1) ? Y1 : Y2;
#pragma unroll
    for (int t = 0; t < 4; ++t) {
      const int c = t * 16 + m;
      const float bv = (c < OC) ? B[c] : 0.f;
#pragma unroll
      for (int rt = 0; rt < 2; ++rt) {
#pragma unroll
        for (int rg = 0; rg < 4; ++rg) {
          const int row = r0 + rt * 16 + q * 4 + rg;
          if (row < NN)
            Y[(size_t)row * 64 + c] = (unsigned short)f2bf(acc[w][t][rt][rg] + bv);
        }
      }
    }
  }
}

// ====== fused: scan_block (blocks 0..195) | layer-1 gemm (blocks 196..586) ======
__global__ __launch_bounds__(256, 2) void scan_gemm1(
    const int* __restrict__ counts, int* __restrict__ partial,
    int* __restrict__ bsums, const short* __restrict__ Xb,
    const short* __restrict__ Wp1, const float* __restrict__ B0,
    const float* __restrict__ B1, const float* __restrict__ B2,
    unsigned short* __restrict__ Y0, unsigned short* __restrict__ Y1,
    unsigned short* __restrict__ Y2) {
  if (blockIdx.x < SB) {
    __shared__ int s[256];
    int i = blockIdx.x * 256 + threadIdx.x;
    int v = (i < NN) ? counts[i] + 1 : 0;  // +1 self-loop
    s[threadIdx.x] = v;
    __syncthreads();
#pragma unroll
    for (int off = 1; off < 256; off <<= 1) {
      int t = (threadIdx.x >= off) ? s[threadIdx.x - off] : 0;
      __syncthreads();
      s[threadIdx.x] += t;
      __syncthreads();
    }
    if (i < NN) partial[i] = s[threadIdx.x];
    if (threadIdx.x == 255) bsums[blockIdx.x] = s[255];
  } else {
    gemm3_body<256>(blockIdx.x - SB, Xb, Wp1, B0, B1, B2, Y0, Y1, Y2, 64);
  }
}

__global__ __launch_bounds__(256) void gemm2(const short* __restrict__ Xb,
                                             const short* __restrict__ Wp,
                                             const float* __restrict__ B0,
                                             const float* __restrict__ B1,
                                             const float* __restrict__ B2,
                                             unsigned short* __restrict__ Y0,
                                             unsigned short* __restrict__ Y1,
                                             unsigned short* __restrict__ Y2) {
  gemm3_body<64>(blockIdx.x, Xb, Wp, B0, B1, B2, Y0, Y1, Y2, 40);
}

// per-block base = sum of bsums below this block; offsets + cursor
__global__ __launch_bounds__(256) void scan_final(const int* __restrict__ partial,
                                                  const int* __restrict__ bsums,
                                                  const int* __restrict__ counts,
                                                  int* __restrict__ offsets,
                                                  int* __restrict__ cursor) {
  __shared__ int red[256];
  const int t = threadIdx.x;
  red[t] = (t < SB && t < (int)blockIdx.x) ? bsums[t] : 0;
  __syncthreads();
#pragma unroll
  for (int off = 128; off >= 1; off >>= 1) {
    if (t < off) red[t] += red[t + off];
    __syncthreads();
  }
  const int base = red[0];
  int i = blockIdx.x * 256 + t;
  if (i < NN) {
    int incl = partial[i] + base;
    offsets[i + 1] = incl;
    cursor[i] = incl - counts[i] - 1;
    if (i == 0) offsets[0] = 0;
  }
}

// ====== LDS-binned CSR fill (+ fused edge_index pass-through, output 1) ======
__global__ __launch_bounds__(256) void fill_binned(const int* __restrict__ ei,
                                                   int* __restrict__ cursor,
                                                   unsigned short* __restrict__ csr16,
                                                   float* __restrict__ outE) {
  __shared__ unsigned sorted[CHUNK];
  __shared__ int hist[512];
  __shared__ int bcur[512];
  const int tid = threadIdx.x;
  const int base = blockIdx.x * CHUNK;
  for (int t = tid; t < 512; t += 256) { hist[t] = 0; bcur[t] = 0; }
  __syncthreads();
  unsigned key[CHUNK / 256];
#pragma unroll
  for (int u = 0; u < CHUNK / 256; ++u) {
    const int j = base + u * 256 + tid;  // coalesced
    unsigned k = 0xFFFFFFFFu;
    if (j < NITEMS) {
      int s, d;
      if (j < NE) {
        s = ei[j]; d = ei[NE + j];
        outE[j] = (float)s; outE[NE + j] = (float)d;
      } else {
        s = j - NE; d = s;
      }
      k = ((unsigned)d << 16) | (unsigned)s;
      atomicAdd(&hist[k >> 23], 1);  // bucket = d >> 7
    }
    key[u] = k;
  }
  __syncthreads();
  // exclusive scan of hist[0..511] by one wave
  if (tid < 64) {
    int carry = 0;
#pragma unroll
    for (int c = 0; c < 8; ++c) {
      int v = hist[c * 64 + tid];
      int inc = v;
#pragma unroll
      for (int off = 1; off < 64; off <<= 1) {
        int tt = __shfl_up(inc, off, 64);
        if (tid >= off) inc += tt;
      }
      hist[c * 64 + tid] = carry + inc - v;  // exclusive
      carry += __shfl(inc, 63, 64);
    }
  }
  __syncthreads();
#pragma unroll
  for (int u = 0; u < CHUNK / 256; ++u) {
    const unsigned k = key[u];
    if (k != 0xFFFFFFFFu) {
      const int b = k >> 23;
      const int pos = hist[b] + atomicAdd(&bcur[b], 1);
      sorted[pos] = k;
    }
  }
  __syncthreads();
  const int cnt = min(CHUNK, NITEMS - base);
  for (int t = tid; t < cnt; t += 256) {
    const unsigned k = sorted[t];
    const int d = k >> 16;
    const int p = atomicAdd(&cursor[d], 1);
    csr16[p] = (unsigned short)(k & 0xFFFFu);
  }
}

// ====== GATv2 aggregation: 8 lanes/edge, 8 edges in flight, 16B gathers ======
// Wave = 8 groups of 8 lanes; group g handles edges beg+8*it+g of dst d.
// Lane l holds dims 8l..8l+7. Group-private online-softmax state merged at end.
template <int OC, bool FINAL>
__global__ __launch_bounds__(256) void gat_agg(const unsigned short* __restrict__ XL,
                                               const unsigned short* __restrict__ XR,
                                               const unsigned short* __restrict__ XLIN,
                                               const float* __restrict__ att,
                                               const float* __restrict__ bias,
                                               const int* __restrict__ offsets,
                                               const unsigned short* __restrict__ csr,
                                               float* __restrict__ out,
                                               unsigned short* __restrict__ outb) {
  const int lane = threadIdx.x & 63;
  const int g = lane >> 3;
  const int l = lane & 7;
  const int d = blockIdx.x * 4 + (threadIdx.x >> 6);
  if (d >= NN) return;
  const bool dimok = (8 * l < OC);  // OC=64: all lanes; OC=40: l<5 exactly
  float a[8] = {};
  if (dimok) {
    const float4 t0 = *reinterpret_cast<const float4*>(&att[8 * l]);
    const float4 t1 = *reinterpret_cast<const float4*>(&att[8 * l + 4]);
    a[0] = t0.x; a[1] = t0.y; a[2] = t0.z; a[3] = t0.w;
    a[4] = t1.x; a[5] = t1.y; a[6] = t1.z; a[7] = t1.w;
  }
  float xr[8];
  ldbf8(XR + (size_t)d * 64 + 8 * l, xr);
  const int beg = offsets[d];
  const int end = offsets[d + 1];
  float m = -1e30f, D = 0.f;
  float A[8] = {};
  const int nit = (end - beg + 7) >> 3;
  const int i0 = beg + g;
  int sa = (int)csr[(i0 < end) ? i0 : beg];
  for (int it = 0; it < nit; ++it) {
    const int icur = beg + it * 8 + g;
    const bool act = (icur < end);
    float xl[8];
    ldbf8(XL + (size_t)sa * 64 + 8 * l, xl);  // prefetched src
    const int inext = icur + 8;
    sa = (int)csr[(inext < end) ? inext : beg];
    float p = 0.f;
#pragma unroll
    for (int j = 0; j < 8; ++j) {
      const float t = xl[j] + xr[j];
      const float lr = fmaxf(t, NEG_SLOPE * t);
      p = fmaf(lr, a[j], p);
    }
    p += __shfl_xor(p, 1, 64);
    p += __shfl_xor(p, 2, 64);
    p += __shfl_xor(p, 4, 64);  // group-uniform logit
    const float e = act ? p : -3e38f;
    const float mn = fmaxf(m, e);
    const float c = __expf(m - mn);
    const float w = __expf(e - mn);
    D = fmaf(D, c, w);
#pragma unroll
    for (int j = 0; j < 8; ++j) A[j] = fmaf(A[j], c, w * xl[j]);
    m = mn;
  }
  // merge the 8 group states (xor bits 3..5 move across groups, keep l)
  float mw = fmaxf(m, __shfl_xor(m, 8, 64));
  mw = fmaxf(mw, __shfl_xor(mw, 16, 64));
  mw = fmaxf(mw, __shfl_xor(mw, 32, 64));
  const float sc = __expf(m - mw);  // 0 for groups that saw no edge
  float Dw = D * sc;
  Dw += __shfl_xor(Dw, 8, 64);
  Dw += __shfl_xor(Dw, 16, 64);
  Dw += __shfl_xor(Dw, 32, 64);
#pragma unroll
  for (int j = 0; j < 8; ++j) {
    float v = A[j] * sc;
    v += __shfl_xor(v, 8, 64);
    v += __shfl_xor(v, 16, 64);
    v += __shfl_xor(v, 32, 64);
    A[j] = v;
  }
  float xlin[8];
  ldbf8(XLIN + (size_t)d * 64 + 8 * l, xlin);
  float b[8] = {};
  if (dimok) {
    const float4 t0 = *reinterpret_cast<const float4*>(&bias[8 * l]);
    const float4 t1 = *reinterpret_cast<const float4*>(&bias[8 * l + 4]);
    b[0] = t0.x; b[1] = t0.y; b[2] = t0.z; b[3] = t0.w;
    b[4] = t1.x; b[5] = t1.y; b[6] = t1.z; b[7] = t1.w;
  }
  const float inv = 1.0f / Dw;  // Dw > 0 (self-loop)
  float val[8];
#pragma unroll
  for (int j = 0; j < 8; ++j) val[j] = fmaf(A[j], inv, b[j]) + xlin[j];
  if (!FINAL) {
    if (g == 0) {  // relu -> bf16 H, 16B store
      uint4 o;
      o.x = pack2(fmaxf(val[0], 0.f), fmaxf(val[1], 0.f));
      o.y = pack2(fmaxf(val[2], 0.f), fmaxf(val[3], 0.f));
      o.z = pack2(fmaxf(val[4], 0.f), fmaxf(val[5], 0.f));
      o.w = pack2(fmaxf(val[6], 0.f), fmaxf(val[7], 0.f));
      *reinterpret_cast<uint4*>(&outb[(size_t)d * 64 + 8 * l]) = o;
    }
  } else {
    // log-softmax over dims 0..OC-1 (reduce across the 8 lanes of a group)
    float mx = -3e38f;
    if (dimok) {
#pragma unroll
      for (int j = 0; j < 8; ++j) mx = fmaxf(mx, val[j]);
    }
    mx = fmaxf(mx, __shfl_xor(mx, 1, 64));
    mx = fmaxf(mx, __shfl_xor(mx, 2, 64));
    mx = fmaxf(mx, __shfl_xor(mx, 4, 64));
    float es = 0.f;
    if (dimok) {
#pragma unroll
      for (int j = 0; j < 8; ++j) es += __expf(val[j] - mx);
    }
    es += __shfl_xor(es, 1, 64);
    es += __shfl_xor(es, 2, 64);
    es += __shfl_xor(es, 4, 64);
    const float lse = mx + __logf(es);
    if (g == 0 && dimok) {
      float4 o0, o1;
      o0.x = val[0] - lse; o0.y = val[1] - lse; o0.z = val[2] - lse; o0.w = val[3] - lse;
      o1.x = val[4] - lse; o1.y = val[5] - lse; o1.z = val[6] - lse; o1.w = val[7] - lse;
      float* dst = &out[(size_t)d * OC + 8 * l];
      *reinterpret_cast<float4*>(dst) = o0;
      *reinterpret_cast<float4*>(dst + 4) = o1;
    }
  }
}

// ---------------- launch ----------------
extern "C" void kernel_launch(void* const* d_in, const int* in_sizes, int n_in,
                              void* d_out, int out_size, void* d_ws, size_t ws_size,
                              hipStream_t stream) {
  const float* x     = (const float*)d_in[0];
  const int*   ei    = (const int*)d_in[1];
  const float* W1l   = (const float*)d_in[2];
  const float* b1l   = (const float*)d_in[3];
  const float* W1r   = (const float*)d_in[4];
  const float* b1r   = (const float*)d_in[5];
  const float* att1  = (const float*)d_in[6];
  const float* bias1 = (const float*)d_in[7];
  const float* lin1W = (const float*)d_in[8];
  const float* lin1b = (const float*)d_in[9];
  const float* W2l   = (const float*)d_in[10];
  const float* b2l   = (const float*)d_in[11];
  const float* W2r   = (const float*)d_in[12];
  const float* b2r   = (const float*)d_in[13];
  const float* att2  = (const float*)d_in[14];
  const float* bias2 = (const float*)d_in[15];
  const float* lin2W = (const float*)d_in[16];
  const float* lin2b = (const float*)d_in[17];
  float* out = (float*)d_out;

  char* ws = (char*)d_ws;
  size_t off = 0;
  auto alloc = [&](size_t bytes) -> void* {
    void* p = ws + off;
    off += (bytes + 255) & ~(size_t)255;
    return p;
  };
  short* Xb  = (short*)alloc((size_t)NP * 256 * 2);
  short* Wp1 = (short*)alloc((size_t)TB1 * 2);
  short* Wp2 = (short*)alloc((size_t)TB2 * 2);
  unsigned short* XL1   = (unsigned short*)alloc((size_t)NN * 64 * 2);
  unsigned short* XR1   = (unsigned short*)alloc((size_t)NN * 64 * 2);
  unsigned short* XLIN1 = (unsigned short*)alloc((size_t)NN * 64 * 2);
  unsigned short* Hb    = (unsigned short*)alloc((size_t)NP * 64 * 2);
  unsigned short* XL2   = (unsigned short*)alloc((size_t)NN * 64 * 2);
  unsigned short* XR2   = (unsigned short*)alloc((size_t)NN * 64 * 2);
  unsigned short* XLIN2 = (unsigned short*)alloc((size_t)NN * 64 * 2);
  int* counts  = (int*)alloc((size_t)NN * 4);
  int* partial = (int*)alloc((size_t)NN * 4);
  int* bsums   = (int*)alloc(1024);
  int* offsets = (int*)alloc((size_t)(NN + 1) * 4);
  int* cursor  = (int*)alloc((size_t)NN * 4);
  unsigned short* csr = (unsigned short*)alloc((size_t)NITEMS * 2);

  hipMemsetAsync(counts, 0, (size_t)NN * 4, stream);

  const int PT = TA + TB1 + TB2 + TCNT;
  mega_prep<<<(PT + 255) / 256, 256, 0, stream>>>(x, Xb, W1l, W1r, lin1W, W2l,
                                                  W2r, lin2W, Wp1, Wp2, ei, counts);
  scan_gemm1<<<SB + GB, 256, 0, stream>>>(counts, partial, bsums, Xb, Wp1,
                                          b1l, b1r, lin1b, XL1, XR1, XLIN1);
  scan_final<<<SB, 256, 0, stream>>>(partial, bsums, counts, offsets, cursor);
  fill_binned<<<(NITEMS + CHUNK - 1) / CHUNK, 256, 0, stream>>>(
      ei, cursor, csr, out + (size_t)NN * CD);
  gat_agg<64, false><<<(NN + 3) / 4, 256, 0, stream>>>(XL1, XR1, XLIN1, att1,
                                                       bias1, offsets, csr,
                                                       nullptr, Hb);
  gemm2<<<GB, 256, 0, stream>>>((const short*)Hb, Wp2, b2l, b2r, lin2b,
                                XL2, XR2, XLIN2);
  gat_agg<40, true><<<(NN + 3) / 4, 256, 0, stream>>>(XL2, XR2, XLIN2, att2,
                                                      bias2, offsets, csr,
                                                      out, nullptr);
}

// Round 7
// 262.616 us; speedup vs baseline: 2.5394x; 1.2389x over previous
//
#include <hip/hip_runtime.h>
#include <cmath>

#define NN 50000
#define NP 50048
#define NE 800000
#define CD 40
#define NEG_SLOPE 0.2f
#define NITEMS (NE + NN)   // edges + self-loops
#define CHUNK 2048
#define NCH 416            // ceil(NITEMS / CHUNK)
#define NBKT 391           // node buckets of 128 (covers 50048)
#define BCAP 3072          // bucket capacity (mean 2174, +19 sigma)
#define GB 391             // gemm blocks (NP/128)
#define TB1 (3 * 64 * 256)
#define TB2 (3 * 64 * 64)
#define WPB 240            // W-pack blocks ((TB1+TB2)/256)

typedef __attribute__((ext_vector_type(8))) short s16x8;   // 8 bf16
typedef __attribute__((ext_vector_type(4))) float f32x4;   // 4 fp32 acc

__device__ __forceinline__ short f2bf(float x) {  // RNE, finite
  unsigned u = __builtin_bit_cast(unsigned, x);
  u += 0x7fffu + ((u >> 16) & 1u);
  return (short)(u >> 16);
}
__device__ __forceinline__ unsigned pack2(float lo, float hi) {
  return (unsigned)(unsigned short)f2bf(lo) | ((unsigned)(unsigned short)f2bf(hi) << 16);
}
__device__ __forceinline__ float bf2f_lo(unsigned v) {
  return __builtin_bit_cast(float, v << 16);
}
__device__ __forceinline__ float bf2f_hi(unsigned v) {
  return __builtin_bit_cast(float, v & 0xffff0000u);
}
__device__ __forceinline__ void ldbf8(const unsigned short* p, float* f) {
  const uint4 v = *reinterpret_cast<const uint4*>(p);
  f[0] = bf2f_lo(v.x); f[1] = bf2f_hi(v.x);
  f[2] = bf2f_lo(v.y); f[3] = bf2f_hi(v.y);
  f[4] = bf2f_lo(v.z); f[5] = bf2f_hi(v.z);
  f[6] = bf2f_lo(v.w); f[7] = bf2f_hi(v.w);
}

// ====== prep_bin: W frag-pack (blocks 0..239) | edge binning (blocks 240..) ======
// Phase A: LDS-sort a 2048-item chunk by bucket dst>>7, claim space with ONE
// aggregated atomic per (block,bucket), write bucket-grouped records. No
// per-edge global atomics. Also emits the edge_index pass-through (output 1).
__global__ __launch_bounds__(256) void prep_bin(const float* __restrict__ W1l,
                                                const float* __restrict__ W1r,
                                                const float* __restrict__ L1,
                                                const float* __restrict__ W2l,
                                                const float* __restrict__ W2r,
                                                const float* __restrict__ L2,
                                                short* __restrict__ Wp1,
                                                short* __restrict__ Wp2,
                                                const int* __restrict__ ei,
                                                float* __restrict__ outE,
                                                int* __restrict__ gcur,
                                                unsigned* __restrict__ rec) {
  const int tid = threadIdx.x;
  if (blockIdx.x < WPB) {  // W pack: [kb][w][t][lane][j]
    int e = blockIdx.x * 256 + tid;
    if (e < TB1) {  // layer 1: K=256, OC=64, src [256][64]
      int kb = e / 6144, r = e % 6144;
      int w = r / 2048, r2 = r % 2048;
      int t = r2 / 512, r3 = r2 % 512;
      int lane = r3 / 8, j = r3 % 8;
      int n = t * 16 + (lane & 15);
      int k = kb * 32 + (lane >> 4) * 8 + j;
      const float* W = (w == 0) ? W1l : (w == 1) ? W1r : L1;
      Wp1[e] = f2bf(W[k * 64 + n]);
    } else {  // layer 2: K=64, OC=40 pad 64
      e -= TB1;
      int kb = e / 6144, r = e % 6144;
      int w = r / 2048, r2 = r % 2048;
      int t = r2 / 512, r3 = r2 % 512;
      int lane = r3 / 8, j = r3 % 8;
      int n = t * 16 + (lane & 15);
      int k = kb * 32 + (lane >> 4) * 8 + j;
      const float* W = (w == 0) ? W2l : (w == 1) ? W2r : L2;
      Wp2[e] = (n < 40) ? f2bf(W[k * 40 + n]) : (short)0;
    }
    return;
  }
  // ---- Phase A ----
  __shared__ unsigned sorted[CHUNK];
  __shared__ int hist[512];
  __shared__ int bcur[512];
  __shared__ int gbase[512];
  const int base = (blockIdx.x - WPB) * CHUNK;
  for (int t = tid; t < 512; t += 256) { hist[t] = 0; bcur[t] = 0; gbase[t] = 0; }
  __syncthreads();
  unsigned key[CHUNK / 256];
#pragma unroll
  for (int u = 0; u < CHUNK / 256; ++u) {
    const int j = base + u * 256 + tid;
    unsigned k = 0xFFFFFFFFu;
    if (j < NITEMS) {
      int s, d;
      if (j < NE) {
        s = ei[j]; d = ei[NE + j];
        outE[j] = (float)s; outE[NE + j] = (float)d;
      } else {
        s = j - NE; d = s;
      }
      k = ((unsigned)d << 16) | (unsigned)s;
      atomicAdd(&hist[k >> 23], 1);
    }
    key[u] = k;
  }
  __syncthreads();
  // exclusive scan hist[0..511], one wave
  if (tid < 64) {
    int carry = 0;
#pragma unroll
    for (int c = 0; c < 8; ++c) {
      int v = hist[c * 64 + tid];
      int inc = v;
#pragma unroll
      for (int off = 1; off < 64; off <<= 1) {
        int tt = __shfl_up(inc, off, 64);
        if (tid >= off) inc += tt;
      }
      hist[c * 64 + tid] = carry + inc - v;
      carry += __shfl(inc, 63, 64);
    }
  }
  __syncthreads();
#pragma unroll
  for (int u = 0; u < CHUNK / 256; ++u) {
    const unsigned k = key[u];
    if (k != 0xFFFFFFFFu) {
      const int b = k >> 23;
      sorted[hist[b] + atomicAdd(&bcur[b], 1)] = k;
    }
  }
  __syncthreads();
  for (int t = tid; t < NBKT; t += 256) {  // one aggregated atomic per bucket
    const int c = bcur[t];
    if (c > 0) gbase[t] = atomicAdd(&gcur[t], c);
  }
  __syncthreads();
  const int cnt = min(CHUNK, NITEMS - base);
  for (int i = tid; i < cnt; i += 256) {  // bucket runs -> contiguous writes
    const unsigned k = sorted[i];
    const int b = k >> 23;
    const int p = gbase[b] + (i - hist[b]);
    if (p < BCAP) rec[(size_t)b * BCAP + p] = k;
  }
}

// ================= gemm bodies (frag-packed B) =================
// gemm1: reads X fp32 directly, converts to bf16 in-register.
__device__ __forceinline__ void gemm1_body(int bid, const float* __restrict__ X,
                                           const short* __restrict__ Wp,
                                           const float* __restrict__ B0,
                                           const float* __restrict__ B1,
                                           const float* __restrict__ B2,
                                           unsigned short* __restrict__ Y0,
                                           unsigned short* __restrict__ Y1,
                                           unsigned short* __restrict__ Y2) {
  const int lane = threadIdx.x & 63;
  const int wave = threadIdx.x >> 6;
  const int r0 = bid * 128 + wave * 32;
  const int m = lane & 15;
  const int q = lane >> 4;
  f32x4 acc[3][4][2] = {};
  const float* a0 = X + (size_t)min(r0 + m, NN - 1) * 256 + q * 8;
  const float* a1 = X + (size_t)min(r0 + 16 + m, NN - 1) * 256 + q * 8;
  const short* bp = Wp + lane * 8;
#pragma unroll
  for (int kb = 0; kb < 8; ++kb) {
    const float4 v0 = *reinterpret_cast<const float4*>(a0 + kb * 32);
    const float4 v1 = *reinterpret_cast<const float4*>(a0 + kb * 32 + 4);
    const float4 v2 = *reinterpret_cast<const float4*>(a1 + kb * 32);
    const float4 v3 = *reinterpret_cast<const float4*>(a1 + kb * 32 + 4);
    s16x8 af0, af1;
    af0[0] = f2bf(v0.x); af0[1] = f2bf(v0.y); af0[2] = f2bf(v0.z); af0[3] = f2bf(v0.w);
    af0[4] = f2bf(v1.x); af0[5] = f2bf(v1.y); af0[6] = f2bf(v1.z); af0[7] = f2bf(v1.w);
    af1[0] = f2bf(v2.x); af1[1] = f2bf(v2.y); af1[2] = f2bf(v2.z); af1[3] = f2bf(v2.w);
    af1[4] = f2bf(v3.x); af1[5] = f2bf(v3.y); af1[6] = f2bf(v3.z); af1[7] = f2bf(v3.w);
#pragma unroll
    for (int w = 0; w < 3; ++w) {
#pragma unroll
      for (int t = 0; t < 4; ++t) {
        const s16x8 bf = *reinterpret_cast<const s16x8*>(
            bp + (size_t)((kb * 3 + w) * 4 + t) * 512);
        acc[w][t][0] = __builtin_amdgcn_mfma_f32_16x16x32_bf16(af0, bf, acc[w][t][0], 0, 0, 0);
        acc[w][t][1] = __builtin_amdgcn_mfma_f32_16x16x32_bf16(af1, bf, acc[w][t][1], 0, 0, 0);
      }
    }
  }
#pragma unroll
  for (int w = 0; w < 3; ++w) {
    const float* B = (w == 0) ? B0 : (w == 1) ? B1 : B2;
    unsigned short* Y = (w == 0) ? Y0 : (w == 1) ? Y1 : Y2;
#pragma unroll
    for (int t = 0; t < 4; ++t) {
      const int c = t * 16 + m;
      const float bv = B[c];
#pragma unroll
      for (int rt = 0; rt < 2; ++rt) {
#pragma unroll
        for (int rg = 0; rg < 4; ++rg) {
          const int row = r0 + rt * 16 + q * 4 + rg;
          if (row < NN)
            Y[(size_t)row * 64 + c] = (unsigned short)f2bf(acc[w][t][rt][rg] + bv);
        }
      }
    }
  }
}

// ====== build_gemm1: gemm1 (blocks 0..390) | CSR Phase B (blocks 391..781) ======
// Phase B: one block per 128-node bucket; LDS histogram + scan + scatter.
__global__ __launch_bounds__(256, 2) void build_gemm1(
    const float* __restrict__ X, const short* __restrict__ Wp1,
    const float* __restrict__ B0, const float* __restrict__ B1,
    const float* __restrict__ B2, unsigned short* __restrict__ Y0,
    unsigned short* __restrict__ Y1, unsigned short* __restrict__ Y2,
    const int* __restrict__ gcur, const unsigned* __restrict__ rec,
    int* __restrict__ offsets, unsigned short* __restrict__ csr16) {
  if (blockIdx.x < GB) {
    gemm1_body(blockIdx.x, X, Wp1, B0, B1, B2, Y0, Y1, Y2);
    return;
  }
  const int b = blockIdx.x - GB;
  const int tid = threadIdx.x;
  __shared__ unsigned recs[BCAP];
  __shared__ int red[256];
  __shared__ int cnt[128];
  __shared__ int sc[128];
  __shared__ int cur[128];
  // base = sum of bucket totals below b
  int acc = 0;
  for (int t = tid; t < NBKT; t += 256)
    if (t < b) acc += gcur[t];
  red[tid] = acc;
  __syncthreads();
#pragma unroll
  for (int off = 128; off >= 1; off >>= 1) {
    if (tid < off) red[tid] += red[tid + off];
    __syncthreads();
  }
  const int base = red[0];
  const int Tb = min(gcur[b], BCAP);
  if (tid < 128) cnt[tid] = 0;
  __syncthreads();
  for (int i = tid; i < Tb; i += 256) {
    const unsigned k = rec[(size_t)b * BCAP + i];
    recs[i] = k;
    atomicAdd(&cnt[(k >> 16) & 127], 1);
  }
  __syncthreads();
  // inclusive scan of cnt[128]
  if (tid < 128) sc[tid] = cnt[tid];
  __syncthreads();
#pragma unroll
  for (int off = 1; off < 128; off <<= 1) {
    int v = (tid < 128 && tid >= off) ? sc[tid - off] : 0;
    __syncthreads();
    if (tid < 128) sc[tid] += v;
    __syncthreads();
  }
  if (tid < 128) {
    const int n = b * 128 + tid;
    if (n < NN) offsets[n + 1] = base + sc[tid];
    cur[tid] = sc[tid] - cnt[tid];  // exclusive
  }
  if (b == 0 && tid == 0) offsets[0] = 0;
  __syncthreads();
  for (int i = tid; i < Tb; i += 256) {
    const unsigned k = recs[i];
    const int p = atomicAdd(&cur[(k >> 16) & 127], 1);
    csr16[base + p] = (unsigned short)(k & 0xFFFFu);
  }
}

// ============ gemm2: Hb bf16 [NP][64] @ Wp2, OC=40 pad 64 ============
__global__ __launch_bounds__(256) void gemm2(const short* __restrict__ Xb,
                                             const short* __restrict__ Wp,
                                             const float* __restrict__ B0,
                                             const float* __restrict__ B1,
                                             const float* __restrict__ B2,
                                             unsigned short* __restrict__ Y0,
                                             unsigned short* __restrict__ Y1,
                                             unsigned short* __restrict__ Y2) {
  const int lane = threadIdx.x & 63;
  const int wave = threadIdx.x >> 6;
  const int r0 = blockIdx.x * 128 + wave * 32;
  const int m = lane & 15;
  const int q = lane >> 4;
  f32x4 acc[3][4][2] = {};
  const short* a0 = Xb + (size_t)(r0 + m) * 64 + q * 8;
  const short* a1 = a0 + 16 * 64;
  const short* bp = Wp + lane * 8;
#pragma unroll
  for (int kb = 0; kb < 2; ++kb) {
    const s16x8 af0 = *reinterpret_cast<const s16x8*>(a0 + kb * 32);
    const s16x8 af1 = *reinterpret_cast<const s16x8*>(a1 + kb * 32);
#pragma unroll
    for (int w = 0; w < 3; ++w) {
#pragma unroll
      for (int t = 0; t < 4; ++t) {
        const s16x8 bf = *reinterpret_cast<const s16x8*>(
            bp + (size_t)((kb * 3 + w) * 4 + t) * 512);
        acc[w][t][0] = __builtin_amdgcn_mfma_f32_16x16x32_bf16(af0, bf, acc[w][t][0], 0, 0, 0);
        acc[w][t][1] = __builtin_amdgcn_mfma_f32_16x16x32_bf16(af1, bf, acc[w][t][1], 0, 0, 0);
      }
    }
  }
#pragma unroll
  for (int w = 0; w < 3; ++w) {
    const float* B = (w == 0) ? B0 : (w == 1) ? B1 : B2;
    unsigned short* Y = (w == 0) ? Y0 : (w == 1) ? Y1 : Y2;
#pragma unroll
    for (int t = 0; t < 4; ++t) {
      const int c = t * 16 + m;
      const float bv = (c < 40) ? B[c] : 0.f;
#pragma unroll
      for (int rt = 0; rt < 2; ++rt) {
#pragma unroll
        for (int rg = 0; rg < 4; ++rg) {
          const int row = r0 + rt * 16 + q * 4 + rg;
          if (row < NN)
            Y[(size_t)row * 64 + c] = (unsigned short)f2bf(acc[w][t][rt][rg] + bv);
        }
      }
    }
  }
}

// ====== GATv2 aggregation: 8 lanes/edge, 8 edges in flight, 16B gathers ======
template <int OC, bool FINAL>
__global__ __launch_bounds__(256) void gat_agg(const unsigned short* __restrict__ XL,
                                               const unsigned short* __restrict__ XR,
                                               const unsigned short* __restrict__ XLIN,
                                               const float* __restrict__ att,
                                               const float* __restrict__ bias,
                                               const int* __restrict__ offsets,
                                               const unsigned short* __restrict__ csr,
                                               float* __restrict__ out,
                                               unsigned short* __restrict__ outb) {
  const int lane = threadIdx.x & 63;
  const int g = lane >> 3;
  const int l = lane & 7;
  const int d = blockIdx.x * 4 + (threadIdx.x >> 6);
  if (d >= NN) return;
  const bool dimok = (8 * l < OC);
  float a[8] = {};
  if (dimok) {
    const float4 t0 = *reinterpret_cast<const float4*>(&att[8 * l]);
    const float4 t1 = *reinterpret_cast<const float4*>(&att[8 * l + 4]);
    a[0] = t0.x; a[1] = t0.y; a[2] = t0.z; a[3] = t0.w;
    a[4] = t1.x; a[5] = t1.y; a[6] = t1.z; a[7] = t1.w;
  }
  float xr[8];
  ldbf8(XR + (size_t)d * 64 + 8 * l, xr);
  const int beg = offsets[d];
  const int end = offsets[d + 1];
  float m = -1e30f, D = 0.f;
  float A[8] = {};
  const int nit = (end - beg + 7) >> 3;
  const int i0 = beg + g;
  int sa = (int)csr[(i0 < end) ? i0 : beg];
  for (int it = 0; it < nit; ++it) {
    const int icur = beg + it * 8 + g;
    const bool act = (icur < end);
    float xl[8];
    ldbf8(XL + (size_t)sa * 64 + 8 * l, xl);
    const int inext = icur + 8;
    sa = (int)csr[(inext < end) ? inext : beg];
    float p = 0.f;
#pragma unroll
    for (int j = 0; j < 8; ++j) {
      const float t = xl[j] + xr[j];
      const float lr = fmaxf(t, NEG_SLOPE * t);
      p = fmaf(lr, a[j], p);
    }
    p += __shfl_xor(p, 1, 64);
    p += __shfl_xor(p, 2, 64);
    p += __shfl_xor(p, 4, 64);
    const float e = act ? p : -3e38f;
    const float mn = fmaxf(m, e);
    const float c = __expf(m - mn);
    const float w = __expf(e - mn);
    D = fmaf(D, c, w);
#pragma unroll
    for (int j = 0; j < 8; ++j) A[j] = fmaf(A[j], c, w * xl[j]);
    m = mn;
  }
  float mw = fmaxf(m, __shfl_xor(m, 8, 64));
  mw = fmaxf(mw, __shfl_xor(mw, 16, 64));
  mw = fmaxf(mw, __shfl_xor(mw, 32, 64));
  const float sc = __expf(m - mw);
  float Dw = D * sc;
  Dw += __shfl_xor(Dw, 8, 64);
  Dw += __shfl_xor(Dw, 16, 64);
  Dw += __shfl_xor(Dw, 32, 64);
#pragma unroll
  for (int j = 0; j < 8; ++j) {
    float v = A[j] * sc;
    v += __shfl_xor(v, 8, 64);
    v += __shfl_xor(v, 16, 64);
    v += __shfl_xor(v, 32, 64);
    A[j] = v;
  }
  float xlin[8];
  ldbf8(XLIN + (size_t)d * 64 + 8 * l, xlin);
  float b[8] = {};
  if (dimok) {
    const float4 t0 = *reinterpret_cast<const float4*>(&bias[8 * l]);
    const float4 t1 = *reinterpret_cast<const float4*>(&bias[8 * l + 4]);
    b[0] = t0.x; b[1] = t0.y; b[2] = t0.z; b[3] = t0.w;
    b[4] = t1.x; b[5] = t1.y; b[6] = t1.z; b[7] = t1.w;
  }
  const float inv = 1.0f / Dw;
  float val[8];
#pragma unroll
  for (int j = 0; j < 8; ++j) val[j] = fmaf(A[j], inv, b[j]) + xlin[j];
  if (!FINAL) {
    if (g == 0) {
      uint4 o;
      o.x = pack2(fmaxf(val[0], 0.f), fmaxf(val[1], 0.f));
      o.y = pack2(fmaxf(val[2], 0.f), fmaxf(val[3], 0.f));
      o.z = pack2(fmaxf(val[4], 0.f), fmaxf(val[5], 0.f));
      o.w = pack2(fmaxf(val[6], 0.f), fmaxf(val[7], 0.f));
      *reinterpret_cast<uint4*>(&outb[(size_t)d * 64 + 8 * l]) = o;
    }
  } else {
    float mx = -3e38f;
    if (dimok) {
#pragma unroll
      for (int j = 0; j < 8; ++j) mx = fmaxf(mx, val[j]);
    }
    mx = fmaxf(mx, __shfl_xor(mx, 1, 64));
    mx = fmaxf(mx, __shfl_xor(mx, 2, 64));
    mx = fmaxf(mx, __shfl_xor(mx, 4, 64));
    float es = 0.f;
    if (dimok) {
#pragma unroll
      for (int j = 0; j < 8; ++j) es += __expf(val[j] - mx);
    }
    es += __shfl_xor(es, 1, 64);
    es += __shfl_xor(es, 2, 64);
    es += __shfl_xor(es, 4, 64);
    const float lse = mx + __logf(es);
    if (g == 0 && dimok) {
      float4 o0, o1;
      o0.x = val[0] - lse; o0.y = val[1] - lse; o0.z = val[2] - lse; o0.w = val[3] - lse;
      o1.x = val[4] - lse; o1.y = val[5] - lse; o1.z = val[6] - lse; o1.w = val[7] - lse;
      float* dst = &out[(size_t)d * OC + 8 * l];
      *reinterpret_cast<float4*>(dst) = o0;
      *reinterpret_cast<float4*>(dst + 4) = o1;
    }
  }
}

// ---------------- launch ----------------
extern "C" void kernel_launch(void* const* d_in, const int* in_sizes, int n_in,
                              void* d_out, int out_size, void* d_ws, size_t ws_size,
                              hipStream_t stream) {
  const float* x     = (const float*)d_in[0];
  const int*   ei    = (const int*)d_in[1];
  const float* W1l   = (const float*)d_in[2];
  const float* b1l   = (const float*)d_in[3];
  const float* W1r   = (const float*)d_in[4];
  const float* b1r   = (const float*)d_in[5];
  const float* att1  = (const float*)d_in[6];
  const float* bias1 = (const float*)d_in[7];
  const float* lin1W = (const float*)d_in[8];
  const float* lin1b = (const float*)d_in[9];
  const float* W2l   = (const float*)d_in[10];
  const float* b2l   = (const float*)d_in[11];
  const float* W2r   = (const float*)d_in[12];
  const float* b2r   = (const float*)d_in[13];
  const float* att2  = (const float*)d_in[14];
  const float* bias2 = (const float*)d_in[15];
  const float* lin2W = (const float*)d_in[16];
  const float* lin2b = (const float*)d_in[17];
  float* out = (float*)d_out;

  char* ws = (char*)d_ws;
  size_t off = 0;
  auto alloc = [&](size_t bytes) -> void* {
    void* p = ws + off;
    off += (bytes + 255) & ~(size_t)255;
    return p;
  };
  short* Wp1 = (short*)alloc((size_t)TB1 * 2);
  short* Wp2 = (short*)alloc((size_t)TB2 * 2);
  unsigned short* XL1   = (unsigned short*)alloc((size_t)NN * 64 * 2);
  unsigned short* XR1   = (unsigned short*)alloc((size_t)NN * 64 * 2);
  unsigned short* XLIN1 = (unsigned short*)alloc((size_t)NN * 64 * 2);
  unsigned short* Hb    = (unsigned short*)alloc((size_t)NP * 64 * 2);
  unsigned short* XL2   = (unsigned short*)alloc((size_t)NN * 64 * 2);
  unsigned short* XR2   = (unsigned short*)alloc((size_t)NN * 64 * 2);
  unsigned short* XLIN2 = (unsigned short*)alloc((size_t)NN * 64 * 2);
  int* gcur    = (int*)alloc((size_t)NBKT * 4);
  int* offsets = (int*)alloc((size_t)(NN + 1) * 4);
  unsigned* rec = (unsigned*)alloc((size_t)NBKT * BCAP * 4);
  unsigned short* csr = (unsigned short*)alloc((size_t)NITEMS * 2);

  hipMemsetAsync(gcur, 0, (size_t)NBKT * 4, stream);
  prep_bin<<<WPB + NCH, 256, 0, stream>>>(W1l, W1r, lin1W, W2l, W2r, lin2W,
                                          Wp1, Wp2, ei, out + (size_t)NN * CD,
                                          gcur, rec);
  build_gemm1<<<GB + NBKT, 256, 0, stream>>>(x, Wp1, b1l, b1r, lin1b,
                                             XL1, XR1, XLIN1, gcur, rec,
                                             offsets, csr);
  gat_agg<64, false><<<(NN + 3) / 4, 256, 0, stream>>>(XL1, XR1, XLIN1, att1,
                                                       bias1, offsets, csr,
                                                       nullptr, Hb);
  gemm2<<<GB, 256, 0, stream>>>((const short*)Hb, Wp2, b2l, b2r, lin2b,
                                XL2, XR2, XLIN2);
  gat_agg<40, true><<<(NN + 3) / 4, 256, 0, stream>>>(XL2, XR2, XLIN2, att2,
                                                      bias2, offsets, csr,
                                                      out, nullptr);
}

// Round 8
// 245.559 us; speedup vs baseline: 2.7158x; 1.0695x over previous
//
#include <hip/hip_runtime.h>
#include <cmath>

#define NN 50000
#define NP 50048
#define NE 800000
#define CD 40
#define NEG_SLOPE 0.2f
#define NITEMS (NE + NN)   // edges + self-loops
#define CHUNK 2048
#define NCH 416            // ceil(NITEMS / CHUNK)
#define NBKT 391           // node buckets of 128 (covers 50048)
#define BCAP 3072          // bucket capacity (mean 2174, +19 sigma)
#define GB1 782            // gemm blocks, 64 rows each (NP/64)
#define TB1 (3 * 64 * 256)
#define TB2 (3 * 64 * 64)
#define WPB 240            // W-pack blocks ((TB1+TB2)/256)

typedef __attribute__((ext_vector_type(8))) short s16x8;   // 8 bf16
typedef __attribute__((ext_vector_type(4))) float f32x4;   // 4 fp32 acc

__device__ __forceinline__ short f2bf(float x) {  // RNE, finite
  unsigned u = __builtin_bit_cast(unsigned, x);
  u += 0x7fffu + ((u >> 16) & 1u);
  return (short)(u >> 16);
}
__device__ __forceinline__ unsigned pack2(float lo, float hi) {
  return (unsigned)(unsigned short)f2bf(lo) | ((unsigned)(unsigned short)f2bf(hi) << 16);
}
__device__ __forceinline__ float bf2f_lo(unsigned v) {
  return __builtin_bit_cast(float, v << 16);
}
__device__ __forceinline__ float bf2f_hi(unsigned v) {
  return __builtin_bit_cast(float, v & 0xffff0000u);
}
__device__ __forceinline__ void ldbf8(const unsigned short* p, float* f) {
  const uint4 v = *reinterpret_cast<const uint4*>(p);
  f[0] = bf2f_lo(v.x); f[1] = bf2f_hi(v.x);
  f[2] = bf2f_lo(v.y); f[3] = bf2f_hi(v.y);
  f[4] = bf2f_lo(v.z); f[5] = bf2f_hi(v.z);
  f[6] = bf2f_lo(v.w); f[7] = bf2f_hi(v.w);
}

// ====== prep_bin: W frag-pack (blocks 0..239) | edge binning (blocks 240..) ======
__global__ __launch_bounds__(256) void prep_bin(const float* __restrict__ W1l,
                                                const float* __restrict__ W1r,
                                                const float* __restrict__ L1,
                                                const float* __restrict__ W2l,
                                                const float* __restrict__ W2r,
                                                const float* __restrict__ L2,
                                                short* __restrict__ Wp1,
                                                short* __restrict__ Wp2,
                                                const int* __restrict__ ei,
                                                float* __restrict__ outE,
                                                int* __restrict__ gcur,
                                                unsigned* __restrict__ rec) {
  const int tid = threadIdx.x;
  if (blockIdx.x < WPB) {  // W pack: [kb][w][t][lane][j]
    int e = blockIdx.x * 256 + tid;
    if (e < TB1) {  // layer 1: K=256, OC=64, src [256][64]
      int kb = e / 6144, r = e % 6144;
      int w = r / 2048, r2 = r % 2048;
      int t = r2 / 512, r3 = r2 % 512;
      int lane = r3 / 8, j = r3 % 8;
      int n = t * 16 + (lane & 15);
      int k = kb * 32 + (lane >> 4) * 8 + j;
      const float* W = (w == 0) ? W1l : (w == 1) ? W1r : L1;
      Wp1[e] = f2bf(W[k * 64 + n]);
    } else {  // layer 2: K=64, OC=40 pad 64
      e -= TB1;
      int kb = e / 6144, r = e % 6144;
      int w = r / 2048, r2 = r % 2048;
      int t = r2 / 512, r3 = r2 % 512;
      int lane = r3 / 8, j = r3 % 8;
      int n = t * 16 + (lane & 15);
      int k = kb * 32 + (lane >> 4) * 8 + j;
      const float* W = (w == 0) ? W2l : (w == 1) ? W2r : L2;
      Wp2[e] = (n < 40) ? f2bf(W[k * 40 + n]) : (short)0;
    }
    return;
  }
  // ---- Phase A: LDS-sort chunk by bucket dst>>7, one aggregated atomic per
  // (block,bucket), bucket-grouped record writes. ----
  __shared__ unsigned sorted[CHUNK];
  __shared__ int hist[512];
  __shared__ int bcur[512];
  __shared__ int gbase[512];
  const int base = (blockIdx.x - WPB) * CHUNK;
  for (int t = tid; t < 512; t += 256) { hist[t] = 0; bcur[t] = 0; gbase[t] = 0; }
  __syncthreads();
  unsigned key[CHUNK / 256];
#pragma unroll
  for (int u = 0; u < CHUNK / 256; ++u) {
    const int j = base + u * 256 + tid;
    unsigned k = 0xFFFFFFFFu;
    if (j < NITEMS) {
      int s, d;
      if (j < NE) {
        s = ei[j]; d = ei[NE + j];
        outE[j] = (float)s; outE[NE + j] = (float)d;
      } else {
        s = j - NE; d = s;
      }
      k = ((unsigned)d << 16) | (unsigned)s;
      atomicAdd(&hist[k >> 23], 1);
    }
    key[u] = k;
  }
  __syncthreads();
  if (tid < 64) {  // exclusive scan hist[0..511], one wave
    int carry = 0;
#pragma unroll
    for (int c = 0; c < 8; ++c) {
      int v = hist[c * 64 + tid];
      int inc = v;
#pragma unroll
      for (int off = 1; off < 64; off <<= 1) {
        int tt = __shfl_up(inc, off, 64);
        if (tid >= off) inc += tt;
      }
      hist[c * 64 + tid] = carry + inc - v;
      carry += __shfl(inc, 63, 64);
    }
  }
  __syncthreads();
#pragma unroll
  for (int u = 0; u < CHUNK / 256; ++u) {
    const unsigned k = key[u];
    if (k != 0xFFFFFFFFu) {
      const int b = k >> 23;
      sorted[hist[b] + atomicAdd(&bcur[b], 1)] = k;
    }
  }
  __syncthreads();
  for (int t = tid; t < NBKT; t += 256) {
    const int c = bcur[t];
    if (c > 0) gbase[t] = atomicAdd(&gcur[t], c);
  }
  __syncthreads();
  const int cnt = min(CHUNK, NITEMS - base);
  for (int i = tid; i < cnt; i += 256) {
    const unsigned k = sorted[i];
    const int b = k >> 23;
    const int p = gbase[b] + (i - hist[b]);
    if (p < BCAP) rec[(size_t)b * BCAP + p] = k;
  }
}

// ================= gemm1 body: 64 rows/block, 16 rows/wave =================
// Reads X fp32 directly, converts to bf16 in-register. Frag-packed B.
__device__ __forceinline__ void gemm1_body(int bid, const float* __restrict__ X,
                                           const short* __restrict__ Wp,
                                           const float* __restrict__ B0,
                                           const float* __restrict__ B1,
                                           const float* __restrict__ B2,
                                           unsigned short* __restrict__ Y0,
                                           unsigned short* __restrict__ Y1,
                                           unsigned short* __restrict__ Y2) {
  const int lane = threadIdx.x & 63;
  const int wave = threadIdx.x >> 6;
  const int r0 = bid * 64 + wave * 16;
  const int m = lane & 15;
  const int q = lane >> 4;
  f32x4 acc[3][4] = {};
  const float* a0 = X + (size_t)min(r0 + m, NN - 1) * 256 + q * 8;
  const short* bp = Wp + lane * 8;
#pragma unroll
  for (int kb = 0; kb < 8; ++kb) {
    const float4 v0 = *reinterpret_cast<const float4*>(a0 + kb * 32);
    const float4 v1 = *reinterpret_cast<const float4*>(a0 + kb * 32 + 4);
    s16x8 af0;
    af0[0] = f2bf(v0.x); af0[1] = f2bf(v0.y); af0[2] = f2bf(v0.z); af0[3] = f2bf(v0.w);
    af0[4] = f2bf(v1.x); af0[5] = f2bf(v1.y); af0[6] = f2bf(v1.z); af0[7] = f2bf(v1.w);
#pragma unroll
    for (int w = 0; w < 3; ++w) {
#pragma unroll
      for (int t = 0; t < 4; ++t) {
        const s16x8 bf = *reinterpret_cast<const s16x8*>(
            bp + (size_t)((kb * 3 + w) * 4 + t) * 512);
        acc[w][t] = __builtin_amdgcn_mfma_f32_16x16x32_bf16(af0, bf, acc[w][t], 0, 0, 0);
      }
    }
  }
#pragma unroll
  for (int w = 0; w < 3; ++w) {
    const float* B = (w == 0) ? B0 : (w == 1) ? B1 : B2;
    unsigned short* Y = (w == 0) ? Y0 : (w == 1) ? Y1 : Y2;
#pragma unroll
    for (int t = 0; t < 4; ++t) {
      const int c = t * 16 + m;
      const float bv = B[c];
#pragma unroll
      for (int rg = 0; rg < 4; ++rg) {
        const int row = r0 + q * 4 + rg;
        if (row < NN)
          Y[(size_t)row * 64 + c] = (unsigned short)f2bf(acc[w][t][rg] + bv);
      }
    }
  }
}

// ====== build_gemm1: gemm1 (blocks 0..781) | CSR Phase B (blocks 782..1172) ======
__global__ __launch_bounds__(256, 2) void build_gemm1(
    const float* __restrict__ X, const short* __restrict__ Wp1,
    const float* __restrict__ B0, const float* __restrict__ B1,
    const float* __restrict__ B2, unsigned short* __restrict__ Y0,
    unsigned short* __restrict__ Y1, unsigned short* __restrict__ Y2,
    const int* __restrict__ gcur, const unsigned* __restrict__ rec,
    int* __restrict__ offsets, unsigned short* __restrict__ csr16) {
  if (blockIdx.x < GB1) {
    gemm1_body(blockIdx.x, X, Wp1, B0, B1, B2, Y0, Y1, Y2);
    return;
  }
  const int b = blockIdx.x - GB1;
  const int tid = threadIdx.x;
  __shared__ unsigned recs[BCAP];
  __shared__ int red[256];
  __shared__ int cnt[128];
  __shared__ int sc[128];
  __shared__ int cur[128];
  int acc = 0;
  for (int t = tid; t < NBKT; t += 256)
    if (t < b) acc += gcur[t];
  red[tid] = acc;
  __syncthreads();
#pragma unroll
  for (int off = 128; off >= 1; off >>= 1) {
    if (tid < off) red[tid] += red[tid + off];
    __syncthreads();
  }
  const int base = red[0];
  const int Tb = min(gcur[b], BCAP);
  if (tid < 128) cnt[tid] = 0;
  __syncthreads();
  for (int i = tid; i < Tb; i += 256) {
    const unsigned k = rec[(size_t)b * BCAP + i];
    recs[i] = k;
    atomicAdd(&cnt[(k >> 16) & 127], 1);
  }
  __syncthreads();
  if (tid < 128) sc[tid] = cnt[tid];
  __syncthreads();
#pragma unroll
  for (int off = 1; off < 128; off <<= 1) {
    int v = (tid < 128 && tid >= off) ? sc[tid - off] : 0;
    __syncthreads();
    if (tid < 128) sc[tid] += v;
    __syncthreads();
  }
  if (tid < 128) {
    const int n = b * 128 + tid;
    if (n < NN) offsets[n + 1] = base + sc[tid];
    cur[tid] = sc[tid] - cnt[tid];
  }
  if (b == 0 && tid == 0) offsets[0] = 0;
  __syncthreads();
  for (int i = tid; i < Tb; i += 256) {
    const unsigned k = recs[i];
    const int p = atomicAdd(&cur[(k >> 16) & 127], 1);
    csr16[base + p] = (unsigned short)(k & 0xFFFFu);
  }
}

// ============ gemm2: Hb bf16 [NP][64] @ Wp2, 64 rows/block ============
__global__ __launch_bounds__(256) void gemm2(const short* __restrict__ Xb,
                                             const short* __restrict__ Wp,
                                             const float* __restrict__ B0,
                                             const float* __restrict__ B1,
                                             const float* __restrict__ B2,
                                             unsigned short* __restrict__ Y0,
                                             unsigned short* __restrict__ Y1,
                                             unsigned short* __restrict__ Y2) {
  const int lane = threadIdx.x & 63;
  const int wave = threadIdx.x >> 6;
  const int r0 = blockIdx.x * 64 + wave * 16;
  const int m = lane & 15;
  const int q = lane >> 4;
  f32x4 acc[3][4] = {};
  const short* a0 = Xb + (size_t)(r0 + m) * 64 + q * 8;
  const short* bp = Wp + lane * 8;
#pragma unroll
  for (int kb = 0; kb < 2; ++kb) {
    const s16x8 af0 = *reinterpret_cast<const s16x8*>(a0 + kb * 32);
#pragma unroll
    for (int w = 0; w < 3; ++w) {
#pragma unroll
      for (int t = 0; t < 4; ++t) {
        const s16x8 bf = *reinterpret_cast<const s16x8*>(
            bp + (size_t)((kb * 3 + w) * 4 + t) * 512);
        acc[w][t] = __builtin_amdgcn_mfma_f32_16x16x32_bf16(af0, bf, acc[w][t], 0, 0, 0);
      }
    }
  }
#pragma unroll
  for (int w = 0; w < 3; ++w) {
    const float* B = (w == 0) ? B0 : (w == 1) ? B1 : B2;
    unsigned short* Y = (w == 0) ? Y0 : (w == 1) ? Y1 : Y2;
#pragma unroll
    for (int t = 0; t < 4; ++t) {
      const int c = t * 16 + m;
      const float bv = (c < 40) ? B[c] : 0.f;
#pragma unroll
      for (int rg = 0; rg < 4; ++rg) {
        const int row = r0 + q * 4 + rg;
        if (row < NN)
          Y[(size_t)row * 64 + c] = (unsigned short)f2bf(acc[w][t][rg] + bv);
      }
    }
  }
}

// ====== GATv2 aggregation: 8 lanes/edge, 8 edges in flight, 16B gathers ======
template <int OC, bool FINAL>
__global__ __launch_bounds__(256) void gat_agg(const unsigned short* __restrict__ XL,
                                               const unsigned short* __restrict__ XR,
                                               const unsigned short* __restrict__ XLIN,
                                               const float* __restrict__ att,
                                               const float* __restrict__ bias,
                                               const int* __restrict__ offsets,
                                               const unsigned short* __restrict__ csr,
                                               float* __restrict__ out,
                                               unsigned short* __restrict__ outb) {
  const int lane = threadIdx.x & 63;
  const int g = lane >> 3;
  const int l = lane & 7;
  const int d = blockIdx.x * 4 + (threadIdx.x >> 6);
  if (d >= NN) return;
  const bool dimok = (8 * l < OC);
  float a[8] = {};
  if (dimok) {
    const float4 t0 = *reinterpret_cast<const float4*>(&att[8 * l]);
    const float4 t1 = *reinterpret_cast<const float4*>(&att[8 * l + 4]);
    a[0] = t0.x; a[1] = t0.y; a[2] = t0.z; a[3] = t0.w;
    a[4] = t1.x; a[5] = t1.y; a[6] = t1.z; a[7] = t1.w;
  }
  float xr[8];
  ldbf8(XR + (size_t)d * 64 + 8 * l, xr);
  const int beg = offsets[d];
  const int end = offsets[d + 1];
  float m = -1e30f, D = 0.f;
  float A[8] = {};
  const int nit = (end - beg + 7) >> 3;
  const int i0 = beg + g;
  int sa = (int)csr[(i0 < end) ? i0 : beg];
  for (int it = 0; it < nit; ++it) {
    const int icur = beg + it * 8 + g;
    const bool act = (icur < end);
    float xl[8];
    ldbf8(XL + (size_t)sa * 64 + 8 * l, xl);
    const int inext = icur + 8;
    sa = (int)csr[(inext < end) ? inext : beg];
    float p = 0.f;
#pragma unroll
    for (int j = 0; j < 8; ++j) {
      const float t = xl[j] + xr[j];
      const float lr = fmaxf(t, NEG_SLOPE * t);
      p = fmaf(lr, a[j], p);
    }
    p += __shfl_xor(p, 1, 64);
    p += __shfl_xor(p, 2, 64);
    p += __shfl_xor(p, 4, 64);
    const float e = act ? p : -3e38f;
    const float mn = fmaxf(m, e);
    const float c = __expf(m - mn);
    const float w = __expf(e - mn);
    D = fmaf(D, c, w);
#pragma unroll
    for (int j = 0; j < 8; ++j) A[j] = fmaf(A[j], c, w * xl[j]);
    m = mn;
  }
  float mw = fmaxf(m, __shfl_xor(m, 8, 64));
  mw = fmaxf(mw, __shfl_xor(mw, 16, 64));
  mw = fmaxf(mw, __shfl_xor(mw, 32, 64));
  const float sc = __expf(m - mw);
  float Dw = D * sc;
  Dw += __shfl_xor(Dw, 8, 64);
  Dw += __shfl_xor(Dw, 16, 64);
  Dw += __shfl_xor(Dw, 32, 64);
#pragma unroll
  for (int j = 0; j < 8; ++j) {
    float v = A[j] * sc;
    v += __shfl_xor(v, 8, 64);
    v += __shfl_xor(v, 16, 64);
    v += __shfl_xor(v, 32, 64);
    A[j] = v;
  }
  float xlin[8];
  ldbf8(XLIN + (size_t)d * 64 + 8 * l, xlin);
  float b[8] = {};
  if (dimok) {
    const float4 t0 = *reinterpret_cast<const float4*>(&bias[8 * l]);
    const float4 t1 = *reinterpret_cast<const float4*>(&bias[8 * l + 4]);
    b[0] = t0.x; b[1] = t0.y; b[2] = t0.z; b[3] = t0.w;
    b[4] = t1.x; b[5] = t1.y; b[6] = t1.z; b[7] = t1.w;
  }
  const float inv = 1.0f / Dw;
  float val[8];
#pragma unroll
  for (int j = 0; j < 8; ++j) val[j] = fmaf(A[j], inv, b[j]) + xlin[j];
  if (!FINAL) {
    if (g == 0) {
      uint4 o;
      o.x = pack2(fmaxf(val[0], 0.f), fmaxf(val[1], 0.f));
      o.y = pack2(fmaxf(val[2], 0.f), fmaxf(val[3], 0.f));
      o.z = pack2(fmaxf(val[4], 0.f), fmaxf(val[5], 0.f));
      o.w = pack2(fmaxf(val[6], 0.f), fmaxf(val[7], 0.f));
      *reinterpret_cast<uint4*>(&outb[(size_t)d * 64 + 8 * l]) = o;
    }
  } else {
    float mx = -3e38f;
    if (dimok) {
#pragma unroll
      for (int j = 0; j < 8; ++j) mx = fmaxf(mx, val[j]);
    }
    mx = fmaxf(mx, __shfl_xor(mx, 1, 64));
    mx = fmaxf(mx, __shfl_xor(mx, 2, 64));
    mx = fmaxf(mx, __shfl_xor(mx, 4, 64));
    float es = 0.f;
    if (dimok) {
#pragma unroll
      for (int j = 0; j < 8; ++j) es += __expf(val[j] - mx);
    }
    es += __shfl_xor(es, 1, 64);
    es += __shfl_xor(es, 2, 64);
    es += __shfl_xor(es, 4, 64);
    const float lse = mx + __logf(es);
    if (g == 0 && dimok) {
      float4 o0, o1;
      o0.x = val[0] - lse; o0.y = val[1] - lse; o0.z = val[2] - lse; o0.w = val[3] - lse;
      o1.x = val[4] - lse; o1.y = val[5] - lse; o1.z = val[6] - lse; o1.w = val[7] - lse;
      float* dst = &out[(size_t)d * OC + 8 * l];
      *reinterpret_cast<float4*>(dst) = o0;
      *reinterpret_cast<float4*>(dst + 4) = o1;
    }
  }
}

// ---------------- launch ----------------
extern "C" void kernel_launch(void* const* d_in, const int* in_sizes, int n_in,
                              void* d_out, int out_size, void* d_ws, size_t ws_size,
                              hipStream_t stream) {
  const float* x     = (const float*)d_in[0];
  const int*   ei    = (const int*)d_in[1];
  const float* W1l   = (const float*)d_in[2];
  const float* b1l   = (const float*)d_in[3];
  const float* W1r   = (const float*)d_in[4];
  const float* b1r   = (const float*)d_in[5];
  const float* att1  = (const float*)d_in[6];
  const float* bias1 = (const float*)d_in[7];
  const float* lin1W = (const float*)d_in[8];
  const float* lin1b = (const float*)d_in[9];
  const float* W2l   = (const float*)d_in[10];
  const float* b2l   = (const float*)d_in[11];
  const float* W2r   = (const float*)d_in[12];
  const float* b2r   = (const float*)d_in[13];
  const float* att2  = (const float*)d_in[14];
  const float* bias2 = (const float*)d_in[15];
  const float* lin2W = (const float*)d_in[16];
  const float* lin2b = (const float*)d_in[17];
  float* out = (float*)d_out;

  char* ws = (char*)d_ws;
  size_t off = 0;
  auto alloc = [&](size_t bytes) -> void* {
    void* p = ws + off;
    off += (bytes + 255) & ~(size_t)255;
    return p;
  };
  short* Wp1 = (short*)alloc((size_t)TB1 * 2);
  short* Wp2 = (short*)alloc((size_t)TB2 * 2);
  unsigned short* XL1   = (unsigned short*)alloc((size_t)NN * 64 * 2);
  unsigned short* XR1   = (unsigned short*)alloc((size_t)NN * 64 * 2);
  unsigned short* XLIN1 = (unsigned short*)alloc((size_t)NN * 64 * 2);
  unsigned short* Hb    = (unsigned short*)alloc((size_t)NP * 64 * 2);
  unsigned short* XL2   = (unsigned short*)alloc((size_t)NN * 64 * 2);
  unsigned short* XR2   = (unsigned short*)alloc((size_t)NN * 64 * 2);
  unsigned short* XLIN2 = (unsigned short*)alloc((size_t)NN * 64 * 2);
  int* gcur    = (int*)alloc((size_t)NBKT * 4);
  int* offsets = (int*)alloc((size_t)(NN + 1) * 4);
  unsigned* rec = (unsigned*)alloc((size_t)NBKT * BCAP * 4);
  unsigned short* csr = (unsigned short*)alloc((size_t)NITEMS * 2);

  hipMemsetAsync(gcur, 0, (size_t)NBKT * 4, stream);
  prep_bin<<<WPB + NCH, 256, 0, stream>>>(W1l, W1r, lin1W, W2l, W2r, lin2W,
                                          Wp1, Wp2, ei, out + (size_t)NN * CD,
                                          gcur, rec);
  build_gemm1<<<GB1 + NBKT, 256, 0, stream>>>(x, Wp1, b1l, b1r, lin1b,
                                              XL1, XR1, XLIN1, gcur, rec,
                                              offsets, csr);
  gat_agg<64, false><<<(NN + 3) / 4, 256, 0, stream>>>(XL1, XR1, XLIN1, att1,
                                                       bias1, offsets, csr,
                                                       nullptr, Hb);
  gemm2<<<GB1, 256, 0, stream>>>((const short*)Hb, Wp2, b2l, b2r, lin2b,
                                 XL2, XR2, XLIN2);
  gat_agg<40, true><<<(NN + 3) / 4, 256, 0, stream>>>(XL2, XR2, XLIN2, att2,
                                                      bias2, offsets, csr,
                                                      out, nullptr);
}

// Round 9
// 243.836 us; speedup vs baseline: 2.7350x; 1.0071x over previous
//
#include <hip/hip_runtime.h>
#include <cmath>

#define NN 50000
#define NP 50048
#define NE 800000
#define CD 40
#define NEG_SLOPE 0.2f
#define NITEMS (NE + NN)   // edges + self-loops
#define CHUNK 2048
#define NCH 416            // ceil(NITEMS / CHUNK)
#define NBKT 391           // node buckets of 128 (covers 50048)
#define BCAP 3072          // bucket capacity (mean 2174, +19 sigma)
#define GB1 782            // gemm blocks, 64 rows each (NP/64)
#define TB1 (3 * 64 * 256)
#define TB2 (3 * 64 * 64)
#define WPB 240            // W-pack blocks ((TB1+TB2)/256)

typedef __attribute__((ext_vector_type(8))) short s16x8;   // 8 bf16
typedef __attribute__((ext_vector_type(4))) float f32x4;   // 4 fp32 acc
typedef __attribute__((ext_vector_type(2))) float f32x2;   // packed-math pair

__device__ __forceinline__ f32x2 pk_fma(f32x2 a, f32x2 b, f32x2 c) {
#if __has_builtin(__builtin_elementwise_fma)
  return __builtin_elementwise_fma(a, b, c);
#else
  f32x2 r; r[0] = fmaf(a[0], b[0], c[0]); r[1] = fmaf(a[1], b[1], c[1]); return r;
#endif
}
__device__ __forceinline__ f32x2 pk_max(f32x2 a, f32x2 b) {
#if __has_builtin(__builtin_elementwise_max)
  return __builtin_elementwise_max(a, b);
#else
  f32x2 r; r[0] = fmaxf(a[0], b[0]); r[1] = fmaxf(a[1], b[1]); return r;
#endif
}

__device__ __forceinline__ short f2bf(float x) {  // RNE, finite
  unsigned u = __builtin_bit_cast(unsigned, x);
  u += 0x7fffu + ((u >> 16) & 1u);
  return (short)(u >> 16);
}
__device__ __forceinline__ unsigned pack2(float lo, float hi) {
  return (unsigned)(unsigned short)f2bf(lo) | ((unsigned)(unsigned short)f2bf(hi) << 16);
}
__device__ __forceinline__ float bf2f_lo(unsigned v) {
  return __builtin_bit_cast(float, v << 16);
}
__device__ __forceinline__ float bf2f_hi(unsigned v) {
  return __builtin_bit_cast(float, v & 0xffff0000u);
}
// load 8 bf16 (16B) -> 4 x f32x2
__device__ __forceinline__ void ldbf8v(const unsigned short* p, f32x2* f) {
  const uint4 v = *reinterpret_cast<const uint4*>(p);
  f[0] = (f32x2){bf2f_lo(v.x), bf2f_hi(v.x)};
  f[1] = (f32x2){bf2f_lo(v.y), bf2f_hi(v.y)};
  f[2] = (f32x2){bf2f_lo(v.z), bf2f_hi(v.z)};
  f[3] = (f32x2){bf2f_lo(v.w), bf2f_hi(v.w)};
}

// ====== prep_bin: W frag-pack (blocks 0..239) | edge binning (blocks 240..) ======
__global__ __launch_bounds__(256) void prep_bin(const float* __restrict__ W1l,
                                                const float* __restrict__ W1r,
                                                const float* __restrict__ L1,
                                                const float* __restrict__ W2l,
                                                const float* __restrict__ W2r,
                                                const float* __restrict__ L2,
                                                short* __restrict__ Wp1,
                                                short* __restrict__ Wp2,
                                                const int* __restrict__ ei,
                                                float* __restrict__ outE,
                                                int* __restrict__ gcur,
                                                unsigned* __restrict__ rec) {
  const int tid = threadIdx.x;
  if (blockIdx.x < WPB) {  // W pack: [kb][w][t][lane][j]
    int e = blockIdx.x * 256 + tid;
    if (e < TB1) {  // layer 1: K=256, OC=64, src [256][64]
      int kb = e / 6144, r = e % 6144;
      int w = r / 2048, r2 = r % 2048;
      int t = r2 / 512, r3 = r2 % 512;
      int lane = r3 / 8, j = r3 % 8;
      int n = t * 16 + (lane & 15);
      int k = kb * 32 + (lane >> 4) * 8 + j;
      const float* W = (w == 0) ? W1l : (w == 1) ? W1r : L1;
      Wp1[e] = f2bf(W[k * 64 + n]);
    } else {  // layer 2: K=64, OC=40 pad 64
      e -= TB1;
      int kb = e / 6144, r = e % 6144;
      int w = r / 2048, r2 = r % 2048;
      int t = r2 / 512, r3 = r2 % 512;
      int lane = r3 / 8, j = r3 % 8;
      int n = t * 16 + (lane & 15);
      int k = kb * 32 + (lane >> 4) * 8 + j;
      const float* W = (w == 0) ? W2l : (w == 1) ? W2r : L2;
      Wp2[e] = (n < 40) ? f2bf(W[k * 40 + n]) : (short)0;
    }
    return;
  }
  // ---- Phase A: LDS-sort chunk by bucket dst>>7, one aggregated atomic per
  // (block,bucket), bucket-grouped record writes. ----
  __shared__ unsigned sorted[CHUNK];
  __shared__ int hist[512];
  __shared__ int bcur[512];
  __shared__ int gbase[512];
  const int base = (blockIdx.x - WPB) * CHUNK;
  for (int t = tid; t < 512; t += 256) { hist[t] = 0; bcur[t] = 0; gbase[t] = 0; }
  __syncthreads();
  unsigned key[CHUNK / 256];
#pragma unroll
  for (int u = 0; u < CHUNK / 256; ++u) {
    const int j = base + u * 256 + tid;
    unsigned k = 0xFFFFFFFFu;
    if (j < NITEMS) {
      int s, d;
      if (j < NE) {
        s = ei[j]; d = ei[NE + j];
        outE[j] = (float)s; outE[NE + j] = (float)d;
      } else {
        s = j - NE; d = s;
      }
      k = ((unsigned)d << 16) | (unsigned)s;
      atomicAdd(&hist[k >> 23], 1);
    }
    key[u] = k;
  }
  __syncthreads();
  if (tid < 64) {  // exclusive scan hist[0..511], one wave
    int carry = 0;
#pragma unroll
    for (int c = 0; c < 8; ++c) {
      int v = hist[c * 64 + tid];
      int inc = v;
#pragma unroll
      for (int off = 1; off < 64; off <<= 1) {
        int tt = __shfl_up(inc, off, 64);
        if (tid >= off) inc += tt;
      }
      hist[c * 64 + tid] = carry + inc - v;
      carry += __shfl(inc, 63, 64);
    }
  }
  __syncthreads();
#pragma unroll
  for (int u = 0; u < CHUNK / 256; ++u) {
    const unsigned k = key[u];
    if (k != 0xFFFFFFFFu) {
      const int b = k >> 23;
      sorted[hist[b] + atomicAdd(&bcur[b], 1)] = k;
    }
  }
  __syncthreads();
  for (int t = tid; t < NBKT; t += 256) {
    const int c = bcur[t];
    if (c > 0) gbase[t] = atomicAdd(&gcur[t], c);
  }
  __syncthreads();
  const int cnt = min(CHUNK, NITEMS - base);
  for (int i = tid; i < cnt; i += 256) {
    const unsigned k = sorted[i];
    const int b = k >> 23;
    const int p = gbase[b] + (i - hist[b]);
    if (p < BCAP) rec[(size_t)b * BCAP + p] = k;
  }
}

// ================= gemm1 body: 64 rows/block, 16 rows/wave =================
__device__ __forceinline__ void gemm1_body(int bid, const float* __restrict__ X,
                                           const short* __restrict__ Wp,
                                           const float* __restrict__ B0,
                                           const float* __restrict__ B1,
                                           const float* __restrict__ B2,
                                           unsigned short* __restrict__ Y0,
                                           unsigned short* __restrict__ Y1,
                                           unsigned short* __restrict__ Y2) {
  const int lane = threadIdx.x & 63;
  const int wave = threadIdx.x >> 6;
  const int r0 = bid * 64 + wave * 16;
  const int m = lane & 15;
  const int q = lane >> 4;
  f32x4 acc[3][4] = {};
  const float* a0 = X + (size_t)min(r0 + m, NN - 1) * 256 + q * 8;
  const short* bp = Wp + lane * 8;
#pragma unroll
  for (int kb = 0; kb < 8; ++kb) {
    const float4 v0 = *reinterpret_cast<const float4*>(a0 + kb * 32);
    const float4 v1 = *reinterpret_cast<const float4*>(a0 + kb * 32 + 4);
    s16x8 af0;
    af0[0] = f2bf(v0.x); af0[1] = f2bf(v0.y); af0[2] = f2bf(v0.z); af0[3] = f2bf(v0.w);
    af0[4] = f2bf(v1.x); af0[5] = f2bf(v1.y); af0[6] = f2bf(v1.z); af0[7] = f2bf(v1.w);
#pragma unroll
    for (int w = 0; w < 3; ++w) {
#pragma unroll
      for (int t = 0; t < 4; ++t) {
        const s16x8 bf = *reinterpret_cast<const s16x8*>(
            bp + (size_t)((kb * 3 + w) * 4 + t) * 512);
        acc[w][t] = __builtin_amdgcn_mfma_f32_16x16x32_bf16(af0, bf, acc[w][t], 0, 0, 0);
      }
    }
  }
#pragma unroll
  for (int w = 0; w < 3; ++w) {
    const float* B = (w == 0) ? B0 : (w == 1) ? B1 : B2;
    unsigned short* Y = (w == 0) ? Y0 : (w == 1) ? Y1 : Y2;
#pragma unroll
    for (int t = 0; t < 4; ++t) {
      const int c = t * 16 + m;
      const float bv = B[c];
#pragma unroll
      for (int rg = 0; rg < 4; ++rg) {
        const int row = r0 + q * 4 + rg;
        if (row < NN)
          Y[(size_t)row * 64 + c] = (unsigned short)f2bf(acc[w][t][rg] + bv);
      }
    }
  }
}

// ====== build_gemm1: gemm1 (blocks 0..781) | CSR Phase B (blocks 782..1172) ======
__global__ __launch_bounds__(256, 2) void build_gemm1(
    const float* __restrict__ X, const short* __restrict__ Wp1,
    const float* __restrict__ B0, const float* __restrict__ B1,
    const float* __restrict__ B2, unsigned short* __restrict__ Y0,
    unsigned short* __restrict__ Y1, unsigned short* __restrict__ Y2,
    const int* __restrict__ gcur, const unsigned* __restrict__ rec,
    int* __restrict__ offsets, unsigned short* __restrict__ csr16) {
  if (blockIdx.x < GB1) {
    gemm1_body(blockIdx.x, X, Wp1, B0, B1, B2, Y0, Y1, Y2);
    return;
  }
  const int b = blockIdx.x - GB1;
  const int tid = threadIdx.x;
  __shared__ unsigned recs[BCAP];
  __shared__ int red[256];
  __shared__ int cnt[128];
  __shared__ int sc[128];
  __shared__ int cur[128];
  int acc = 0;
  for (int t = tid; t < NBKT; t += 256)
    if (t < b) acc += gcur[t];
  red[tid] = acc;
  __syncthreads();
#pragma unroll
  for (int off = 128; off >= 1; off >>= 1) {
    if (tid < off) red[tid] += red[tid + off];
    __syncthreads();
  }
  const int base = red[0];
  const int Tb = min(gcur[b], BCAP);
  if (tid < 128) cnt[tid] = 0;
  __syncthreads();
  for (int i = tid; i < Tb; i += 256) {
    const unsigned k = rec[(size_t)b * BCAP + i];
    recs[i] = k;
    atomicAdd(&cnt[(k >> 16) & 127], 1);
  }
  __syncthreads();
  if (tid < 128) sc[tid] = cnt[tid];
  __syncthreads();
#pragma unroll
  for (int off = 1; off < 128; off <<= 1) {
    int v = (tid < 128 && tid >= off) ? sc[tid - off] : 0;
    __syncthreads();
    if (tid < 128) sc[tid] += v;
    __syncthreads();
  }
  if (tid < 128) {
    const int n = b * 128 + tid;
    if (n < NN) offsets[n + 1] = base + sc[tid];
    cur[tid] = sc[tid] - cnt[tid];
  }
  if (b == 0 && tid == 0) offsets[0] = 0;
  __syncthreads();
  for (int i = tid; i < Tb; i += 256) {
    const unsigned k = recs[i];
    const int p = atomicAdd(&cur[(k >> 16) & 127], 1);
    csr16[base + p] = (unsigned short)(k & 0xFFFFu);
  }
}

// ============ gemm2: Hb bf16 [NP][64] @ Wp2, 64 rows/block ============
__global__ __launch_bounds__(256) void gemm2(const short* __restrict__ Xb,
                                             const short* __restrict__ Wp,
                                             const float* __restrict__ B0,
                                             const float* __restrict__ B1,
                                             const float* __restrict__ B2,
                                             unsigned short* __restrict__ Y0,
                                             unsigned short* __restrict__ Y1,
                                             unsigned short* __restrict__ Y2) {
  const int lane = threadIdx.x & 63;
  const int wave = threadIdx.x >> 6;
  const int r0 = blockIdx.x * 64 + wave * 16;
  const int m = lane & 15;
  const int q = lane >> 4;
  f32x4 acc[3][4] = {};
  const short* a0 = Xb + (size_t)(r0 + m) * 64 + q * 8;
  const short* bp = Wp + lane * 8;
#pragma unroll
  for (int kb = 0; kb < 2; ++kb) {
    const s16x8 af0 = *reinterpret_cast<const s16x8*>(a0 + kb * 32);
#pragma unroll
    for (int w = 0; w < 3; ++w) {
#pragma unroll
      for (int t = 0; t < 4; ++t) {
        const s16x8 bf = *reinterpret_cast<const s16x8*>(
            bp + (size_t)((kb * 3 + w) * 4 + t) * 512);
        acc[w][t] = __builtin_amdgcn_mfma_f32_16x16x32_bf16(af0, bf, acc[w][t], 0, 0, 0);
      }
    }
  }
#pragma unroll
  for (int w = 0; w < 3; ++w) {
    const float* B = (w == 0) ? B0 : (w == 1) ? B1 : B2;
    unsigned short* Y = (w == 0) ? Y0 : (w == 1) ? Y1 : Y2;
#pragma unroll
    for (int t = 0; t < 4; ++t) {
      const int c = t * 16 + m;
      const float bv = (c < 40) ? B[c] : 0.f;
#pragma unroll
      for (int rg = 0; rg < 4; ++rg) {
        const int row = r0 + q * 4 + rg;
        if (row < NN)
          Y[(size_t)row * 64 + c] = (unsigned short)f2bf(acc[w][t][rg] + bv);
      }
    }
  }
}

// ====== GATv2 aggregation: 8 lanes/edge, 8 edges in flight, packed fp32 ======
// No-max softmax: logits are O(20) worst-case -> exp() safely in fp32 range;
// mathematically identical to reference's shifted segment softmax.
template <int OC, bool FINAL>
__global__ __launch_bounds__(256) void gat_agg(const unsigned short* __restrict__ XL,
                                               const unsigned short* __restrict__ XR,
                                               const unsigned short* __restrict__ XLIN,
                                               const float* __restrict__ att,
                                               const float* __restrict__ bias,
                                               const int* __restrict__ offsets,
                                               const unsigned short* __restrict__ csr,
                                               float* __restrict__ out,
                                               unsigned short* __restrict__ outb) {
  const int lane = threadIdx.x & 63;
  const int g = lane >> 3;
  const int l = lane & 7;
  const int d = blockIdx.x * 4 + (threadIdx.x >> 6);
  if (d >= NN) return;
  const bool dimok = (8 * l < OC);
  f32x2 a2[4] = {};
  if (dimok) {
    const float4 t0 = *reinterpret_cast<const float4*>(&att[8 * l]);
    const float4 t1 = *reinterpret_cast<const float4*>(&att[8 * l + 4]);
    a2[0] = (f32x2){t0.x, t0.y}; a2[1] = (f32x2){t0.z, t0.w};
    a2[2] = (f32x2){t1.x, t1.y}; a2[3] = (f32x2){t1.z, t1.w};
  }
  f32x2 xr2[4];
  ldbf8v(XR + (size_t)d * 64 + 8 * l, xr2);
  const int beg = offsets[d];
  const int end = offsets[d + 1];
  float D = 0.f;
  f32x2 A2[4] = {};
  const f32x2 ns = (f32x2){NEG_SLOPE, NEG_SLOPE};
  const int nit = (end - beg + 7) >> 3;
  const int i0 = beg + g;
  int sa = (int)csr[(i0 < end) ? i0 : beg];
  for (int it = 0; it < nit; ++it) {
    const int icur = beg + it * 8 + g;
    const bool act = (icur < end);
    f32x2 xl2[4];
    ldbf8v(XL + (size_t)sa * 64 + 8 * l, xl2);
    const int inext = icur + 8;
    sa = (int)csr[(inext < end) ? inext : beg];
    f32x2 pacc = (f32x2){0.f, 0.f};
#pragma unroll
    for (int j = 0; j < 4; ++j) {
      const f32x2 t = xl2[j] + xr2[j];
      const f32x2 lr = pk_max(t, t * ns);
      pacc = pk_fma(lr, a2[j], pacc);
    }
    float p = pacc[0] + pacc[1];
    p += __shfl_xor(p, 1, 64);
    p += __shfl_xor(p, 2, 64);
    p += __shfl_xor(p, 4, 64);          // group-uniform logit
    const float w = __expf(act ? p : -INFINITY);  // 0 for inactive slots
    D += w;
    const f32x2 w2 = (f32x2){w, w};
#pragma unroll
    for (int j = 0; j < 4; ++j) A2[j] = pk_fma(w2, xl2[j], A2[j]);
  }
  // merge the 8 group states: plain sums (no rescale needed)
  D += __shfl_xor(D, 8, 64);
  D += __shfl_xor(D, 16, 64);
  D += __shfl_xor(D, 32, 64);
  float A[8];
#pragma unroll
  for (int j = 0; j < 4; ++j) {
#pragma unroll
    for (int c = 0; c < 2; ++c) {
      float v = A2[j][c];
      v += __shfl_xor(v, 8, 64);
      v += __shfl_xor(v, 16, 64);
      v += __shfl_xor(v, 32, 64);
      A[j * 2 + c] = v;
    }
  }
  f32x2 xlin2[4];
  ldbf8v(XLIN + (size_t)d * 64 + 8 * l, xlin2);
  float b[8] = {};
  if (dimok) {
    const float4 t0 = *reinterpret_cast<const float4*>(&bias[8 * l]);
    const float4 t1 = *reinterpret_cast<const float4*>(&bias[8 * l + 4]);
    b[0] = t0.x; b[1] = t0.y; b[2] = t0.z; b[3] = t0.w;
    b[4] = t1.x; b[5] = t1.y; b[6] = t1.z; b[7] = t1.w;
  }
  const float inv = 1.0f / D;  // D > 0 (self-loop)
  float val[8];
#pragma unroll
  for (int j = 0; j < 8; ++j)
    val[j] = fmaf(A[j], inv, b[j]) + xlin2[j >> 1][j & 1];
  if (!FINAL) {
    if (g == 0) {
      uint4 o;
      o.x = pack2(fmaxf(val[0], 0.f), fmaxf(val[1], 0.f));
      o.y = pack2(fmaxf(val[2], 0.f), fmaxf(val[3], 0.f));
      o.z = pack2(fmaxf(val[4], 0.f), fmaxf(val[5], 0.f));
      o.w = pack2(fmaxf(val[6], 0.f), fmaxf(val[7], 0.f));
      *reinterpret_cast<uint4*>(&outb[(size_t)d * 64 + 8 * l]) = o;
    }
  } else {
    float mx = -3e38f;
    if (dimok) {
#pragma unroll
      for (int j = 0; j < 8; ++j) mx = fmaxf(mx, val[j]);
    }
    mx = fmaxf(mx, __shfl_xor(mx, 1, 64));
    mx = fmaxf(mx, __shfl_xor(mx, 2, 64));
    mx = fmaxf(mx, __shfl_xor(mx, 4, 64));
    float es = 0.f;
    if (dimok) {
#pragma unroll
      for (int j = 0; j < 8; ++j) es += __expf(val[j] - mx);
    }
    es += __shfl_xor(es, 1, 64);
    es += __shfl_xor(es, 2, 64);
    es += __shfl_xor(es, 4, 64);
    const float lse = mx + __logf(es);
    if (g == 0 && dimok) {
      float4 o0, o1;
      o0.x = val[0] - lse; o0.y = val[1] - lse; o0.z = val[2] - lse; o0.w = val[3] - lse;
      o1.x = val[4] - lse; o1.y = val[5] - lse; o1.z = val[6] - lse; o1.w = val[7] - lse;
      float* dst = &out[(size_t)d * OC + 8 * l];
      *reinterpret_cast<float4*>(dst) = o0;
      *reinterpret_cast<float4*>(dst + 4) = o1;
    }
  }
}

// ---------------- launch ----------------
extern "C" void kernel_launch(void* const* d_in, const int* in_sizes, int n_in,
                              void* d_out, int out_size, void* d_ws, size_t ws_size,
                              hipStream_t stream) {
  const float* x     = (const float*)d_in[0];
  const int*   ei    = (const int*)d_in[1];
  const float* W1l   = (const float*)d_in[2];
  const float* b1l   = (const float*)d_in[3];
  const float* W1r   = (const float*)d_in[4];
  const float* b1r   = (const float*)d_in[5];
  const float* att1  = (const float*)d_in[6];
  const float* bias1 = (const float*)d_in[7];
  const float* lin1W = (const float*)d_in[8];
  const float* lin1b = (const float*)d_in[9];
  const float* W2l   = (const float*)d_in[10];
  const float* b2l   = (const float*)d_in[11];
  const float* W2r   = (const float*)d_in[12];
  const float* b2r   = (const float*)d_in[13];
  const float* att2  = (const float*)d_in[14];
  const float* bias2 = (const float*)d_in[15];
  const float* lin2W = (const float*)d_in[16];
  const float* lin2b = (const float*)d_in[17];
  float* out = (float*)d_out;

  char* ws = (char*)d_ws;
  size_t off = 0;
  auto alloc = [&](size_t bytes) -> void* {
    void* p = ws + off;
    off += (bytes + 255) & ~(size_t)255;
    return p;
  };
  short* Wp1 = (short*)alloc((size_t)TB1 * 2);
  short* Wp2 = (short*)alloc((size_t)TB2 * 2);
  unsigned short* XL1   = (unsigned short*)alloc((size_t)NN * 64 * 2);
  unsigned short* XR1   = (unsigned short*)alloc((size_t)NN * 64 * 2);
  unsigned short* XLIN1 = (unsigned short*)alloc((size_t)NN * 64 * 2);
  unsigned short* Hb    = (unsigned short*)alloc((size_t)NP * 64 * 2);
  unsigned short* XL2   = (unsigned short*)alloc((size_t)NN * 64 * 2);
  unsigned short* XR2   = (unsigned short*)alloc((size_t)NN * 64 * 2);
  unsigned short* XLIN2 = (unsigned short*)alloc((size_t)NN * 64 * 2);
  int* gcur    = (int*)alloc((size_t)NBKT * 4);
  int* offsets = (int*)alloc((size_t)(NN + 1) * 4);
  unsigned* rec = (unsigned*)alloc((size_t)NBKT * BCAP * 4);
  unsigned short* csr = (unsigned short*)alloc((size_t)NITEMS * 2);

  hipMemsetAsync(gcur, 0, (size_t)NBKT * 4, stream);
  prep_bin<<<WPB + NCH, 256, 0, stream>>>(W1l, W1r, lin1W, W2l, W2r, lin2W,
                                          Wp1, Wp2, ei, out + (size_t)NN * CD,
                                          gcur, rec);
  build_gemm1<<<GB1 + NBKT, 256, 0, stream>>>(x, Wp1, b1l, b1r, lin1b,
                                              XL1, XR1, XLIN1, gcur, rec,
                                              offsets, csr);
  gat_agg<64, false><<<(NN + 3) / 4, 256, 0, stream>>>(XL1, XR1, XLIN1, att1,
                                                       bias1, offsets, csr,
                                                       nullptr, Hb);
  gemm2<<<GB1, 256, 0, stream>>>((const short*)Hb, Wp2, b2l, b2r, lin2b,
                                 XL2, XR2, XLIN2);
  gat_agg<40, true><<<(NN + 3) / 4, 256, 0, stream>>>(XL2, XR2, XLIN2, att2,
                                                      bias2, offsets, csr,
                                                      out, nullptr);
}

// Round 10
// 234.359 us; speedup vs baseline: 2.8455x; 1.0404x over previous
//
#include <hip/hip_runtime.h>
#include <cmath>

#define NN 50000
#define NP 50048
#define NE 800000
#define CD 40
#define NEG_SLOPE 0.2f
#define NITEMS (NE + NN)   // edges + self-loops
#define CHUNK 2048
#define NCH 416            // ceil(NITEMS / CHUNK)
#define NBKT 391           // node buckets of 128 (covers 50048)
#define BCAP 3072          // bucket capacity (mean 2174, +19 sigma)
#define GB1 782            // gemm blocks, 64 rows each (NP/64)
#define TB1 (3 * 64 * 256)
#define TB2 (3 * 64 * 64)
#define WPB 240            // W-pack blocks ((TB1+TB2)/256)

typedef __attribute__((ext_vector_type(8))) short s16x8;   // 8 bf16
typedef __attribute__((ext_vector_type(4))) float f32x4;   // 4 fp32 acc
typedef __attribute__((ext_vector_type(2))) float f32x2;   // packed-math pair

__device__ __forceinline__ f32x2 pk_fma(f32x2 a, f32x2 b, f32x2 c) {
#if __has_builtin(__builtin_elementwise_fma)
  return __builtin_elementwise_fma(a, b, c);
#else
  f32x2 r; r[0] = fmaf(a[0], b[0], c[0]); r[1] = fmaf(a[1], b[1], c[1]); return r;
#endif
}
__device__ __forceinline__ f32x2 pk_max(f32x2 a, f32x2 b) {
#if __has_builtin(__builtin_elementwise_max)
  return __builtin_elementwise_max(a, b);
#else
  f32x2 r; r[0] = fmaxf(a[0], b[0]); r[1] = fmaxf(a[1], b[1]); return r;
#endif
}

__device__ __forceinline__ short f2bf(float x) {  // RNE, finite
  unsigned u = __builtin_bit_cast(unsigned, x);
  u += 0x7fffu + ((u >> 16) & 1u);
  return (short)(u >> 16);
}
__device__ __forceinline__ unsigned pack2(float lo, float hi) {
  return (unsigned)(unsigned short)f2bf(lo) | ((unsigned)(unsigned short)f2bf(hi) << 16);
}
__device__ __forceinline__ float bf2f_lo(unsigned v) {
  return __builtin_bit_cast(float, v << 16);
}
__device__ __forceinline__ float bf2f_hi(unsigned v) {
  return __builtin_bit_cast(float, v & 0xffff0000u);
}
__device__ __forceinline__ void unp8(uint4 v, f32x2* f) {
  f[0] = (f32x2){bf2f_lo(v.x), bf2f_hi(v.x)};
  f[1] = (f32x2){bf2f_lo(v.y), bf2f_hi(v.y)};
  f[2] = (f32x2){bf2f_lo(v.z), bf2f_hi(v.z)};
  f[3] = (f32x2){bf2f_lo(v.w), bf2f_hi(v.w)};
}

// ====== prep_bin: W frag-pack (blocks 0..239) | edge binning (blocks 240..) ======
__global__ __launch_bounds__(256) void prep_bin(const float* __restrict__ W1l,
                                                const float* __restrict__ W1r,
                                                const float* __restrict__ L1,
                                                const float* __restrict__ W2l,
                                                const float* __restrict__ W2r,
                                                const float* __restrict__ L2,
                                                short* __restrict__ Wp1,
                                                short* __restrict__ Wp2,
                                                const int* __restrict__ ei,
                                                float* __restrict__ outE,
                                                int* __restrict__ gcur,
                                                unsigned* __restrict__ rec) {
  const int tid = threadIdx.x;
  if (blockIdx.x < WPB) {  // W pack: [kb][w][t][lane][j]
    int e = blockIdx.x * 256 + tid;
    if (e < TB1) {  // layer 1: K=256, OC=64, src [256][64]
      int kb = e / 6144, r = e % 6144;
      int w = r / 2048, r2 = r % 2048;
      int t = r2 / 512, r3 = r2 % 512;
      int lane = r3 / 8, j = r3 % 8;
      int n = t * 16 + (lane & 15);
      int k = kb * 32 + (lane >> 4) * 8 + j;
      const float* W = (w == 0) ? W1l : (w == 1) ? W1r : L1;
      Wp1[e] = f2bf(W[k * 64 + n]);
    } else {  // layer 2: K=64, OC=40 pad 64
      e -= TB1;
      int kb = e / 6144, r = e % 6144;
      int w = r / 2048, r2 = r % 2048;
      int t = r2 / 512, r3 = r2 % 512;
      int lane = r3 / 8, j = r3 % 8;
      int n = t * 16 + (lane & 15);
      int k = kb * 32 + (lane >> 4) * 8 + j;
      const float* W = (w == 0) ? W2l : (w == 1) ? W2r : L2;
      Wp2[e] = (n < 40) ? f2bf(W[k * 40 + n]) : (short)0;
    }
    return;
  }
  // ---- Phase A ----
  __shared__ unsigned sorted[CHUNK];
  __shared__ int hist[512];
  __shared__ int bcur[512];
  __shared__ int gbase[512];
  const int base = (blockIdx.x - WPB) * CHUNK;
  for (int t = tid; t < 512; t += 256) { hist[t] = 0; bcur[t] = 0; gbase[t] = 0; }
  __syncthreads();
  unsigned key[CHUNK / 256];
#pragma unroll
  for (int u = 0; u < CHUNK / 256; ++u) {
    const int j = base + u * 256 + tid;
    unsigned k = 0xFFFFFFFFu;
    if (j < NITEMS) {
      int s, d;
      if (j < NE) {
        s = ei[j]; d = ei[NE + j];
        outE[j] = (float)s; outE[NE + j] = (float)d;
      } else {
        s = j - NE; d = s;
      }
      k = ((unsigned)d << 16) | (unsigned)s;
      atomicAdd(&hist[k >> 23], 1);
    }
    key[u] = k;
  }
  __syncthreads();
  if (tid < 64) {  // exclusive scan hist[0..511], one wave
    int carry = 0;
#pragma unroll
    for (int c = 0; c < 8; ++c) {
      int v = hist[c * 64 + tid];
      int inc = v;
#pragma unroll
      for (int off = 1; off < 64; off <<= 1) {
        int tt = __shfl_up(inc, off, 64);
        if (tid >= off) inc += tt;
      }
      hist[c * 64 + tid] = carry + inc - v;
      carry += __shfl(inc, 63, 64);
    }
  }
  __syncthreads();
#pragma unroll
  for (int u = 0; u < CHUNK / 256; ++u) {
    const unsigned k = key[u];
    if (k != 0xFFFFFFFFu) {
      const int b = k >> 23;
      sorted[hist[b] + atomicAdd(&bcur[b], 1)] = k;
    }
  }
  __syncthreads();
  for (int t = tid; t < NBKT; t += 256) {
    const int c = bcur[t];
    if (c > 0) gbase[t] = atomicAdd(&gcur[t], c);
  }
  __syncthreads();
  const int cnt = min(CHUNK, NITEMS - base);
  for (int i = tid; i < cnt; i += 256) {
    const unsigned k = sorted[i];
    const int b = k >> 23;
    const int p = gbase[b] + (i - hist[b]);
    if (p < BCAP) rec[(size_t)b * BCAP + p] = k;
  }
}

// ================= gemm1 body: 64 rows/block, 16 rows/wave =================
// 12-deep B-frag load batch (bf[12] regs) + A prefetch for k-step pipelining.
__device__ __forceinline__ void gemm1_body(int bid, const float* __restrict__ X,
                                           const short* __restrict__ Wp,
                                           const float* __restrict__ B0,
                                           const float* __restrict__ B1,
                                           const float* __restrict__ B2,
                                           unsigned short* __restrict__ Y0,
                                           unsigned short* __restrict__ Y1,
                                           unsigned short* __restrict__ Y2) {
  const int lane = threadIdx.x & 63;
  const int wave = threadIdx.x >> 6;
  const int r0 = bid * 64 + wave * 16;
  const int m = lane & 15;
  const int q = lane >> 4;
  f32x4 acc[3][4] = {};
  const float* a0 = X + (size_t)min(r0 + m, NN - 1) * 256 + q * 8;
  const short* bp = Wp + lane * 8;
  float4 v0 = *reinterpret_cast<const float4*>(a0);
  float4 v1 = *reinterpret_cast<const float4*>(a0 + 4);
#pragma unroll
  for (int kb = 0; kb < 8; ++kb) {
    s16x8 bf[12];
#pragma unroll
    for (int i = 0; i < 12; ++i)  // 12 independent loads, batched
      bf[i] = *reinterpret_cast<const s16x8*>(bp + (size_t)(kb * 12 + i) * 512);
    s16x8 af;
    af[0] = f2bf(v0.x); af[1] = f2bf(v0.y); af[2] = f2bf(v0.z); af[3] = f2bf(v0.w);
    af[4] = f2bf(v1.x); af[5] = f2bf(v1.y); af[6] = f2bf(v1.z); af[7] = f2bf(v1.w);
    if (kb < 7) {  // prefetch next A step before the MFMA burst
      v0 = *reinterpret_cast<const float4*>(a0 + (kb + 1) * 32);
      v1 = *reinterpret_cast<const float4*>(a0 + (kb + 1) * 32 + 4);
    }
#pragma unroll
    for (int i = 0; i < 12; ++i)
      acc[i >> 2][i & 3] = __builtin_amdgcn_mfma_f32_16x16x32_bf16(
          af, bf[i], acc[i >> 2][i & 3], 0, 0, 0);
  }
#pragma unroll
  for (int w = 0; w < 3; ++w) {
    const float* B = (w == 0) ? B0 : (w == 1) ? B1 : B2;
    unsigned short* Y = (w == 0) ? Y0 : (w == 1) ? Y1 : Y2;
#pragma unroll
    for (int t = 0; t < 4; ++t) {
      const int c = t * 16 + m;
      const float bv = B[c];
#pragma unroll
      for (int rg = 0; rg < 4; ++rg) {
        const int row = r0 + q * 4 + rg;
        if (row < NN)
          Y[(size_t)row * 64 + c] = (unsigned short)f2bf(acc[w][t][rg] + bv);
      }
    }
  }
}

// ====== build_gemm1: gemm1 (blocks 0..781) | CSR Phase B (blocks 782..1172) ======
__global__ __launch_bounds__(256, 2) void build_gemm1(
    const float* __restrict__ X, const short* __restrict__ Wp1,
    const float* __restrict__ B0, const float* __restrict__ B1,
    const float* __restrict__ B2, unsigned short* __restrict__ Y0,
    unsigned short* __restrict__ Y1, unsigned short* __restrict__ Y2,
    const int* __restrict__ gcur, const unsigned* __restrict__ rec,
    int* __restrict__ offsets, unsigned short* __restrict__ csr16) {
  if (blockIdx.x < GB1) {
    gemm1_body(blockIdx.x, X, Wp1, B0, B1, B2, Y0, Y1, Y2);
    return;
  }
  const int b = blockIdx.x - GB1;
  const int tid = threadIdx.x;
  __shared__ unsigned recs[BCAP];
  __shared__ int red[256];
  __shared__ int cnt[128];
  __shared__ int sc[128];
  __shared__ int cur[128];
  int acc = 0;
  for (int t = tid; t < NBKT; t += 256)
    if (t < b) acc += gcur[t];
  red[tid] = acc;
  __syncthreads();
#pragma unroll
  for (int off = 128; off >= 1; off >>= 1) {
    if (tid < off) red[tid] += red[tid + off];
    __syncthreads();
  }
  const int base = red[0];
  const int Tb = min(gcur[b], BCAP);
  if (tid < 128) cnt[tid] = 0;
  __syncthreads();
  for (int i = tid; i < Tb; i += 256) {
    const unsigned k = rec[(size_t)b * BCAP + i];
    recs[i] = k;
    atomicAdd(&cnt[(k >> 16) & 127], 1);
  }
  __syncthreads();
  if (tid < 128) sc[tid] = cnt[tid];
  __syncthreads();
#pragma unroll
  for (int off = 1; off < 128; off <<= 1) {
    int v = (tid < 128 && tid >= off) ? sc[tid - off] : 0;
    __syncthreads();
    if (tid < 128) sc[tid] += v;
    __syncthreads();
  }
  if (tid < 128) {
    const int n = b * 128 + tid;
    if (n < NN) offsets[n + 1] = base + sc[tid];
    cur[tid] = sc[tid] - cnt[tid];
  }
  if (b == 0 && tid == 0) offsets[0] = 0;
  __syncthreads();
  for (int i = tid; i < Tb; i += 256) {
    const unsigned k = recs[i];
    const int p = atomicAdd(&cur[(k >> 16) & 127], 1);
    csr16[base + p] = (unsigned short)(k & 0xFFFFu);
  }
}

// ============ gemm2: Hb bf16 [NP][64] @ Wp2, 64 rows/block ============
__global__ __launch_bounds__(256, 2) void gemm2(const short* __restrict__ Xb,
                                                const short* __restrict__ Wp,
                                                const float* __restrict__ B0,
                                                const float* __restrict__ B1,
                                                const float* __restrict__ B2,
                                                unsigned short* __restrict__ Y0,
                                                unsigned short* __restrict__ Y1,
                                                unsigned short* __restrict__ Y2) {
  const int lane = threadIdx.x & 63;
  const int wave = threadIdx.x >> 6;
  const int r0 = blockIdx.x * 64 + wave * 16;
  const int m = lane & 15;
  const int q = lane >> 4;
  f32x4 acc[3][4] = {};
  const short* a0 = Xb + (size_t)(r0 + m) * 64 + q * 8;
  const short* bp = Wp + lane * 8;
#pragma unroll
  for (int kb = 0; kb < 2; ++kb) {
    s16x8 bf[12];
#pragma unroll
    for (int i = 0; i < 12; ++i)
      bf[i] = *reinterpret_cast<const s16x8*>(bp + (size_t)(kb * 12 + i) * 512);
    const s16x8 af = *reinterpret_cast<const s16x8*>(a0 + kb * 32);
#pragma unroll
    for (int i = 0; i < 12; ++i)
      acc[i >> 2][i & 3] = __builtin_amdgcn_mfma_f32_16x16x32_bf16(
          af, bf[i], acc[i >> 2][i & 3], 0, 0, 0);
  }
#pragma unroll
  for (int w = 0; w < 3; ++w) {
    const float* B = (w == 0) ? B0 : (w == 1) ? B1 : B2;
    unsigned short* Y = (w == 0) ? Y0 : (w == 1) ? Y1 : Y2;
#pragma unroll
    for (int t = 0; t < 4; ++t) {
      const int c = t * 16 + m;
      const float bv = (c < 40) ? B[c] : 0.f;
#pragma unroll
      for (int rg = 0; rg < 4; ++rg) {
        const int row = r0 + q * 4 + rg;
        if (row < NN)
          Y[(size_t)row * 64 + c] = (unsigned short)f2bf(acc[w][t][rg] + bv);
      }
    }
  }
}

// ====== GATv2 aggregation: 8 lanes/edge, 8 edges in flight, data pipeline ======
// No-max softmax (logits O(20) worst-case; exp safely in fp32; identical math
// to reference's shifted segment softmax). XL row data for iteration i+1 is
// loaded before the math of iteration i (index prefetched 2 ahead).
template <int OC, bool FINAL>
__global__ __launch_bounds__(256) void gat_agg(const unsigned short* __restrict__ XL,
                                               const unsigned short* __restrict__ XR,
                                               const unsigned short* __restrict__ XLIN,
                                               const float* __restrict__ att,
                                               const float* __restrict__ bias,
                                               const int* __restrict__ offsets,
                                               const unsigned short* __restrict__ csr,
                                               float* __restrict__ out,
                                               unsigned short* __restrict__ outb) {
  const int lane = threadIdx.x & 63;
  const int g = lane >> 3;
  const int l = lane & 7;
  const int d = blockIdx.x * 4 + (threadIdx.x >> 6);
  if (d >= NN) return;
  const bool dimok = (8 * l < OC);
  f32x2 a2[4] = {};
  if (dimok) {
    const float4 t0 = *reinterpret_cast<const float4*>(&att[8 * l]);
    const float4 t1 = *reinterpret_cast<const float4*>(&att[8 * l + 4]);
    a2[0] = (f32x2){t0.x, t0.y}; a2[1] = (f32x2){t0.z, t0.w};
    a2[2] = (f32x2){t1.x, t1.y}; a2[3] = (f32x2){t1.z, t1.w};
  }
  f32x2 xr2[4];
  unp8(*reinterpret_cast<const uint4*>(XR + (size_t)d * 64 + 8 * l), xr2);
  const int beg = offsets[d];
  const int end = offsets[d + 1];
  float D = 0.f;
  f32x2 A2[4] = {};
  const f32x2 ns = (f32x2){NEG_SLOPE, NEG_SLOPE};
  const int nit = (end - beg + 7) >> 3;
  // pipeline prologue: data(0), index(1)
  const int i0 = beg + g;
  int sa = (int)csr[(i0 < end) ? i0 : beg];
  uint4 raw_next = *reinterpret_cast<const uint4*>(XL + (size_t)sa * 64 + 8 * l);
  const int i1 = i0 + 8;
  sa = (int)csr[(i1 < end) ? i1 : beg];
  for (int it = 0; it < nit; ++it) {
    const uint4 raw = raw_next;
    const bool act = (beg + it * 8 + g) < end;
    // issue next data load + next-next index before this iteration's math
    raw_next = *reinterpret_cast<const uint4*>(XL + (size_t)sa * 64 + 8 * l);
    const int i2 = beg + (it + 2) * 8 + g;
    sa = (int)csr[(i2 < end) ? i2 : beg];
    f32x2 xl2[4];
    unp8(raw, xl2);
    f32x2 pacc = (f32x2){0.f, 0.f};
#pragma unroll
    for (int j = 0; j < 4; ++j) {
      const f32x2 t = xl2[j] + xr2[j];
      const f32x2 lr = pk_max(t, t * ns);
      pacc = pk_fma(lr, a2[j], pacc);
    }
    float p = pacc[0] + pacc[1];
    p += __shfl_xor(p, 1, 64);
    p += __shfl_xor(p, 2, 64);
    p += __shfl_xor(p, 4, 64);          // group-uniform logit
    const float w = __expf(act ? p : -INFINITY);  // 0 for inactive slots
    D += w;
    const f32x2 w2 = (f32x2){w, w};
#pragma unroll
    for (int j = 0; j < 4; ++j) A2[j] = pk_fma(w2, xl2[j], A2[j]);
  }
  // merge the 8 group states: plain sums (no rescale needed)
  D += __shfl_xor(D, 8, 64);
  D += __shfl_xor(D, 16, 64);
  D += __shfl_xor(D, 32, 64);
  float A[8];
#pragma unroll
  for (int j = 0; j < 4; ++j) {
#pragma unroll
    for (int c = 0; c < 2; ++c) {
      float v = A2[j][c];
      v += __shfl_xor(v, 8, 64);
      v += __shfl_xor(v, 16, 64);
      v += __shfl_xor(v, 32, 64);
      A[j * 2 + c] = v;
    }
  }
  f32x2 xlin2[4];
  unp8(*reinterpret_cast<const uint4*>(XLIN + (size_t)d * 64 + 8 * l), xlin2);
  float b[8] = {};
  if (dimok) {
    const float4 t0 = *reinterpret_cast<const float4*>(&bias[8 * l]);
    const float4 t1 = *reinterpret_cast<const float4*>(&bias[8 * l + 4]);
    b[0] = t0.x; b[1] = t0.y; b[2] = t0.z; b[3] = t0.w;
    b[4] = t1.x; b[5] = t1.y; b[6] = t1.z; b[7] = t1.w;
  }
  const float inv = 1.0f / D;  // D > 0 (self-loop)
  float val[8];
#pragma unroll
  for (int j = 0; j < 8; ++j)
    val[j] = fmaf(A[j], inv, b[j]) + xlin2[j >> 1][j & 1];
  if (!FINAL) {
    if (g == 0) {
      uint4 o;
      o.x = pack2(fmaxf(val[0], 0.f), fmaxf(val[1], 0.f));
      o.y = pack2(fmaxf(val[2], 0.f), fmaxf(val[3], 0.f));
      o.z = pack2(fmaxf(val[4], 0.f), fmaxf(val[5], 0.f));
      o.w = pack2(fmaxf(val[6], 0.f), fmaxf(val[7], 0.f));
      *reinterpret_cast<uint4*>(&outb[(size_t)d * 64 + 8 * l]) = o;
    }
  } else {
    float mx = -3e38f;
    if (dimok) {
#pragma unroll
      for (int j = 0; j < 8; ++j) mx = fmaxf(mx, val[j]);
    }
    mx = fmaxf(mx, __shfl_xor(mx, 1, 64));
    mx = fmaxf(mx, __shfl_xor(mx, 2, 64));
    mx = fmaxf(mx, __shfl_xor(mx, 4, 64));
    float es = 0.f;
    if (dimok) {
#pragma unroll
      for (int j = 0; j < 8; ++j) es += __expf(val[j] - mx);
    }
    es += __shfl_xor(es, 1, 64);
    es += __shfl_xor(es, 2, 64);
    es += __shfl_xor(es, 4, 64);
    const float lse = mx + __logf(es);
    if (g == 0 && dimok) {
      float4 o0, o1;
      o0.x = val[0] - lse; o0.y = val[1] - lse; o0.z = val[2] - lse; o0.w = val[3] - lse;
      o1.x = val[4] - lse; o1.y = val[5] - lse; o1.z = val[6] - lse; o1.w = val[7] - lse;
      float* dst = &out[(size_t)d * OC + 8 * l];
      *reinterpret_cast<float4*>(dst) = o0;
      *reinterpret_cast<float4*>(dst + 4) = o1;
    }
  }
}

// ---------------- launch ----------------
extern "C" void kernel_launch(void* const* d_in, const int* in_sizes, int n_in,
                              void* d_out, int out_size, void* d_ws, size_t ws_size,
                              hipStream_t stream) {
  const float* x     = (const float*)d_in[0];
  const int*   ei    = (const int*)d_in[1];
  const float* W1l   = (const float*)d_in[2];
  const float* b1l   = (const float*)d_in[3];
  const float* W1r   = (const float*)d_in[4];
  const float* b1r   = (const float*)d_in[5];
  const float* att1  = (const float*)d_in[6];
  const float* bias1 = (const float*)d_in[7];
  const float* lin1W = (const float*)d_in[8];
  const float* lin1b = (const float*)d_in[9];
  const float* W2l   = (const float*)d_in[10];
  const float* b2l   = (const float*)d_in[11];
  const float* W2r   = (const float*)d_in[12];
  const float* b2r   = (const float*)d_in[13];
  const float* att2  = (const float*)d_in[14];
  const float* bias2 = (const float*)d_in[15];
  const float* lin2W = (const float*)d_in[16];
  const float* lin2b = (const float*)d_in[17];
  float* out = (float*)d_out;

  char* ws = (char*)d_ws;
  size_t off = 0;
  auto alloc = [&](size_t bytes) -> void* {
    void* p = ws + off;
    off += (bytes + 255) & ~(size_t)255;
    return p;
  };
  short* Wp1 = (short*)alloc((size_t)TB1 * 2);
  short* Wp2 = (short*)alloc((size_t)TB2 * 2);
  unsigned short* XL1   = (unsigned short*)alloc((size_t)NN * 64 * 2);
  unsigned short* XR1   = (unsigned short*)alloc((size_t)NN * 64 * 2);
  unsigned short* XLIN1 = (unsigned short*)alloc((size_t)NN * 64 * 2);
  unsigned short* Hb    = (unsigned short*)alloc((size_t)NP * 64 * 2);
  unsigned short* XL2   = (unsigned short*)alloc((size_t)NN * 64 * 2);
  unsigned short* XR2   = (unsigned short*)alloc((size_t)NN * 64 * 2);
  unsigned short* XLIN2 = (unsigned short*)alloc((size_t)NN * 64 * 2);
  int* gcur    = (int*)alloc((size_t)NBKT * 4);
  int* offsets = (int*)alloc((size_t)(NN + 1) * 4);
  unsigned* rec = (unsigned*)alloc((size_t)NBKT * BCAP * 4);
  unsigned short* csr = (unsigned short*)alloc((size_t)NITEMS * 2);

  hipMemsetAsync(gcur, 0, (size_t)NBKT * 4, stream);
  prep_bin<<<WPB + NCH, 256, 0, stream>>>(W1l, W1r, lin1W, W2l, W2r, lin2W,
                                          Wp1, Wp2, ei, out + (size_t)NN * CD,
                                          gcur, rec);
  build_gemm1<<<GB1 + NBKT, 256, 0, stream>>>(x, Wp1, b1l, b1r, lin1b,
                                              XL1, XR1, XLIN1, gcur, rec,
                                              offsets, csr);
  gat_agg<64, false><<<(NN + 3) / 4, 256, 0, stream>>>(XL1, XR1, XLIN1, att1,
                                                       bias1, offsets, csr,
                                                       nullptr, Hb);
  gemm2<<<GB1, 256, 0, stream>>>((const short*)Hb, Wp2, b2l, b2r, lin2b,
                                 XL2, XR2, XLIN2);
  gat_agg<40, true><<<(NN + 3) / 4, 256, 0, stream>>>(XL2, XR2, XLIN2, att2,
                                                      bias2, offsets, csr,
                                                      out, nullptr);
}